// Round 8
// baseline (445.598 us; speedup 1.0000x reference)
//
#include <hip/hip_runtime.h>

#define Gg   32
#define Nn   128
#define Hh   128
#define Ee   65536
#define GN   4096      // Gg*Nn
#define GNN  524288    // Gg*Nn*Nn

typedef unsigned short ushort_t;
typedef __attribute__((ext_vector_type(8))) __bf16 bf16x8;
typedef __attribute__((ext_vector_type(4))) float f32x4;
struct us4 { ushort_t a, b, c, d; };

__device__ __forceinline__ float reluf(float x) { return x > 0.f ? x : 0.f; }

// round-to-nearest-even f32 -> bf16 bits
__device__ __forceinline__ ushort_t bfh(float x) {
  unsigned u = __float_as_uint(x);
  return (ushort_t)((u + 0x7FFFu + ((u >> 16) & 1u)) >> 16);
}
__device__ __forceinline__ void split2(float x, ushort_t& h, ushort_t& l) {
  h = bfh(x);
  float hf = __uint_as_float(((unsigned)h) << 16);
  l = bfh(x - hf);
}

// ---------------- edge_index layout detection ----------------
__global__ __launch_bounds__(128) void k_detect(const int* __restrict__ e32,
                                                int* __restrict__ flag) {
  __shared__ int s;
  if (threadIdx.x == 0) s = 0;
  __syncthreads();
  if (e32[2 * threadIdx.x + 1] != 0) atomicOr(&s, 1);
  __syncthreads();
  if (threadIdx.x == 0) *flag = s;  // 1 => int32 layout, 0 => int64 layout
}

// ---------------- encoders ----------------
__global__ __launch_bounds__(256) void k_node_encode(const int* __restrict__ x,
                                                     const float* __restrict__ atom_tab,
                                                     float* __restrict__ nf,
                                                     float* __restrict__ hid) {
  int t = blockIdx.x * 256 + threadIdx.x;      // over GN*Hh
  int v = t >> 7, h = t & 127;
  float s = 0.f;
#pragma unroll
  for (int f = 0; f < 9; ++f) {
    int idx = x[v * 9 + f];
    s += atom_tab[(f * 119 + idx) * Hh + h];
  }
  nf[t] = s;
  hid[t] = 0.f;
}

__global__ __launch_bounds__(256) void k_bond_fts(const float* __restrict__ bond_tab,
                                                  float* __restrict__ bf) {
  int t = blockIdx.x * 256 + threadIdx.x;      // 512*128
  int c = t >> 7, h = t & 127;
  int a0 = c & 7, a1 = (c >> 3) & 7, a2 = (c >> 6) & 7;
  bf[t] = bond_tab[(0 * 8 + a0) * Hh + h] + bond_tab[(1 * 8 + a1) * Hh + h] +
          bond_tab[(2 * 8 + a2) * Hh + h];
}

// ---------------- edge winner: win indexed by (g, d, s); last edge wins ----------
__global__ __launch_bounds__(256) void k_scatter_win(const int* __restrict__ e32,
                                                     const int* __restrict__ flag,
                                                     int* __restrict__ win) {
  int e = blockIdx.x * 256 + threadIdx.x;
  int sg, dg;
  if (*flag) { sg = e32[e]; dg = e32[Ee + e]; }
  else       { sg = e32[2 * e]; dg = e32[2 * Ee + 2 * e]; }
  int g = sg / Nn;
  int s = sg % Nn;
  int d = dg % Nn;
  atomicMax(&win[(g * Nn + d) * Nn + s], e);   // destination-major
}

// ---------------- per-destination compaction: count / scan / fill ----------------
__global__ __launch_bounds__(256) void k_dcount(const int* __restrict__ win,
                                                int* __restrict__ dcnt) {
  int tid = threadIdx.x;
  int grp = tid >> 7, t = tid & 127;
  int dest = blockIdx.x * 2 + grp;
  bool valid = win[dest * 128 + t] >= 0;
  unsigned long long mask = __ballot(valid);
  __shared__ int cw[4];
  if ((tid & 63) == 0) cw[tid >> 6] = __popcll(mask);
  __syncthreads();
  if (t == 0) dcnt[dest] = cw[grp * 2] + cw[grp * 2 + 1];
}

__global__ __launch_bounds__(512) void k_dscan(const int* __restrict__ dcnt,
                                               int* __restrict__ rowptr) {
  int tid = threadIdx.x;            // 512 threads x 8 dests = 4096
  int c0, c1, c2, c3, c4, c5, c6, c7;
  int bi = tid * 8;
  c0 = dcnt[bi + 0]; c1 = dcnt[bi + 1]; c2 = dcnt[bi + 2]; c3 = dcnt[bi + 3];
  c4 = dcnt[bi + 4]; c5 = dcnt[bi + 5]; c6 = dcnt[bi + 6]; c7 = dcnt[bi + 7];
  int s = c0 + c1 + c2 + c3 + c4 + c5 + c6 + c7;
  int x = s;
#pragma unroll
  for (int off = 1; off < 64; off <<= 1) {
    int y = __shfl_up(x, off, 64);
    if ((tid & 63) >= off) x += y;
  }
  __shared__ int wsum[8], woff[8];
  if ((tid & 63) == 63) wsum[tid >> 6] = x;
  __syncthreads();
  if (tid == 0) {
    int a = 0;
#pragma unroll
    for (int i = 0; i < 8; ++i) { woff[i] = a; a += wsum[i]; }
  }
  __syncthreads();
  int base = x - s + woff[tid >> 6];
  rowptr[bi + 0] = base; base += c0;
  rowptr[bi + 1] = base; base += c1;
  rowptr[bi + 2] = base; base += c2;
  rowptr[bi + 3] = base; base += c3;
  rowptr[bi + 4] = base; base += c4;
  rowptr[bi + 5] = base; base += c5;
  rowptr[bi + 6] = base; base += c6;
  rowptr[bi + 7] = base; base += c7;
  if (tid == 511) rowptr[4096] = base;
}

__global__ __launch_bounds__(256) void k_dfill(const int* __restrict__ win,
                                               const int* __restrict__ eattr,
                                               const int* __restrict__ rowptr,
                                               unsigned* __restrict__ recs) {
  int tid = threadIdx.x;
  int grp = tid >> 7, t = tid & 127;
  int dest = blockIdx.x * 2 + grp;
  int e = win[dest * 128 + t];
  bool valid = e >= 0;
  unsigned long long mask = __ballot(valid);
  __shared__ int cw[4];
  int lane = tid & 63;
  if (lane == 0) cw[tid >> 6] = __popcll(mask);
  __syncthreads();
  if (valid) {
    int off = __popcll(mask & ((1ull << lane) - 1));
    if ((tid >> 6) & 1) off += cw[grp * 2];
    int a0 = eattr[e * 3 + 0], a1 = eattr[e * 3 + 1], a2 = eattr[e * 3 + 2];
    unsigned code = (unsigned)(a0 + (a1 << 3) + (a2 << 6));
    recs[rowptr[dest] + off] = ((unsigned)t << 9) | code;   // s = t, sorted by dest
  }
}

// ---------------- weight prep: W_h1/W_h2 -> transposed hi/lo bf16 ----------------
// wt layout: [layer(2)][mat(2)][part(2)][n(128)][k(128)] ushort
__global__ __launch_bounds__(256) void k_wprep(const float* __restrict__ W_h1,
                                               const float* __restrict__ W_h2,
                                               ushort_t* __restrict__ wt) {
  int t = blockIdx.x * 256 + threadIdx.x;      // 2*2*16384
  int l = t >> 15;
  int m = (t >> 14) & 1;
  int e = t & 16383;
  int n = e & 127, k = e >> 7;
  const float* W = (m == 0 ? W_h1 : W_h2) + l * 16384;
  float v = W[k * 128 + n];
  ushort_t h, lo;
  split2(v, h, lo);
  int base = ((l * 2 + m) * 2) * 16384;
  wt[base + n * 128 + k] = h;
  wt[base + 16384 + n * 128 + k] = lo;
}

// ---------------- weight prep: [Wo1;Wo2] -> transposed hi/lo bf16 ----------------
// wo layout: [layer(2)][part(2)][n(128)][k(384)] ushort; grid (192, 2)
__global__ __launch_bounds__(256) void k_wprep_o(const float* __restrict__ W_o1,
                                                 const float* __restrict__ W_o2,
                                                 ushort_t* __restrict__ wo) {
  int e = blockIdx.x * 256 + threadIdx.x;      // 0 .. 49151  (= n*384 + k)
  int l = blockIdx.y;
  int n = e / 384, k = e - n * 384;
  float v = (k < 256) ? W_o1[(l * 256 + k) * 128 + n]
                      : W_o2[(l * 128 + (k - 256)) * 128 + n];
  ushort_t h, lo;
  split2(v, h, lo);
  wo[((l * 2 + 0) * 128 + n) * 384 + k] = h;
  wo[((l * 2 + 1) * 128 + n) * 384 + k] = lo;
}

// ---------------- weight prep: W_m1/W_m2 -> transposed hi/lo bf16 ----------------
// wm layout: [layer(2)][mat(2)][part(2)][n(128)][k(256)] ushort
__global__ __launch_bounds__(256) void k_wprep_m(const float* __restrict__ W_m1,
                                                 const float* __restrict__ W_m2,
                                                 ushort_t* __restrict__ wm) {
  int t = blockIdx.x * 256 + threadIdx.x;      // 131072 = 2l*2m*32768
  int l = t >> 16;
  int m = (t >> 15) & 1;
  int e = t & 32767;                           // n*256 + k
  int n = e >> 8, k = e & 255;
  const float* W = (m == 0 ? W_m1 : W_m2);
  float v = W[(l * 256 + k) * 128 + n];
  ushort_t h, lo;
  split2(v, h, lo);
  int base = ((l * 2 + m) * 2) * 32768;
  wm[base + n * 256 + k] = h;
  wm[base + 32768 + n * 256 + k] = lo;
}

// ---------------- me table ----------------
__global__ __launch_bounds__(256) void k_me(const float* __restrict__ bf,
                                            const float* __restrict__ W_me,
                                            const float* __restrict__ b_me,
                                            const float* __restrict__ b_mg,
                                            float* __restrict__ me) {
  __shared__ float v[2][128];
  int tid = threadIdx.x;
  int half = tid >> 7, j = tid & 127;
  int c = blockIdx.x * 2 + half;
  v[half][j] = bf[c * 128 + j];
  __syncthreads();
  float acc = b_me[j] + b_mg[j];
  for (int i = 0; i < 128; ++i) acc += v[half][i] * W_me[i * 128 + j];
  me[c * 128 + j] = acc;
}

// ---------------- m1,m2 = [nf|hid] @ W_m1 / W_m2 via MFMA ----------------
__global__ __launch_bounds__(64) void k_m12(const float* __restrict__ nf_,
                                            const float* __restrict__ hid,
                                            const ushort_t* __restrict__ wm,
                                            const float* __restrict__ bi1,
                                            const float* __restrict__ bi2,
                                            float* __restrict__ m1,
                                            float* __restrict__ m2) {
  __shared__ ushort_t AH[16][264];
  __shared__ ushort_t AL[16][264];
  int tid = threadIdx.x;              // one wave
  int v0 = blockIdx.x * 16;
#pragma unroll
  for (int i = 0; i < 16; ++i) {
    int idx = tid + i * 64;           // 16 rows x 64 float4
    int row = idx >> 6, c4 = idx & 63;
    float4 v = (c4 < 32) ? ((const float4*)nf_)[(v0 + row) * 32 + c4]
                         : ((const float4*)hid)[(v0 + row) * 32 + (c4 - 32)];
    us4 h4, l4;
    split2(v.x, h4.a, l4.a); split2(v.y, h4.b, l4.b);
    split2(v.z, h4.c, l4.c); split2(v.w, h4.d, l4.d);
    *(us4*)&AH[row][c4 * 4] = h4;
    *(us4*)&AL[row][c4 * 4] = l4;
  }
  __syncthreads();
  int lr = tid & 15, lg = tid >> 4;
  f32x4 a1[8], a2[8];
#pragma unroll
  for (int i = 0; i < 8; ++i) { a1[i] = (f32x4){0.f,0.f,0.f,0.f}; a2[i] = (f32x4){0.f,0.f,0.f,0.f}; }
  const ushort_t* w1h = wm;
  const ushort_t* w1l = wm + 32768;
  const ushort_t* w2h = wm + 65536;
  const ushort_t* w2l = wm + 98304;
#pragma unroll
  for (int seg = 0; seg < 2; ++seg) {
    bf16x8 ah[4], al[4];
#pragma unroll
    for (int kf = 0; kf < 4; ++kf) {
      ah[kf] = *(const bf16x8*)&AH[lr][seg * 128 + lg * 8 + 32 * kf];
      al[kf] = *(const bf16x8*)&AL[lr][seg * 128 + lg * 8 + 32 * kf];
    }
#pragma unroll
    for (int nfr = 0; nfr < 8; ++nfr) {
      const ushort_t* p1h = w1h + (16 * nfr + lr) * 256 + seg * 128 + lg * 8;
      const ushort_t* p1l = w1l + (16 * nfr + lr) * 256 + seg * 128 + lg * 8;
      const ushort_t* p2h = w2h + (16 * nfr + lr) * 256 + seg * 128 + lg * 8;
      const ushort_t* p2l = w2l + (16 * nfr + lr) * 256 + seg * 128 + lg * 8;
#pragma unroll
      for (int kf = 0; kf < 4; ++kf) {
        bf16x8 b1h = *(const bf16x8*)(p1h + 32 * kf);
        bf16x8 b1l = *(const bf16x8*)(p1l + 32 * kf);
        bf16x8 b2h = *(const bf16x8*)(p2h + 32 * kf);
        bf16x8 b2l = *(const bf16x8*)(p2l + 32 * kf);
        a1[nfr] = __builtin_amdgcn_mfma_f32_16x16x32_bf16(ah[kf], b1h, a1[nfr], 0, 0, 0);
        a1[nfr] = __builtin_amdgcn_mfma_f32_16x16x32_bf16(ah[kf], b1l, a1[nfr], 0, 0, 0);
        a1[nfr] = __builtin_amdgcn_mfma_f32_16x16x32_bf16(al[kf], b1h, a1[nfr], 0, 0, 0);
        a2[nfr] = __builtin_amdgcn_mfma_f32_16x16x32_bf16(ah[kf], b2h, a2[nfr], 0, 0, 0);
        a2[nfr] = __builtin_amdgcn_mfma_f32_16x16x32_bf16(ah[kf], b2l, a2[nfr], 0, 0, 0);
        a2[nfr] = __builtin_amdgcn_mfma_f32_16x16x32_bf16(al[kf], b2h, a2[nfr], 0, 0, 0);
      }
    }
  }
#pragma unroll
  for (int nfr = 0; nfr < 8; ++nfr) {
    int col = 16 * nfr + lr;
    float bb1 = bi1[col], bb2 = bi2[col];
#pragma unroll
    for (int reg = 0; reg < 4; ++reg) {
      int row = v0 + lg * 4 + reg;
      m1[row * Hh + col] = a1[nfr][reg] + bb1;
      m2[row * Hh + col] = a2[nfr][reg] + bb2;
    }
  }
}

// ---------------- MFMA helpers ----------------
__device__ __forceinline__ void load_afrag(const ushort_t (*MH)[136],
                                           const ushort_t (*ML)[136],
                                           int row, int lg,
                                           bf16x8 ah[4], bf16x8 al[4]) {
#pragma unroll
  for (int kf = 0; kf < 4; ++kf) {
    ah[kf] = *(const bf16x8*)&MH[row][lg * 8 + 32 * kf];
    al[kf] = *(const bf16x8*)&ML[row][lg * 8 + 32 * kf];
  }
}

__device__ __forceinline__ void wave_gemm(const ushort_t* __restrict__ wth,
                                          const ushort_t* __restrict__ wtl,
                                          const bf16x8 ah[4], const bf16x8 al[4],
                                          int lr, int lg, f32x4 acc[8]) {
#pragma unroll
  for (int nf = 0; nf < 8; ++nf) {
    acc[nf] = (f32x4){0.f, 0.f, 0.f, 0.f};
    const ushort_t* bh_base = wth + (16 * nf + lr) * 128 + lg * 8;
    const ushort_t* bl_base = wtl + (16 * nf + lr) * 128 + lg * 8;
#pragma unroll
    for (int kf = 0; kf < 4; ++kf) {
      bf16x8 bh = *(const bf16x8*)(bh_base + 32 * kf);
      bf16x8 bl = *(const bf16x8*)(bl_base + 32 * kf);
      acc[nf] = __builtin_amdgcn_mfma_f32_16x16x32_bf16(ah[kf], bh, acc[nf], 0, 0, 0);
      acc[nf] = __builtin_amdgcn_mfma_f32_16x16x32_bf16(ah[kf], bl, acc[nf], 0, 0, 0);
      acc[nf] = __builtin_amdgcn_mfma_f32_16x16x32_bf16(al[kf], bh, acc[nf], 0, 0, 0);
    }
  }
}

// ---------------- edge phase: dest-partitioned, atomic-free ----------------
// block b owns dests [4b, 4b+4); edges sorted by dest in recs
__global__ __launch_bounds__(256) void k_edge(const unsigned* __restrict__ recs,
                                              const int* __restrict__ rowptr,
                                              const float* __restrict__ m1,
                                              const float* __restrict__ m2,
                                              const float* __restrict__ me,
                                              const ushort_t* __restrict__ wt1h,
                                              const ushort_t* __restrict__ wt1l,
                                              const ushort_t* __restrict__ wt2h,
                                              const ushort_t* __restrict__ wt2l,
                                              const float* __restrict__ b_h1,
                                              const float* __restrict__ b_h2,
                                              float* __restrict__ agg) {
  __shared__ ushort_t MH[64][136];
  __shared__ ushort_t ML[64][136];
  __shared__ unsigned srow[64];
  __shared__ float sm1[4][128];
  __shared__ int sdest[5];
  int tid = threadIdx.x;
  int D = blockIdx.x * 4;
  int g = D >> 7;
  if (tid < 5) sdest[tid] = rowptr[D + tid];
  {
    int i0 = tid, i1 = tid + 256;   // stage m1 rows of this block's 4 dests
    sm1[i0 >> 7][i0 & 127] = m1[(D + (i0 >> 7)) * 128 + (i0 & 127)];
    sm1[i1 >> 7][i1 & 127] = m1[(D + (i1 >> 7)) * 128 + (i1 & 127)];
  }
  __syncthreads();
  int start = sdest[0], end = sdest[4];
  int rp1 = sdest[1], rp2 = sdest[2], rp3 = sdest[3];
  int nrows = end - start;

  int lane = tid & 63, wid = tid >> 6;
  int lr = lane & 15, lg = lane >> 4;
  float b1v[8], b2v[8];
#pragma unroll
  for (int nf = 0; nf < 8; ++nf) {
    b1v[nf] = b_h1[16 * nf + lr];
    b2v[nf] = b_h2[16 * nf + lr];
  }
  // scan-thread assignment: col c, dest pair kp
  int c = tid & 127, kp = tid >> 7;
  int d0 = 2 * kp, d1 = 2 * kp + 1;
  int l0s = sdest[d0] - start, l0e = sdest[d0 + 1] - start;
  int l1s = sdest[d1] - start, l1e = sdest[d1 + 1] - start;
  float mx0 = -1.0e9f, mx1 = -1.0e9f;

  for (int base = 0; base < nrows; base += 64) {
    // row records for this pass
    if (tid < 64) {
      int ridx = start + base + tid;
      unsigned v = 0xFFFFFFFFu;
      if (ridx < end) {
        unsigned rec = recs[ridx];                       // (s<<9)|code
        int dl = (ridx >= rp1) + (ridx >= rp2) + (ridx >= rp3);
        v = ((unsigned)dl << 16) | rec;
      }
      srow[tid] = v;
    }
    __syncthreads();
    // M build (float4-vectorized, chunked 2x4 rows to cap register pressure)
    {
      int c4 = tid & 31, r8 = tid >> 5;
#pragma unroll
      for (int ch = 0; ch < 2; ++ch) {
        float4 vv[4];
#pragma unroll
        for (int i = 0; i < 4; ++i) {
          int r = r8 + 8 * (ch * 4 + i);
          float4 v = make_float4(0.f, 0.f, 0.f, 0.f);
          unsigned rec = srow[r];
          if (rec != 0xFFFFFFFFu) {
            int code = rec & 511, s = (rec >> 9) & 127, dl = rec >> 16;
            float4 a = *(const float4*)(m2 + (((g << 7) + s) << 7) + c4 * 4);
            float4 bb = *(const float4*)(me + (code << 7) + c4 * 4);
            float4 mm = *(const float4*)(&sm1[dl][c4 * 4]);
            v.x = reluf(mm.x + a.x + bb.x);
            v.y = reluf(mm.y + a.y + bb.y);
            v.z = reluf(mm.z + a.z + bb.z);
            v.w = reluf(mm.w + a.w + bb.w);
          }
          vv[i] = v;
        }
#pragma unroll
        for (int i = 0; i < 4; ++i) {
          int r = r8 + 8 * (ch * 4 + i);
          us4 h4, l4;
          split2(vv[i].x, h4.a, l4.a); split2(vv[i].y, h4.b, l4.b);
          split2(vv[i].z, h4.c, l4.c); split2(vv[i].w, h4.d, l4.d);
          *(us4*)&MH[r][c4 * 4] = h4;
          *(us4*)&ML[r][c4 * 4] = l4;
        }
      }
    }
    __syncthreads();
    // GEMM1
    int arow = 16 * wid + lr;
    bf16x8 ah[4], al[4];
    load_afrag(MH, ML, arow, lg, ah, al);
    f32x4 acc[8];
    wave_gemm(wt1h, wt1l, ah, al, lr, lg, acc);
    // T = relu(acc + b1) -> wave-private rows
#pragma unroll
    for (int nf = 0; nf < 8; ++nf)
#pragma unroll
      for (int reg = 0; reg < 4; ++reg) {
        float t = reluf(acc[nf][reg] + b1v[nf]);
        int row = 16 * wid + lg * 4 + reg;
        int col = 16 * nf + lr;
        ushort_t h, l;
        split2(t, h, l);
        MH[row][col] = h;
        ML[row][col] = l;
      }
    __syncthreads();
    load_afrag(MH, ML, arow, lg, ah, al);
    wave_gemm(wt2h, wt2l, ah, al, lr, lg, acc);
    // park f32 bits (wave-private rows)
#pragma unroll
    for (int nf = 0; nf < 8; ++nf)
#pragma unroll
      for (int reg = 0; reg < 4; ++reg) {
        int row = 16 * wid + lg * 4 + reg;
        int col = 16 * nf + lr;
        unsigned b = __float_as_uint(acc[nf][reg] + b2v[nf]);
        MH[row][col] = (ushort_t)(b >> 16);
        ML[row][col] = (ushort_t)(b & 0xFFFFu);
      }
    __syncthreads();
    // local column-max per dest (no atomics)
    {
      int blo = base, bhi = base + 64;
      int f0 = l0s > blo ? l0s : blo, t0 = l0e < bhi ? l0e : bhi;
      for (int r = f0; r < t0; ++r) {
        unsigned b = ((unsigned)MH[r - base][c] << 16) | (unsigned)ML[r - base][c];
        mx0 = fmaxf(mx0, __uint_as_float(b));
      }
      int f1 = l1s > blo ? l1s : blo, t1 = l1e < bhi ? l1e : bhi;
      for (int r = f1; r < t1; ++r) {
        unsigned b = ((unsigned)MH[r - base][c] << 16) | (unsigned)ML[r - base][c];
        mx1 = fmaxf(mx1, __uint_as_float(b));
      }
    }
    __syncthreads();   // before next pass overwrites MH/ML
  }
  agg[(D + d0) * 128 + c] = mx0;
  agg[(D + d1) * 128 + c] = mx1;
}

// ---------------- hid update: relu([nf|hid|agg] @ [Wo1;Wo2] + b) via MFMA --------
__global__ __launch_bounds__(64) void k_out(const float* __restrict__ nf,
                                            const float* __restrict__ hid,
                                            const float* __restrict__ agg,
                                            const ushort_t* __restrict__ wo_h,
                                            const ushort_t* __restrict__ wo_l,
                                            const float* __restrict__ bo1,
                                            const float* __restrict__ bo2,
                                            float* __restrict__ hidn) {
  __shared__ ushort_t MH[16][136];
  __shared__ ushort_t ML[16][136];
  int tid = threadIdx.x;              // one wave
  int v0 = blockIdx.x * 16;
  int lr = tid & 15, lg = tid >> 4;
  f32x4 acc[8];
#pragma unroll
  for (int nfr = 0; nfr < 8; ++nfr) acc[nfr] = (f32x4){0.f, 0.f, 0.f, 0.f};

  for (int seg = 0; seg < 3; ++seg) {
#pragma unroll
    for (int i = 0; i < 8; ++i) {
      int idx = tid + i * 64;         // over 512 float4s
      int row = idx >> 5, c4 = idx & 31;
      float4 v;
      if (seg == 0)      v = ((const float4*)nf)[(v0 + row) * 32 + c4];
      else if (seg == 1) v = ((const float4*)hid)[(v0 + row) * 32 + c4];
      else               v = ((const float4*)agg)[(v0 + row) * 32 + c4];
      us4 h4, l4;
      split2(v.x, h4.a, l4.a);
      split2(v.y, h4.b, l4.b);
      split2(v.z, h4.c, l4.c);
      split2(v.w, h4.d, l4.d);
      *(us4*)&MH[row][c4 * 4] = h4;
      *(us4*)&ML[row][c4 * 4] = l4;
    }
    __syncthreads();
    bf16x8 ah[4], al[4];
    load_afrag(MH, ML, lr, lg, ah, al);
#pragma unroll
    for (int nfr = 0; nfr < 8; ++nfr) {
      const ushort_t* bh_base = wo_h + (16 * nfr + lr) * 384 + seg * 128 + lg * 8;
      const ushort_t* bl_base = wo_l + (16 * nfr + lr) * 384 + seg * 128 + lg * 8;
#pragma unroll
      for (int kf = 0; kf < 4; ++kf) {
        bf16x8 bh = *(const bf16x8*)(bh_base + 32 * kf);
        bf16x8 bl = *(const bf16x8*)(bl_base + 32 * kf);
        acc[nfr] = __builtin_amdgcn_mfma_f32_16x16x32_bf16(ah[kf], bh, acc[nfr], 0, 0, 0);
        acc[nfr] = __builtin_amdgcn_mfma_f32_16x16x32_bf16(ah[kf], bl, acc[nfr], 0, 0, 0);
        acc[nfr] = __builtin_amdgcn_mfma_f32_16x16x32_bf16(al[kf], bh, acc[nfr], 0, 0, 0);
      }
    }
    __syncthreads();
  }
#pragma unroll
  for (int nfr = 0; nfr < 8; ++nfr) {
    int col = 16 * nfr + lr;
    float b = bo1[col] + bo2[col];
#pragma unroll
    for (int reg = 0; reg < 4; ++reg)
      hidn[(v0 + lg * 4 + reg) * Hh + col] = reluf(acc[nfr][reg] + b);
  }
}

// ---------------- readout head ----------------
__global__ __launch_bounds__(128) void k_head(const float* __restrict__ hid,
                                              const float* __restrict__ Wg1,
                                              const float* __restrict__ bg1,
                                              const float* __restrict__ Wg2,
                                              const float* __restrict__ bg2,
                                              float* __restrict__ out) {
  __shared__ float emb[Hh];
  __shared__ float tt[Hh];
  int g = blockIdx.x, j = threadIdx.x;
  float s = 0.f;
  for (int n = 0; n < Nn; ++n) s += hid[(g * Nn + n) * Hh + j];
  emb[j] = s * (1.f / Nn);
  __syncthreads();
  float a = bg1[j];
  for (int i = 0; i < Hh; ++i) a += emb[i] * Wg1[i * Hh + j];
  tt[j] = reluf(a);
  __syncthreads();
  if (j < 12) {
    float o = bg2[j];
    for (int i = 0; i < Hh; ++i) o += tt[i] * Wg2[i * 12 + j];
    out[g * 12 + j] = o;
  }
}

extern "C" void kernel_launch(void* const* d_in, const int* in_sizes, int n_in,
                              void* d_out, int out_size, void* d_ws, size_t ws_size,
                              hipStream_t stream) {
  const int* x = (const int*)d_in[0];
  const int* eidx32 = (const int*)d_in[1];
  const int* eattr = (const int*)d_in[2];
  const float* atom_tab = (const float*)d_in[4];
  const float* bond_tab = (const float*)d_in[5];
  const float* W_m1 = (const float*)d_in[6];
  const float* b_m1 = (const float*)d_in[7];
  const float* W_m2 = (const float*)d_in[8];
  const float* b_m2 = (const float*)d_in[9];
  const float* W_me = (const float*)d_in[10];
  const float* b_me = (const float*)d_in[11];
  const float* b_mg = (const float*)d_in[13];
  const float* W_h1 = (const float*)d_in[14];
  const float* b_h1 = (const float*)d_in[15];
  const float* W_h2 = (const float*)d_in[16];
  const float* b_h2 = (const float*)d_in[17];
  const float* W_o1 = (const float*)d_in[18];
  const float* b_o1 = (const float*)d_in[19];
  const float* W_o2 = (const float*)d_in[20];
  const float* b_o2 = (const float*)d_in[21];
  const float* Wg1 = (const float*)d_in[22];
  const float* bg1 = (const float*)d_in[23];
  const float* Wg2 = (const float*)d_in[24];
  const float* bg2 = (const float*)d_in[25];
  float* out = (float*)d_out;

  char* ws = (char*)d_ws;
  float* nf = (float*)(ws);                                 // 2MB
  float* hidA = (float*)(ws + (2u << 20));                  // 2MB
  float* hidB = (float*)(ws + (4u << 20));                  // 2MB
  float* m1 = (float*)(ws + (6u << 20));                    // 2MB
  float* m2 = (float*)(ws + (8u << 20));                    // 2MB
  float* agg = (float*)(ws + (10u << 20));                  // 2MB
  int* win = (int*)(ws + (12u << 20));                      // 2MB (dead after k_dfill)
  ushort_t* wo = (ushort_t*)(ws + (12u << 20));             // 384KB (overlays win)
  ushort_t* wm = (ushort_t*)(ws + (12u << 20) + 393216);    // 512KB (overlays win)
  ushort_t* wt = (ushort_t*)(ws + (14u << 20));             // 256KB
  float* bf = (float*)(ws + (14u << 20) + (256u << 10));    // 256KB
  float* me = (float*)(ws + (14u << 20) + (512u << 10));    // 256KB
  unsigned* recs = (unsigned*)(ws + (14u << 20) + (768u << 10));  // 256KB
  int* dcnt = (int*)(ws + (15u << 20));                     // 16KB
  int* rowptr = (int*)(ws + (15u << 20) + (16u << 10));     // ~16KB (4097)
  int* eflag = (int*)(ws + (15u << 20) + (48u << 10));      // 4B

  hipMemsetAsync(win, 0xFF, GNN * sizeof(int), stream);
  k_detect<<<1, 128, 0, stream>>>(eidx32, eflag);
  k_node_encode<<<2048, 256, 0, stream>>>(x, atom_tab, nf, hidA);
  k_bond_fts<<<256, 256, 0, stream>>>(bond_tab, bf);
  k_scatter_win<<<256, 256, 0, stream>>>(eidx32, eflag, win);
  k_dcount<<<2048, 256, 0, stream>>>(win, dcnt);
  k_dscan<<<1, 512, 0, stream>>>(dcnt, rowptr);
  k_dfill<<<2048, 256, 0, stream>>>(win, eattr, rowptr, recs);
  k_wprep<<<256, 256, 0, stream>>>(W_h1, W_h2, wt);
  k_wprep_o<<<dim3(192, 2), 256, 0, stream>>>(W_o1, W_o2, wo);   // win dead now
  k_wprep_m<<<512, 256, 0, stream>>>(W_m1, W_m2, wm);

  float* hc = hidA;
  float* hn = hidB;
  for (int l = 0; l < 2; ++l) {
    const ushort_t* wt1h = wt + ((l * 2 + 0) * 2 + 0) * 16384;
    const ushort_t* wt1l = wt + ((l * 2 + 0) * 2 + 1) * 16384;
    const ushort_t* wt2h = wt + ((l * 2 + 1) * 2 + 0) * 16384;
    const ushort_t* wt2l = wt + ((l * 2 + 1) * 2 + 1) * 16384;
    const ushort_t* wo_h = wo + (l * 2 + 0) * 49152;
    const ushort_t* wo_l = wo + (l * 2 + 1) * 49152;
    k_me<<<256, 256, 0, stream>>>(bf, W_me + l * Hh * Hh, b_me + l * Hh,
                                  b_mg + l * Hh, me);
    k_m12<<<256, 64, 0, stream>>>(nf, hc, wm + l * 131072, b_m1 + l * Hh,
                                  b_m2 + l * Hh, m1, m2);
    k_edge<<<1024, 256, 0, stream>>>(recs, rowptr, m1, m2, me, wt1h, wt1l, wt2h, wt2l,
                                     b_h1 + l * Hh, b_h2 + l * Hh, agg);
    k_out<<<256, 64, 0, stream>>>(nf, hc, agg, wo_h, wo_l,
                                  b_o1 + l * Hh, b_o2 + l * Hh, hn);
    float* t = hc; hc = hn; hn = t;
  }
  k_head<<<32, 128, 0, stream>>>(hc, Wg1, bg1, Wg2, bg2, out);
}

// Round 9
// 392.093 us; speedup vs baseline: 1.1365x; 1.1365x over previous
//
#include <hip/hip_runtime.h>

#define Gg   32
#define Nn   128
#define Hh   128
#define Ee   65536
#define GN   4096      // Gg*Nn
#define GNN  524288    // Gg*Nn*Nn

typedef unsigned short ushort_t;
typedef __attribute__((ext_vector_type(8))) __bf16 bf16x8;
typedef __attribute__((ext_vector_type(4))) float f32x4;
struct us4 { ushort_t a, b, c, d; };

__device__ __forceinline__ float reluf(float x) { return x > 0.f ? x : 0.f; }

// round-to-nearest-even f32 -> bf16 bits
__device__ __forceinline__ ushort_t bfh(float x) {
  unsigned u = __float_as_uint(x);
  return (ushort_t)((u + 0x7FFFu + ((u >> 16) & 1u)) >> 16);
}
__device__ __forceinline__ void split2(float x, ushort_t& h, ushort_t& l) {
  h = bfh(x);
  float hf = __uint_as_float(((unsigned)h) << 16);
  l = bfh(x - hf);
}

// ---------------- edge_index layout detection ----------------
__global__ __launch_bounds__(128) void k_detect(const int* __restrict__ e32,
                                                int* __restrict__ flag) {
  __shared__ int s;
  if (threadIdx.x == 0) s = 0;
  __syncthreads();
  if (e32[2 * threadIdx.x + 1] != 0) atomicOr(&s, 1);
  __syncthreads();
  if (threadIdx.x == 0) *flag = s;  // 1 => int32 layout, 0 => int64 layout
}

// ---------------- encoders ----------------
__global__ __launch_bounds__(256) void k_node_encode(const int* __restrict__ x,
                                                     const float* __restrict__ atom_tab,
                                                     float* __restrict__ nf,
                                                     float* __restrict__ hid) {
  int t = blockIdx.x * 256 + threadIdx.x;      // over GN*Hh
  int v = t >> 7, h = t & 127;
  float s = 0.f;
#pragma unroll
  for (int f = 0; f < 9; ++f) {
    int idx = x[v * 9 + f];
    s += atom_tab[(f * 119 + idx) * Hh + h];
  }
  nf[t] = s;
  hid[t] = 0.f;
}

__global__ __launch_bounds__(256) void k_bond_fts(const float* __restrict__ bond_tab,
                                                  float* __restrict__ bf) {
  int t = blockIdx.x * 256 + threadIdx.x;      // 512*128
  int c = t >> 7, h = t & 127;
  int a0 = c & 7, a1 = (c >> 3) & 7, a2 = (c >> 6) & 7;
  bf[t] = bond_tab[(0 * 8 + a0) * Hh + h] + bond_tab[(1 * 8 + a1) * Hh + h] +
          bond_tab[(2 * 8 + a2) * Hh + h];
}

// ---------------- edge winner: win indexed by (g, d, s); last edge wins ----------
__global__ __launch_bounds__(256) void k_scatter_win(const int* __restrict__ e32,
                                                     const int* __restrict__ flag,
                                                     int* __restrict__ win) {
  int e = blockIdx.x * 256 + threadIdx.x;
  int sg, dg;
  if (*flag) { sg = e32[e]; dg = e32[Ee + e]; }
  else       { sg = e32[2 * e]; dg = e32[2 * Ee + 2 * e]; }
  int g = sg / Nn;
  int s = sg % Nn;
  int d = dg % Nn;
  atomicMax(&win[(g * Nn + d) * Nn + s], e);   // destination-major
}

// ---------------- per-destination compaction: count / scan / fill ----------------
__global__ __launch_bounds__(256) void k_dcount(const int* __restrict__ win,
                                                int* __restrict__ dcnt) {
  int tid = threadIdx.x;
  int grp = tid >> 7, t = tid & 127;
  int dest = blockIdx.x * 2 + grp;
  bool valid = win[dest * 128 + t] >= 0;
  unsigned long long mask = __ballot(valid);
  __shared__ int cw[4];
  if ((tid & 63) == 0) cw[tid >> 6] = __popcll(mask);
  __syncthreads();
  if (t == 0) dcnt[dest] = cw[grp * 2] + cw[grp * 2 + 1];
}

__global__ __launch_bounds__(512) void k_dscan(const int* __restrict__ dcnt,
                                               int* __restrict__ rowptr) {
  int tid = threadIdx.x;            // 512 threads x 8 dests = 4096
  int c0, c1, c2, c3, c4, c5, c6, c7;
  int bi = tid * 8;
  c0 = dcnt[bi + 0]; c1 = dcnt[bi + 1]; c2 = dcnt[bi + 2]; c3 = dcnt[bi + 3];
  c4 = dcnt[bi + 4]; c5 = dcnt[bi + 5]; c6 = dcnt[bi + 6]; c7 = dcnt[bi + 7];
  int s = c0 + c1 + c2 + c3 + c4 + c5 + c6 + c7;
  int x = s;
#pragma unroll
  for (int off = 1; off < 64; off <<= 1) {
    int y = __shfl_up(x, off, 64);
    if ((tid & 63) >= off) x += y;
  }
  __shared__ int wsum[8], woff[8];
  if ((tid & 63) == 63) wsum[tid >> 6] = x;
  __syncthreads();
  if (tid == 0) {
    int a = 0;
#pragma unroll
    for (int i = 0; i < 8; ++i) { woff[i] = a; a += wsum[i]; }
  }
  __syncthreads();
  int base = x - s + woff[tid >> 6];
  rowptr[bi + 0] = base; base += c0;
  rowptr[bi + 1] = base; base += c1;
  rowptr[bi + 2] = base; base += c2;
  rowptr[bi + 3] = base; base += c3;
  rowptr[bi + 4] = base; base += c4;
  rowptr[bi + 5] = base; base += c5;
  rowptr[bi + 6] = base; base += c6;
  rowptr[bi + 7] = base; base += c7;
  if (tid == 511) rowptr[4096] = base;
}

__global__ __launch_bounds__(256) void k_dfill(const int* __restrict__ win,
                                               const int* __restrict__ eattr,
                                               const int* __restrict__ rowptr,
                                               unsigned* __restrict__ recs) {
  int tid = threadIdx.x;
  int grp = tid >> 7, t = tid & 127;
  int dest = blockIdx.x * 2 + grp;
  int e = win[dest * 128 + t];
  bool valid = e >= 0;
  unsigned long long mask = __ballot(valid);
  __shared__ int cw[4];
  int lane = tid & 63;
  if (lane == 0) cw[tid >> 6] = __popcll(mask);
  __syncthreads();
  if (valid) {
    int off = __popcll(mask & ((1ull << lane) - 1));
    if ((tid >> 6) & 1) off += cw[grp * 2];
    int a0 = eattr[e * 3 + 0], a1 = eattr[e * 3 + 1], a2 = eattr[e * 3 + 2];
    unsigned code = (unsigned)(a0 + (a1 << 3) + (a2 << 6));
    recs[rowptr[dest] + off] = ((unsigned)t << 9) | code;   // s = t, sorted by dest
  }
}

// ---------------- weight prep: W_h1/W_h2 -> transposed hi/lo bf16 ----------------
// wt layout: [layer(2)][mat(2)][part(2)][n(128)][k(128)] ushort
__global__ __launch_bounds__(256) void k_wprep(const float* __restrict__ W_h1,
                                               const float* __restrict__ W_h2,
                                               ushort_t* __restrict__ wt) {
  int t = blockIdx.x * 256 + threadIdx.x;      // 2*2*16384
  int l = t >> 15;
  int m = (t >> 14) & 1;
  int e = t & 16383;
  int n = e & 127, k = e >> 7;
  const float* W = (m == 0 ? W_h1 : W_h2) + l * 16384;
  float v = W[k * 128 + n];
  ushort_t h, lo;
  split2(v, h, lo);
  int base = ((l * 2 + m) * 2) * 16384;
  wt[base + n * 128 + k] = h;
  wt[base + 16384 + n * 128 + k] = lo;
}

// ---------------- weight prep: [Wo1;Wo2] -> transposed hi/lo bf16 ----------------
// wo layout: [layer(2)][part(2)][n(128)][k(384)] ushort; grid (192, 2)
__global__ __launch_bounds__(256) void k_wprep_o(const float* __restrict__ W_o1,
                                                 const float* __restrict__ W_o2,
                                                 ushort_t* __restrict__ wo) {
  int e = blockIdx.x * 256 + threadIdx.x;      // 0 .. 49151  (= n*384 + k)
  int l = blockIdx.y;
  int n = e / 384, k = e - n * 384;
  float v = (k < 256) ? W_o1[(l * 256 + k) * 128 + n]
                      : W_o2[(l * 128 + (k - 256)) * 128 + n];
  ushort_t h, lo;
  split2(v, h, lo);
  wo[((l * 2 + 0) * 128 + n) * 384 + k] = h;
  wo[((l * 2 + 1) * 128 + n) * 384 + k] = lo;
}

// ---------------- weight prep: W_m1/W_m2 -> transposed hi/lo bf16 ----------------
// wm layout: [layer(2)][mat(2)][part(2)][n(128)][k(256)] ushort
__global__ __launch_bounds__(256) void k_wprep_m(const float* __restrict__ W_m1,
                                                 const float* __restrict__ W_m2,
                                                 ushort_t* __restrict__ wm) {
  int t = blockIdx.x * 256 + threadIdx.x;      // 131072 = 2l*2m*32768
  int l = t >> 16;
  int m = (t >> 15) & 1;
  int e = t & 32767;                           // n*256 + k
  int n = e >> 8, k = e & 255;
  const float* W = (m == 0 ? W_m1 : W_m2);
  float v = W[(l * 256 + k) * 128 + n];
  ushort_t h, lo;
  split2(v, h, lo);
  int base = ((l * 2 + m) * 2) * 32768;
  wm[base + n * 256 + k] = h;
  wm[base + 32768 + n * 256 + k] = lo;
}

// ---------------- me table ----------------
__global__ __launch_bounds__(256) void k_me(const float* __restrict__ bf,
                                            const float* __restrict__ W_me,
                                            const float* __restrict__ b_me,
                                            const float* __restrict__ b_mg,
                                            float* __restrict__ me) {
  __shared__ float v[2][128];
  int tid = threadIdx.x;
  int half = tid >> 7, j = tid & 127;
  int c = blockIdx.x * 2 + half;
  v[half][j] = bf[c * 128 + j];
  __syncthreads();
  float acc = b_me[j] + b_mg[j];
  for (int i = 0; i < 128; ++i) acc += v[half][i] * W_me[i * 128 + j];
  me[c * 128 + j] = acc;
}

// ---------------- m1,m2 = [nf|hid] @ W_m1 / W_m2 via MFMA ----------------
__global__ __launch_bounds__(64) void k_m12(const float* __restrict__ nf_,
                                            const float* __restrict__ hid,
                                            const ushort_t* __restrict__ wm,
                                            const float* __restrict__ bi1,
                                            const float* __restrict__ bi2,
                                            float* __restrict__ m1,
                                            float* __restrict__ m2) {
  __shared__ ushort_t AH[16][264];
  __shared__ ushort_t AL[16][264];
  int tid = threadIdx.x;              // one wave
  int v0 = blockIdx.x * 16;
#pragma unroll
  for (int i = 0; i < 16; ++i) {
    int idx = tid + i * 64;           // 16 rows x 64 float4
    int row = idx >> 6, c4 = idx & 63;
    float4 v = (c4 < 32) ? ((const float4*)nf_)[(v0 + row) * 32 + c4]
                         : ((const float4*)hid)[(v0 + row) * 32 + (c4 - 32)];
    us4 h4, l4;
    split2(v.x, h4.a, l4.a); split2(v.y, h4.b, l4.b);
    split2(v.z, h4.c, l4.c); split2(v.w, h4.d, l4.d);
    *(us4*)&AH[row][c4 * 4] = h4;
    *(us4*)&AL[row][c4 * 4] = l4;
  }
  __syncthreads();
  int lr = tid & 15, lg = tid >> 4;
  f32x4 a1[8], a2[8];
#pragma unroll
  for (int i = 0; i < 8; ++i) { a1[i] = (f32x4){0.f,0.f,0.f,0.f}; a2[i] = (f32x4){0.f,0.f,0.f,0.f}; }
  const ushort_t* w1h = wm;
  const ushort_t* w1l = wm + 32768;
  const ushort_t* w2h = wm + 65536;
  const ushort_t* w2l = wm + 98304;
#pragma unroll
  for (int seg = 0; seg < 2; ++seg) {
    bf16x8 ah[4], al[4];
#pragma unroll
    for (int kf = 0; kf < 4; ++kf) {
      ah[kf] = *(const bf16x8*)&AH[lr][seg * 128 + lg * 8 + 32 * kf];
      al[kf] = *(const bf16x8*)&AL[lr][seg * 128 + lg * 8 + 32 * kf];
    }
#pragma unroll
    for (int nfr = 0; nfr < 8; ++nfr) {
      const ushort_t* p1h = w1h + (16 * nfr + lr) * 256 + seg * 128 + lg * 8;
      const ushort_t* p1l = w1l + (16 * nfr + lr) * 256 + seg * 128 + lg * 8;
      const ushort_t* p2h = w2h + (16 * nfr + lr) * 256 + seg * 128 + lg * 8;
      const ushort_t* p2l = w2l + (16 * nfr + lr) * 256 + seg * 128 + lg * 8;
#pragma unroll
      for (int kf = 0; kf < 4; ++kf) {
        bf16x8 b1h = *(const bf16x8*)(p1h + 32 * kf);
        bf16x8 b1l = *(const bf16x8*)(p1l + 32 * kf);
        bf16x8 b2h = *(const bf16x8*)(p2h + 32 * kf);
        bf16x8 b2l = *(const bf16x8*)(p2l + 32 * kf);
        a1[nfr] = __builtin_amdgcn_mfma_f32_16x16x32_bf16(ah[kf], b1h, a1[nfr], 0, 0, 0);
        a1[nfr] = __builtin_amdgcn_mfma_f32_16x16x32_bf16(ah[kf], b1l, a1[nfr], 0, 0, 0);
        a1[nfr] = __builtin_amdgcn_mfma_f32_16x16x32_bf16(al[kf], b1h, a1[nfr], 0, 0, 0);
        a2[nfr] = __builtin_amdgcn_mfma_f32_16x16x32_bf16(ah[kf], b2h, a2[nfr], 0, 0, 0);
        a2[nfr] = __builtin_amdgcn_mfma_f32_16x16x32_bf16(ah[kf], b2l, a2[nfr], 0, 0, 0);
        a2[nfr] = __builtin_amdgcn_mfma_f32_16x16x32_bf16(al[kf], b2h, a2[nfr], 0, 0, 0);
      }
    }
  }
#pragma unroll
  for (int nfr = 0; nfr < 8; ++nfr) {
    int col = 16 * nfr + lr;
    float bb1 = bi1[col], bb2 = bi2[col];
#pragma unroll
    for (int reg = 0; reg < 4; ++reg) {
      int row = v0 + lg * 4 + reg;
      m1[row * Hh + col] = a1[nfr][reg] + bb1;
      m2[row * Hh + col] = a2[nfr][reg] + bb2;
    }
  }
}

// ---------------- MFMA helpers ----------------
__device__ __forceinline__ void load_afrag(const ushort_t (*MH)[136],
                                           const ushort_t (*ML)[136],
                                           int row, int lg,
                                           bf16x8 ah[4], bf16x8 al[4]) {
#pragma unroll
  for (int kf = 0; kf < 4; ++kf) {
    ah[kf] = *(const bf16x8*)&MH[row][lg * 8 + 32 * kf];
    al[kf] = *(const bf16x8*)&ML[row][lg * 8 + 32 * kf];
  }
}

__device__ __forceinline__ void wave_gemm(const ushort_t* __restrict__ wth,
                                          const ushort_t* __restrict__ wtl,
                                          const bf16x8 ah[4], const bf16x8 al[4],
                                          int lr, int lg, f32x4 acc[8]) {
#pragma unroll
  for (int nf = 0; nf < 8; ++nf) {
    acc[nf] = (f32x4){0.f, 0.f, 0.f, 0.f};
    const ushort_t* bh_base = wth + (16 * nf + lr) * 128 + lg * 8;
    const ushort_t* bl_base = wtl + (16 * nf + lr) * 128 + lg * 8;
#pragma unroll
    for (int kf = 0; kf < 4; ++kf) {
      bf16x8 bh = *(const bf16x8*)(bh_base + 32 * kf);
      bf16x8 bl = *(const bf16x8*)(bl_base + 32 * kf);
      acc[nf] = __builtin_amdgcn_mfma_f32_16x16x32_bf16(ah[kf], bh, acc[nf], 0, 0, 0);
      acc[nf] = __builtin_amdgcn_mfma_f32_16x16x32_bf16(ah[kf], bl, acc[nf], 0, 0, 0);
      acc[nf] = __builtin_amdgcn_mfma_f32_16x16x32_bf16(al[kf], bh, acc[nf], 0, 0, 0);
    }
  }
}

// ---------------- edge phase: dest-partitioned, atomic-free ----------------
// block b owns dests [4b, 4b+4); edges sorted by dest in recs
__global__ __launch_bounds__(256) void k_edge(const unsigned* __restrict__ recs,
                                              const int* __restrict__ rowptr,
                                              const float* __restrict__ m1,
                                              const float* __restrict__ m2,
                                              const float* __restrict__ me,
                                              const ushort_t* __restrict__ wt1h,
                                              const ushort_t* __restrict__ wt1l,
                                              const ushort_t* __restrict__ wt2h,
                                              const ushort_t* __restrict__ wt2l,
                                              const float* __restrict__ b_h1,
                                              const float* __restrict__ b_h2,
                                              float* __restrict__ agg) {
  __shared__ ushort_t MH[64][136];
  __shared__ ushort_t ML[64][136];
  __shared__ unsigned srow[64];
  __shared__ float sm1[4][128];
  __shared__ int sdest[5];
  int tid = threadIdx.x;
  int D = blockIdx.x * 4;
  int g = D >> 7;
  if (tid < 5) sdest[tid] = rowptr[D + tid];
  {
    int i0 = tid, i1 = tid + 256;   // stage m1 rows of this block's 4 dests
    sm1[i0 >> 7][i0 & 127] = m1[(D + (i0 >> 7)) * 128 + (i0 & 127)];
    sm1[i1 >> 7][i1 & 127] = m1[(D + (i1 >> 7)) * 128 + (i1 & 127)];
  }
  __syncthreads();
  int start = sdest[0], end = sdest[4];
  int rp1 = sdest[1], rp2 = sdest[2], rp3 = sdest[3];
  int nrows = end - start;

  int lane = tid & 63, wid = tid >> 6;
  int lr = lane & 15, lg = lane >> 4;
  float b1v[8], b2v[8];
#pragma unroll
  for (int nf = 0; nf < 8; ++nf) {
    b1v[nf] = b_h1[16 * nf + lr];
    b2v[nf] = b_h2[16 * nf + lr];
  }
  // scan-thread assignment: col c, dest pair kp
  int c = tid & 127, kp = tid >> 7;
  int d0 = 2 * kp, d1 = 2 * kp + 1;
  int l0s = sdest[d0] - start, l0e = sdest[d0 + 1] - start;
  int l1s = sdest[d1] - start, l1e = sdest[d1 + 1] - start;
  float mx0 = -1.0e9f, mx1 = -1.0e9f;

  for (int base = 0; base < nrows; base += 64) {
    // compiler fence: forbid hoisting loop-invariant weight loads out of the
    // pass loop (R7/R8: LICM kept 64 B-fragments live -> VGPR 256 + spills)
    asm volatile("" ::: "memory");
    // row records for this pass
    if (tid < 64) {
      int ridx = start + base + tid;
      unsigned v = 0xFFFFFFFFu;
      if (ridx < end) {
        unsigned rec = recs[ridx];                       // (s<<9)|code
        int dl = (ridx >= rp1) + (ridx >= rp2) + (ridx >= rp3);
        v = ((unsigned)dl << 16) | rec;
      }
      srow[tid] = v;
    }
    __syncthreads();
    // M build (float4-vectorized)
    {
      int c4 = tid & 31, r8 = tid >> 5;
#pragma unroll
      for (int i = 0; i < 8; ++i) {
        int r = r8 + 8 * i;
        float4 v = make_float4(0.f, 0.f, 0.f, 0.f);
        unsigned rec = srow[r];
        if (rec != 0xFFFFFFFFu) {
          int code = rec & 511, s = (rec >> 9) & 127, dl = rec >> 16;
          float4 a = *(const float4*)(m2 + (((g << 7) + s) << 7) + c4 * 4);
          float4 bb = *(const float4*)(me + (code << 7) + c4 * 4);
          float4 mm = *(const float4*)(&sm1[dl][c4 * 4]);
          v.x = reluf(mm.x + a.x + bb.x);
          v.y = reluf(mm.y + a.y + bb.y);
          v.z = reluf(mm.z + a.z + bb.z);
          v.w = reluf(mm.w + a.w + bb.w);
        }
        us4 h4, l4;
        split2(v.x, h4.a, l4.a); split2(v.y, h4.b, l4.b);
        split2(v.z, h4.c, l4.c); split2(v.w, h4.d, l4.d);
        *(us4*)&MH[r][c4 * 4] = h4;
        *(us4*)&ML[r][c4 * 4] = l4;
      }
    }
    __syncthreads();
    // GEMM1
    int arow = 16 * wid + lr;
    bf16x8 ah[4], al[4];
    load_afrag(MH, ML, arow, lg, ah, al);
    f32x4 acc[8];
    wave_gemm(wt1h, wt1l, ah, al, lr, lg, acc);
    // T = relu(acc + b1) -> wave-private rows
#pragma unroll
    for (int nf = 0; nf < 8; ++nf)
#pragma unroll
      for (int reg = 0; reg < 4; ++reg) {
        float t = reluf(acc[nf][reg] + b1v[nf]);
        int row = 16 * wid + lg * 4 + reg;
        int col = 16 * nf + lr;
        ushort_t h, l;
        split2(t, h, l);
        MH[row][col] = h;
        ML[row][col] = l;
      }
    __syncthreads();
    load_afrag(MH, ML, arow, lg, ah, al);
    wave_gemm(wt2h, wt2l, ah, al, lr, lg, acc);
    // park f32 bits (wave-private rows)
#pragma unroll
    for (int nf = 0; nf < 8; ++nf)
#pragma unroll
      for (int reg = 0; reg < 4; ++reg) {
        int row = 16 * wid + lg * 4 + reg;
        int col = 16 * nf + lr;
        unsigned b = __float_as_uint(acc[nf][reg] + b2v[nf]);
        MH[row][col] = (ushort_t)(b >> 16);
        ML[row][col] = (ushort_t)(b & 0xFFFFu);
      }
    __syncthreads();
    // local column-max per dest (no atomics)
    {
      int blo = base, bhi = base + 64;
      int f0 = l0s > blo ? l0s : blo, t0 = l0e < bhi ? l0e : bhi;
      for (int r = f0; r < t0; ++r) {
        unsigned b = ((unsigned)MH[r - base][c] << 16) | (unsigned)ML[r - base][c];
        mx0 = fmaxf(mx0, __uint_as_float(b));
      }
      int f1 = l1s > blo ? l1s : blo, t1 = l1e < bhi ? l1e : bhi;
      for (int r = f1; r < t1; ++r) {
        unsigned b = ((unsigned)MH[r - base][c] << 16) | (unsigned)ML[r - base][c];
        mx1 = fmaxf(mx1, __uint_as_float(b));
      }
    }
    __syncthreads();   // before next pass overwrites MH/ML
  }
  agg[(D + d0) * 128 + c] = mx0;
  agg[(D + d1) * 128 + c] = mx1;
}

// ---------------- hid update: relu([nf|hid|agg] @ [Wo1;Wo2] + b) via MFMA --------
__global__ __launch_bounds__(64) void k_out(const float* __restrict__ nf,
                                            const float* __restrict__ hid,
                                            const float* __restrict__ agg,
                                            const ushort_t* __restrict__ wo_h,
                                            const ushort_t* __restrict__ wo_l,
                                            const float* __restrict__ bo1,
                                            const float* __restrict__ bo2,
                                            float* __restrict__ hidn) {
  __shared__ ushort_t MH[16][136];
  __shared__ ushort_t ML[16][136];
  int tid = threadIdx.x;              // one wave
  int v0 = blockIdx.x * 16;
  int lr = tid & 15, lg = tid >> 4;
  f32x4 acc[8];
#pragma unroll
  for (int nfr = 0; nfr < 8; ++nfr) acc[nfr] = (f32x4){0.f, 0.f, 0.f, 0.f};

  for (int seg = 0; seg < 3; ++seg) {
#pragma unroll
    for (int i = 0; i < 8; ++i) {
      int idx = tid + i * 64;         // over 512 float4s
      int row = idx >> 5, c4 = idx & 31;
      float4 v;
      if (seg == 0)      v = ((const float4*)nf)[(v0 + row) * 32 + c4];
      else if (seg == 1) v = ((const float4*)hid)[(v0 + row) * 32 + c4];
      else               v = ((const float4*)agg)[(v0 + row) * 32 + c4];
      us4 h4, l4;
      split2(v.x, h4.a, l4.a);
      split2(v.y, h4.b, l4.b);
      split2(v.z, h4.c, l4.c);
      split2(v.w, h4.d, l4.d);
      *(us4*)&MH[row][c4 * 4] = h4;
      *(us4*)&ML[row][c4 * 4] = l4;
    }
    __syncthreads();
    bf16x8 ah[4], al[4];
    load_afrag(MH, ML, lr, lg, ah, al);
#pragma unroll
    for (int nfr = 0; nfr < 8; ++nfr) {
      const ushort_t* bh_base = wo_h + (16 * nfr + lr) * 384 + seg * 128 + lg * 8;
      const ushort_t* bl_base = wo_l + (16 * nfr + lr) * 384 + seg * 128 + lg * 8;
#pragma unroll
      for (int kf = 0; kf < 4; ++kf) {
        bf16x8 bh = *(const bf16x8*)(bh_base + 32 * kf);
        bf16x8 bl = *(const bf16x8*)(bl_base + 32 * kf);
        acc[nfr] = __builtin_amdgcn_mfma_f32_16x16x32_bf16(ah[kf], bh, acc[nfr], 0, 0, 0);
        acc[nfr] = __builtin_amdgcn_mfma_f32_16x16x32_bf16(ah[kf], bl, acc[nfr], 0, 0, 0);
        acc[nfr] = __builtin_amdgcn_mfma_f32_16x16x32_bf16(al[kf], bh, acc[nfr], 0, 0, 0);
      }
    }
    __syncthreads();
  }
#pragma unroll
  for (int nfr = 0; nfr < 8; ++nfr) {
    int col = 16 * nfr + lr;
    float b = bo1[col] + bo2[col];
#pragma unroll
    for (int reg = 0; reg < 4; ++reg)
      hidn[(v0 + lg * 4 + reg) * Hh + col] = reluf(acc[nfr][reg] + b);
  }
}

// ---------------- readout head ----------------
__global__ __launch_bounds__(128) void k_head(const float* __restrict__ hid,
                                              const float* __restrict__ Wg1,
                                              const float* __restrict__ bg1,
                                              const float* __restrict__ Wg2,
                                              const float* __restrict__ bg2,
                                              float* __restrict__ out) {
  __shared__ float emb[Hh];
  __shared__ float tt[Hh];
  int g = blockIdx.x, j = threadIdx.x;
  float s = 0.f;
  for (int n = 0; n < Nn; ++n) s += hid[(g * Nn + n) * Hh + j];
  emb[j] = s * (1.f / Nn);
  __syncthreads();
  float a = bg1[j];
  for (int i = 0; i < Hh; ++i) a += emb[i] * Wg1[i * Hh + j];
  tt[j] = reluf(a);
  __syncthreads();
  if (j < 12) {
    float o = bg2[j];
    for (int i = 0; i < Hh; ++i) o += tt[i] * Wg2[i * 12 + j];
    out[g * 12 + j] = o;
  }
}

extern "C" void kernel_launch(void* const* d_in, const int* in_sizes, int n_in,
                              void* d_out, int out_size, void* d_ws, size_t ws_size,
                              hipStream_t stream) {
  const int* x = (const int*)d_in[0];
  const int* eidx32 = (const int*)d_in[1];
  const int* eattr = (const int*)d_in[2];
  const float* atom_tab = (const float*)d_in[4];
  const float* bond_tab = (const float*)d_in[5];
  const float* W_m1 = (const float*)d_in[6];
  const float* b_m1 = (const float*)d_in[7];
  const float* W_m2 = (const float*)d_in[8];
  const float* b_m2 = (const float*)d_in[9];
  const float* W_me = (const float*)d_in[10];
  const float* b_me = (const float*)d_in[11];
  const float* b_mg = (const float*)d_in[13];
  const float* W_h1 = (const float*)d_in[14];
  const float* b_h1 = (const float*)d_in[15];
  const float* W_h2 = (const float*)d_in[16];
  const float* b_h2 = (const float*)d_in[17];
  const float* W_o1 = (const float*)d_in[18];
  const float* b_o1 = (const float*)d_in[19];
  const float* W_o2 = (const float*)d_in[20];
  const float* b_o2 = (const float*)d_in[21];
  const float* Wg1 = (const float*)d_in[22];
  const float* bg1 = (const float*)d_in[23];
  const float* Wg2 = (const float*)d_in[24];
  const float* bg2 = (const float*)d_in[25];
  float* out = (float*)d_out;

  char* ws = (char*)d_ws;
  float* nf = (float*)(ws);                                 // 2MB
  float* hidA = (float*)(ws + (2u << 20));                  // 2MB
  float* hidB = (float*)(ws + (4u << 20));                  // 2MB
  float* m1 = (float*)(ws + (6u << 20));                    // 2MB
  float* m2 = (float*)(ws + (8u << 20));                    // 2MB
  float* agg = (float*)(ws + (10u << 20));                  // 2MB
  int* win = (int*)(ws + (12u << 20));                      // 2MB (dead after k_dfill)
  ushort_t* wo = (ushort_t*)(ws + (12u << 20));             // 384KB (overlays win)
  ushort_t* wm = (ushort_t*)(ws + (12u << 20) + 393216);    // 512KB (overlays win)
  ushort_t* wt = (ushort_t*)(ws + (14u << 20));             // 256KB
  float* bf = (float*)(ws + (14u << 20) + (256u << 10));    // 256KB
  float* me = (float*)(ws + (14u << 20) + (512u << 10));    // 256KB
  unsigned* recs = (unsigned*)(ws + (14u << 20) + (768u << 10));  // 256KB
  int* dcnt = (int*)(ws + (15u << 20));                     // 16KB
  int* rowptr = (int*)(ws + (15u << 20) + (16u << 10));     // ~16KB (4097)
  int* eflag = (int*)(ws + (15u << 20) + (48u << 10));      // 4B

  hipMemsetAsync(win, 0xFF, GNN * sizeof(int), stream);
  k_detect<<<1, 128, 0, stream>>>(eidx32, eflag);
  k_node_encode<<<2048, 256, 0, stream>>>(x, atom_tab, nf, hidA);
  k_bond_fts<<<256, 256, 0, stream>>>(bond_tab, bf);
  k_scatter_win<<<256, 256, 0, stream>>>(eidx32, eflag, win);
  k_dcount<<<2048, 256, 0, stream>>>(win, dcnt);
  k_dscan<<<1, 512, 0, stream>>>(dcnt, rowptr);
  k_dfill<<<2048, 256, 0, stream>>>(win, eattr, rowptr, recs);
  k_wprep<<<256, 256, 0, stream>>>(W_h1, W_h2, wt);
  k_wprep_o<<<dim3(192, 2), 256, 0, stream>>>(W_o1, W_o2, wo);   // win dead now
  k_wprep_m<<<512, 256, 0, stream>>>(W_m1, W_m2, wm);

  float* hc = hidA;
  float* hn = hidB;
  for (int l = 0; l < 2; ++l) {
    const ushort_t* wt1h = wt + ((l * 2 + 0) * 2 + 0) * 16384;
    const ushort_t* wt1l = wt + ((l * 2 + 0) * 2 + 1) * 16384;
    const ushort_t* wt2h = wt + ((l * 2 + 1) * 2 + 0) * 16384;
    const ushort_t* wt2l = wt + ((l * 2 + 1) * 2 + 1) * 16384;
    const ushort_t* wo_h = wo + (l * 2 + 0) * 49152;
    const ushort_t* wo_l = wo + (l * 2 + 1) * 49152;
    k_me<<<256, 256, 0, stream>>>(bf, W_me + l * Hh * Hh, b_me + l * Hh,
                                  b_mg + l * Hh, me);
    k_m12<<<256, 64, 0, stream>>>(nf, hc, wm + l * 131072, b_m1 + l * Hh,
                                  b_m2 + l * Hh, m1, m2);
    k_edge<<<1024, 256, 0, stream>>>(recs, rowptr, m1, m2, me, wt1h, wt1l, wt2h, wt2l,
                                     b_h1 + l * Hh, b_h2 + l * Hh, agg);
    k_out<<<256, 64, 0, stream>>>(nf, hc, agg, wo_h, wo_l,
                                  b_o1 + l * Hh, b_o2 + l * Hh, hn);
    float* t = hc; hc = hn; hn = t;
  }
  k_head<<<32, 128, 0, stream>>>(hc, Wg1, bg1, Wg2, bg2, out);
}

// Round 10
// 297.847 us; speedup vs baseline: 1.4961x; 1.3164x over previous
//
#include <hip/hip_runtime.h>

#define Gg   32
#define Nn   128
#define Hh   128
#define Ee   65536
#define GN   4096      // Gg*Nn
#define GNN  524288    // Gg*Nn*Nn

typedef unsigned short ushort_t;
typedef __attribute__((ext_vector_type(8))) __bf16 bf16x8;
typedef __attribute__((ext_vector_type(4))) float f32x4;
struct us4 { ushort_t a, b, c, d; };

__device__ __forceinline__ float reluf(float x) { return x > 0.f ? x : 0.f; }

// monotone float <-> u32 key (for atomicMax on floats incl. negatives)
__device__ __forceinline__ unsigned fkey(float f) {
  unsigned u = __float_as_uint(f);
  return (u & 0x80000000u) ? ~u : (u | 0x80000000u);
}
__device__ __forceinline__ float funkey(unsigned k) {
  unsigned u = (k & 0x80000000u) ? (k ^ 0x80000000u) : ~k;
  return __uint_as_float(u);
}

// round-to-nearest-even f32 -> bf16 bits
__device__ __forceinline__ ushort_t bfh(float x) {
  unsigned u = __float_as_uint(x);
  return (ushort_t)((u + 0x7FFFu + ((u >> 16) & 1u)) >> 16);
}
__device__ __forceinline__ void split2(float x, ushort_t& h, ushort_t& l) {
  h = bfh(x);
  float hf = __uint_as_float(((unsigned)h) << 16);
  l = bfh(x - hf);
}

// ---------------- edge_index layout detection ----------------
__global__ __launch_bounds__(128) void k_detect(const int* __restrict__ e32,
                                                int* __restrict__ flag) {
  __shared__ int s;
  if (threadIdx.x == 0) s = 0;
  __syncthreads();
  if (e32[2 * threadIdx.x + 1] != 0) atomicOr(&s, 1);
  __syncthreads();
  if (threadIdx.x == 0) *flag = s;  // 1 => int32 layout, 0 => int64 layout
}

// ---------------- encoders ----------------
__global__ __launch_bounds__(256) void k_node_encode(const int* __restrict__ x,
                                                     const float* __restrict__ atom_tab,
                                                     float* __restrict__ nf,
                                                     float* __restrict__ hid) {
  int t = blockIdx.x * 256 + threadIdx.x;      // over GN*Hh
  int v = t >> 7, h = t & 127;
  float s = 0.f;
#pragma unroll
  for (int f = 0; f < 9; ++f) {
    int idx = x[v * 9 + f];
    s += atom_tab[(f * 119 + idx) * Hh + h];
  }
  nf[t] = s;
  hid[t] = 0.f;
}

__global__ __launch_bounds__(256) void k_bond_fts(const float* __restrict__ bond_tab,
                                                  float* __restrict__ bf) {
  int t = blockIdx.x * 256 + threadIdx.x;      // 512*128
  int c = t >> 7, h = t & 127;
  int a0 = c & 7, a1 = (c >> 3) & 7, a2 = (c >> 6) & 7;
  bf[t] = bond_tab[(0 * 8 + a0) * Hh + h] + bond_tab[(1 * 8 + a1) * Hh + h] +
          bond_tab[(2 * 8 + a2) * Hh + h];
}

// ---------------- edge winner: win indexed by (g, d, s); last edge wins ----------
__global__ __launch_bounds__(256) void k_scatter_win(const int* __restrict__ e32,
                                                     const int* __restrict__ flag,
                                                     int* __restrict__ win) {
  int e = blockIdx.x * 256 + threadIdx.x;
  int sg, dg;
  if (*flag) { sg = e32[e]; dg = e32[Ee + e]; }
  else       { sg = e32[2 * e]; dg = e32[2 * Ee + 2 * e]; }
  int g = sg / Nn;
  int s = sg % Nn;
  int d = dg % Nn;
  atomicMax(&win[(g * Nn + d) * Nn + s], e);   // destination-major
}

// ---------------- per-destination compaction: count / scan / fill ----------------
__global__ __launch_bounds__(256) void k_dcount(const int* __restrict__ win,
                                                int* __restrict__ dcnt) {
  int tid = threadIdx.x;
  int grp = tid >> 7, t = tid & 127;
  int dest = blockIdx.x * 2 + grp;
  bool valid = win[dest * 128 + t] >= 0;
  unsigned long long mask = __ballot(valid);
  __shared__ int cw[4];
  if ((tid & 63) == 0) cw[tid >> 6] = __popcll(mask);
  __syncthreads();
  if (t == 0) dcnt[dest] = cw[grp * 2] + cw[grp * 2 + 1];
}

__global__ __launch_bounds__(512) void k_dscan(const int* __restrict__ dcnt,
                                               int* __restrict__ rowptr) {
  int tid = threadIdx.x;            // 512 threads x 8 dests = 4096
  int c0, c1, c2, c3, c4, c5, c6, c7;
  int bi = tid * 8;
  c0 = dcnt[bi + 0]; c1 = dcnt[bi + 1]; c2 = dcnt[bi + 2]; c3 = dcnt[bi + 3];
  c4 = dcnt[bi + 4]; c5 = dcnt[bi + 5]; c6 = dcnt[bi + 6]; c7 = dcnt[bi + 7];
  int s = c0 + c1 + c2 + c3 + c4 + c5 + c6 + c7;
  int x = s;
#pragma unroll
  for (int off = 1; off < 64; off <<= 1) {
    int y = __shfl_up(x, off, 64);
    if ((tid & 63) >= off) x += y;
  }
  __shared__ int wsum[8], woff[8];
  if ((tid & 63) == 63) wsum[tid >> 6] = x;
  __syncthreads();
  if (tid == 0) {
    int a = 0;
#pragma unroll
    for (int i = 0; i < 8; ++i) { woff[i] = a; a += wsum[i]; }
  }
  __syncthreads();
  int base = x - s + woff[tid >> 6];
  rowptr[bi + 0] = base; base += c0;
  rowptr[bi + 1] = base; base += c1;
  rowptr[bi + 2] = base; base += c2;
  rowptr[bi + 3] = base; base += c3;
  rowptr[bi + 4] = base; base += c4;
  rowptr[bi + 5] = base; base += c5;
  rowptr[bi + 6] = base; base += c6;
  rowptr[bi + 7] = base; base += c7;
  if (tid == 511) rowptr[4096] = base;   // total count
}

__global__ __launch_bounds__(256) void k_dfill(const int* __restrict__ win,
                                               const int* __restrict__ eattr,
                                               const int* __restrict__ rowptr,
                                               unsigned* __restrict__ recs) {
  int tid = threadIdx.x;
  int grp = tid >> 7, t = tid & 127;
  int dest = blockIdx.x * 2 + grp;
  int e = win[dest * 128 + t];
  bool valid = e >= 0;
  unsigned long long mask = __ballot(valid);
  __shared__ int cw[4];
  int lane = tid & 63;
  if (lane == 0) cw[tid >> 6] = __popcll(mask);
  __syncthreads();
  if (valid) {
    int off = __popcll(mask & ((1ull << lane) - 1));
    if ((tid >> 6) & 1) off += cw[grp * 2];
    int a0 = eattr[e * 3 + 0], a1 = eattr[e * 3 + 1], a2 = eattr[e * 3 + 2];
    unsigned code = (unsigned)(a0 + (a1 << 3) + (a2 << 6));
    unsigned idx = ((unsigned)dest << 7) | (unsigned)t;   // (g*128+d)*128+s
    recs[rowptr[dest] + off] = (idx << 9) | code;         // sorted by dest
  }
}

// ---------------- weight prep: W_h1/W_h2 -> transposed hi/lo bf16 ----------------
// wt layout: [layer(2)][mat(2)][part(2)][n(128)][k(128)] ushort
__global__ __launch_bounds__(256) void k_wprep(const float* __restrict__ W_h1,
                                               const float* __restrict__ W_h2,
                                               ushort_t* __restrict__ wt) {
  int t = blockIdx.x * 256 + threadIdx.x;      // 2*2*16384
  int l = t >> 15;
  int m = (t >> 14) & 1;
  int e = t & 16383;
  int n = e & 127, k = e >> 7;
  const float* W = (m == 0 ? W_h1 : W_h2) + l * 16384;
  float v = W[k * 128 + n];
  ushort_t h, lo;
  split2(v, h, lo);
  int base = ((l * 2 + m) * 2) * 16384;
  wt[base + n * 128 + k] = h;
  wt[base + 16384 + n * 128 + k] = lo;
}

// ---------------- weight prep: [Wo1;Wo2] -> transposed hi/lo bf16 ----------------
// wo layout: [layer(2)][part(2)][n(128)][k(384)] ushort; grid (192, 2)
__global__ __launch_bounds__(256) void k_wprep_o(const float* __restrict__ W_o1,
                                                 const float* __restrict__ W_o2,
                                                 ushort_t* __restrict__ wo) {
  int e = blockIdx.x * 256 + threadIdx.x;      // 0 .. 49151  (= n*384 + k)
  int l = blockIdx.y;
  int n = e / 384, k = e - n * 384;
  float v = (k < 256) ? W_o1[(l * 256 + k) * 128 + n]
                      : W_o2[(l * 128 + (k - 256)) * 128 + n];
  ushort_t h, lo;
  split2(v, h, lo);
  wo[((l * 2 + 0) * 128 + n) * 384 + k] = h;
  wo[((l * 2 + 1) * 128 + n) * 384 + k] = lo;
}

// ---------------- weight prep: W_m1/W_m2 -> transposed hi/lo bf16 ----------------
// wm layout: [layer(2)][mat(2)][part(2)][n(128)][k(256)] ushort
__global__ __launch_bounds__(256) void k_wprep_m(const float* __restrict__ W_m1,
                                                 const float* __restrict__ W_m2,
                                                 ushort_t* __restrict__ wm) {
  int t = blockIdx.x * 256 + threadIdx.x;      // 131072 = 2l*2m*32768
  int l = t >> 16;
  int m = (t >> 15) & 1;
  int e = t & 32767;                           // n*256 + k
  int n = e >> 8, k = e & 255;
  const float* W = (m == 0 ? W_m1 : W_m2);
  float v = W[(l * 256 + k) * 128 + n];
  ushort_t h, lo;
  split2(v, h, lo);
  int base = ((l * 2 + m) * 2) * 32768;
  wm[base + n * 256 + k] = h;
  wm[base + 32768 + n * 256 + k] = lo;
}

// ---------------- me table + agg init (fused) ----------------
__global__ __launch_bounds__(256) void k_me_init(const float* __restrict__ bf,
                                                 const float* __restrict__ W_me,
                                                 const float* __restrict__ b_me,
                                                 const float* __restrict__ b_mg,
                                                 float* __restrict__ me,
                                                 unsigned* __restrict__ aggk) {
  __shared__ float v[2][128];
  int tid = threadIdx.x;
  int half = tid >> 7, j = tid & 127;
  int c = blockIdx.x * 2 + half;
  v[half][j] = bf[c * 128 + j];
  __syncthreads();
  float acc = b_me[j] + b_mg[j];
  for (int i = 0; i < 128; ++i) acc += v[half][i] * W_me[i * 128 + j];
  me[c * 128 + j] = acc;
  unsigned key = fkey(-1.0e9f);
#pragma unroll
  for (int i = 0; i < 8; ++i) aggk[blockIdx.x * 2048 + i * 256 + tid] = key;
}

// ---------------- m1,m2 = [nf|hid] @ W_m1 / W_m2 via MFMA ----------------
__global__ __launch_bounds__(64) void k_m12(const float* __restrict__ nf_,
                                            const float* __restrict__ hid,
                                            const ushort_t* __restrict__ wm,
                                            const float* __restrict__ bi1,
                                            const float* __restrict__ bi2,
                                            float* __restrict__ m1,
                                            float* __restrict__ m2) {
  __shared__ ushort_t AH[16][264];
  __shared__ ushort_t AL[16][264];
  int tid = threadIdx.x;              // one wave
  int v0 = blockIdx.x * 16;
#pragma unroll
  for (int i = 0; i < 16; ++i) {
    int idx = tid + i * 64;           // 16 rows x 64 float4
    int row = idx >> 6, c4 = idx & 63;
    float4 v = (c4 < 32) ? ((const float4*)nf_)[(v0 + row) * 32 + c4]
                         : ((const float4*)hid)[(v0 + row) * 32 + (c4 - 32)];
    us4 h4, l4;
    split2(v.x, h4.a, l4.a); split2(v.y, h4.b, l4.b);
    split2(v.z, h4.c, l4.c); split2(v.w, h4.d, l4.d);
    *(us4*)&AH[row][c4 * 4] = h4;
    *(us4*)&AL[row][c4 * 4] = l4;
  }
  __syncthreads();
  int lr = tid & 15, lg = tid >> 4;
  f32x4 a1[8], a2[8];
#pragma unroll
  for (int i = 0; i < 8; ++i) { a1[i] = (f32x4){0.f,0.f,0.f,0.f}; a2[i] = (f32x4){0.f,0.f,0.f,0.f}; }
  const ushort_t* w1h = wm;
  const ushort_t* w1l = wm + 32768;
  const ushort_t* w2h = wm + 65536;
  const ushort_t* w2l = wm + 98304;
#pragma unroll
  for (int seg = 0; seg < 2; ++seg) {
    bf16x8 ah[4], al[4];
#pragma unroll
    for (int kf = 0; kf < 4; ++kf) {
      ah[kf] = *(const bf16x8*)&AH[lr][seg * 128 + lg * 8 + 32 * kf];
      al[kf] = *(const bf16x8*)&AL[lr][seg * 128 + lg * 8 + 32 * kf];
    }
#pragma unroll
    for (int nfr = 0; nfr < 8; ++nfr) {
      const ushort_t* p1h = w1h + (16 * nfr + lr) * 256 + seg * 128 + lg * 8;
      const ushort_t* p1l = w1l + (16 * nfr + lr) * 256 + seg * 128 + lg * 8;
      const ushort_t* p2h = w2h + (16 * nfr + lr) * 256 + seg * 128 + lg * 8;
      const ushort_t* p2l = w2l + (16 * nfr + lr) * 256 + seg * 128 + lg * 8;
#pragma unroll
      for (int kf = 0; kf < 4; ++kf) {
        bf16x8 b1h = *(const bf16x8*)(p1h + 32 * kf);
        bf16x8 b1l = *(const bf16x8*)(p1l + 32 * kf);
        bf16x8 b2h = *(const bf16x8*)(p2h + 32 * kf);
        bf16x8 b2l = *(const bf16x8*)(p2l + 32 * kf);
        a1[nfr] = __builtin_amdgcn_mfma_f32_16x16x32_bf16(ah[kf], b1h, a1[nfr], 0, 0, 0);
        a1[nfr] = __builtin_amdgcn_mfma_f32_16x16x32_bf16(ah[kf], b1l, a1[nfr], 0, 0, 0);
        a1[nfr] = __builtin_amdgcn_mfma_f32_16x16x32_bf16(al[kf], b1h, a1[nfr], 0, 0, 0);
        a2[nfr] = __builtin_amdgcn_mfma_f32_16x16x32_bf16(ah[kf], b2h, a2[nfr], 0, 0, 0);
        a2[nfr] = __builtin_amdgcn_mfma_f32_16x16x32_bf16(ah[kf], b2l, a2[nfr], 0, 0, 0);
        a2[nfr] = __builtin_amdgcn_mfma_f32_16x16x32_bf16(al[kf], b2h, a2[nfr], 0, 0, 0);
      }
    }
  }
#pragma unroll
  for (int nfr = 0; nfr < 8; ++nfr) {
    int col = 16 * nfr + lr;
    float bb1 = bi1[col], bb2 = bi2[col];
#pragma unroll
    for (int reg = 0; reg < 4; ++reg) {
      int row = v0 + lg * 4 + reg;
      m1[row * Hh + col] = a1[nfr][reg] + bb1;
      m2[row * Hh + col] = a2[nfr][reg] + bb2;
    }
  }
}

// ---------------- MFMA helpers ----------------
__device__ __forceinline__ void load_afrag(const ushort_t (*MH)[136],
                                           const ushort_t (*ML)[136],
                                           int row, int lg,
                                           bf16x8 ah[4], bf16x8 al[4]) {
#pragma unroll
  for (int kf = 0; kf < 4; ++kf) {
    ah[kf] = *(const bf16x8*)&MH[row][lg * 8 + 32 * kf];
    al[kf] = *(const bf16x8*)&ML[row][lg * 8 + 32 * kf];
  }
}

__device__ __forceinline__ void wave_gemm(const ushort_t* __restrict__ wth,
                                          const ushort_t* __restrict__ wtl,
                                          const bf16x8 ah[4], const bf16x8 al[4],
                                          int lr, int lg, f32x4 acc[8]) {
#pragma unroll
  for (int nf = 0; nf < 8; ++nf) {
    acc[nf] = (f32x4){0.f, 0.f, 0.f, 0.f};
    const ushort_t* bh_base = wth + (16 * nf + lr) * 128 + lg * 8;
    const ushort_t* bl_base = wtl + (16 * nf + lr) * 128 + lg * 8;
#pragma unroll
    for (int kf = 0; kf < 4; ++kf) {
      bf16x8 bh = *(const bf16x8*)(bh_base + 32 * kf);
      bf16x8 bl = *(const bf16x8*)(bl_base + 32 * kf);
      acc[nf] = __builtin_amdgcn_mfma_f32_16x16x32_bf16(ah[kf], bh, acc[nf], 0, 0, 0);
      acc[nf] = __builtin_amdgcn_mfma_f32_16x16x32_bf16(ah[kf], bl, acc[nf], 0, 0, 0);
      acc[nf] = __builtin_amdgcn_mfma_f32_16x16x32_bf16(al[kf], bh, acc[nf], 0, 0, 0);
    }
  }
}

// ---------------- edge phase (R6-proven: flat 64-edge tile, MFMA bf16x3,
//                  run-dedup scatter with boundary atomics) ----------------
__global__ __launch_bounds__(256) void k_edge(const unsigned* __restrict__ recs,
                                              const int* __restrict__ cnt,
                                              const float* __restrict__ m1,
                                              const float* __restrict__ m2,
                                              const float* __restrict__ me,
                                              const ushort_t* __restrict__ wt1h,
                                              const ushort_t* __restrict__ wt1l,
                                              const ushort_t* __restrict__ wt2h,
                                              const ushort_t* __restrict__ wt2l,
                                              const float* __restrict__ b_h1,
                                              const float* __restrict__ b_h2,
                                              unsigned* __restrict__ aggk) {
  __shared__ ushort_t MH[64][136];
  __shared__ ushort_t ML[64][136];
  __shared__ unsigned srec[64];
  int tid = threadIdx.x;
  int n = *cnt;
  if (tid < 64) {
    int r = blockIdx.x * 64 + tid;
    srec[tid] = (r < n) ? recs[r] : 0xFFFFFFFFu;
  }
  __syncthreads();
  // build M tile (hi/lo bf16); rec idx = (g*128 + d)*128 + s
  {
    int c = tid & 127, rr = tid >> 7;
#pragma unroll
    for (int i = 0; i < 32; ++i) {
      int r = rr + i * 2;
      unsigned rec = srec[r];
      float v = 0.f;
      if (rec != 0xFFFFFFFFu) {
        int code = rec & 511;
        unsigned idx = rec >> 9;
        int s = idx & 127, d = (idx >> 7) & 127, g = idx >> 14;
        v = reluf(m1[((g << 7) + d) * Hh + c] + m2[((g << 7) + s) * Hh + c] +
                  me[code * Hh + c]);
      }
      ushort_t h, l;
      split2(v, h, l);
      MH[r][c] = h;
      ML[r][c] = l;
    }
  }
  __syncthreads();

  int lane = tid & 63, wid = tid >> 6;
  int lr = lane & 15, lg = lane >> 4;
  float b1v[8], b2v[8];
#pragma unroll
  for (int nf = 0; nf < 8; ++nf) {
    b1v[nf] = b_h1[16 * nf + lr];
    b2v[nf] = b_h2[16 * nf + lr];
  }
  int arow = 16 * wid + lr;
  bf16x8 ah[4], al[4];
  load_afrag(MH, ML, arow, lg, ah, al);
  f32x4 acc[8];
  wave_gemm(wt1h, wt1l, ah, al, lr, lg, acc);
  // T = relu(acc + b1) -> back into MH/ML (wave-private rows)
#pragma unroll
  for (int nf = 0; nf < 8; ++nf)
#pragma unroll
    for (int reg = 0; reg < 4; ++reg) {
      float t = reluf(acc[nf][reg] + b1v[nf]);
      int row = 16 * wid + lg * 4 + reg;
      int col = 16 * nf + lr;
      ushort_t h, l;
      split2(t, h, l);
      MH[row][col] = h;
      ML[row][col] = l;
    }
  __syncthreads();
  load_afrag(MH, ML, arow, lg, ah, al);
  wave_gemm(wt2h, wt2l, ah, al, lr, lg, acc);
  // park f32 result bits in MH/ML (wave-private rows)
#pragma unroll
  for (int nf = 0; nf < 8; ++nf)
#pragma unroll
    for (int reg = 0; reg < 4; ++reg) {
      int row = 16 * wid + lg * 4 + reg;
      int col = 16 * nf + lr;
      unsigned b = __float_as_uint(acc[nf][reg] + b2v[nf]);
      MH[row][col] = (ushort_t)(b >> 16);
      ML[row][col] = (ushort_t)(b & 0xFFFFu);
    }
  __syncthreads();
  // run-dedup scatter: rows sorted by (g,d) = rec>>16; one atomic per run per col
  {
    int c = tid & 127, half = tid >> 7;
    int rbeg = half * 32, rend = rbeg + 32;
    unsigned curkey = 0xFFFFu;
    float best = -3.0e38f;
    for (int r = rbeg; r < rend; ++r) {
      unsigned rec = srec[r];
      unsigned key = rec >> 16;   // g*128+d (<=0xFFF) or 0xFFFF if invalid
      if (key != curkey) {
        if (curkey != 0xFFFFu)
          atomicMax(aggk + (curkey << 7) + c, fkey(best));
        curkey = key;
        best = -3.0e38f;
      }
      if (key != 0xFFFFu) {
        unsigned b = ((unsigned)MH[r][c] << 16) | (unsigned)ML[r][c];
        best = fmaxf(best, __uint_as_float(b));
      }
    }
    if (curkey != 0xFFFFu)
      atomicMax(aggk + (curkey << 7) + c, fkey(best));
  }
}

// ---------------- hid update: relu([nf|hid|agg] @ [Wo1;Wo2] + b) via MFMA --------
__global__ __launch_bounds__(64) void k_out(const float* __restrict__ nf,
                                            const float* __restrict__ hid,
                                            const unsigned* __restrict__ aggk,
                                            const ushort_t* __restrict__ wo_h,
                                            const ushort_t* __restrict__ wo_l,
                                            const float* __restrict__ bo1,
                                            const float* __restrict__ bo2,
                                            float* __restrict__ hidn) {
  __shared__ ushort_t MH[16][136];
  __shared__ ushort_t ML[16][136];
  int tid = threadIdx.x;              // one wave
  int v0 = blockIdx.x * 16;
  int lr = tid & 15, lg = tid >> 4;
  f32x4 acc[8];
#pragma unroll
  for (int nfr = 0; nfr < 8; ++nfr) acc[nfr] = (f32x4){0.f, 0.f, 0.f, 0.f};

  for (int seg = 0; seg < 3; ++seg) {
#pragma unroll
    for (int i = 0; i < 8; ++i) {
      int idx = tid + i * 64;         // over 512 float4s
      int row = idx >> 5, c4 = idx & 31;
      float4 v;
      if (seg == 0)      v = ((const float4*)nf)[(v0 + row) * 32 + c4];
      else if (seg == 1) v = ((const float4*)hid)[(v0 + row) * 32 + c4];
      else {
        uint4 k4 = ((const uint4*)aggk)[(v0 + row) * 32 + c4];
        v.x = funkey(k4.x); v.y = funkey(k4.y); v.z = funkey(k4.z); v.w = funkey(k4.w);
      }
      us4 h4, l4;
      split2(v.x, h4.a, l4.a);
      split2(v.y, h4.b, l4.b);
      split2(v.z, h4.c, l4.c);
      split2(v.w, h4.d, l4.d);
      *(us4*)&MH[row][c4 * 4] = h4;
      *(us4*)&ML[row][c4 * 4] = l4;
    }
    __syncthreads();
    bf16x8 ah[4], al[4];
    load_afrag(MH, ML, lr, lg, ah, al);
#pragma unroll
    for (int nfr = 0; nfr < 8; ++nfr) {
      const ushort_t* bh_base = wo_h + (16 * nfr + lr) * 384 + seg * 128 + lg * 8;
      const ushort_t* bl_base = wo_l + (16 * nfr + lr) * 384 + seg * 128 + lg * 8;
#pragma unroll
      for (int kf = 0; kf < 4; ++kf) {
        bf16x8 bh = *(const bf16x8*)(bh_base + 32 * kf);
        bf16x8 bl = *(const bf16x8*)(bl_base + 32 * kf);
        acc[nfr] = __builtin_amdgcn_mfma_f32_16x16x32_bf16(ah[kf], bh, acc[nfr], 0, 0, 0);
        acc[nfr] = __builtin_amdgcn_mfma_f32_16x16x32_bf16(ah[kf], bl, acc[nfr], 0, 0, 0);
        acc[nfr] = __builtin_amdgcn_mfma_f32_16x16x32_bf16(al[kf], bh, acc[nfr], 0, 0, 0);
      }
    }
    __syncthreads();
  }
#pragma unroll
  for (int nfr = 0; nfr < 8; ++nfr) {
    int col = 16 * nfr + lr;
    float b = bo1[col] + bo2[col];
#pragma unroll
    for (int reg = 0; reg < 4; ++reg)
      hidn[(v0 + lg * 4 + reg) * Hh + col] = reluf(acc[nfr][reg] + b);
  }
}

// ---------------- readout head ----------------
__global__ __launch_bounds__(128) void k_head(const float* __restrict__ hid,
                                              const float* __restrict__ Wg1,
                                              const float* __restrict__ bg1,
                                              const float* __restrict__ Wg2,
                                              const float* __restrict__ bg2,
                                              float* __restrict__ out) {
  __shared__ float emb[Hh];
  __shared__ float tt[Hh];
  int g = blockIdx.x, j = threadIdx.x;
  float s = 0.f;
  for (int n = 0; n < Nn; ++n) s += hid[(g * Nn + n) * Hh + j];
  emb[j] = s * (1.f / Nn);
  __syncthreads();
  float a = bg1[j];
  for (int i = 0; i < Hh; ++i) a += emb[i] * Wg1[i * Hh + j];
  tt[j] = reluf(a);
  __syncthreads();
  if (j < 12) {
    float o = bg2[j];
    for (int i = 0; i < Hh; ++i) o += tt[i] * Wg2[i * 12 + j];
    out[g * 12 + j] = o;
  }
}

extern "C" void kernel_launch(void* const* d_in, const int* in_sizes, int n_in,
                              void* d_out, int out_size, void* d_ws, size_t ws_size,
                              hipStream_t stream) {
  const int* x = (const int*)d_in[0];
  const int* eidx32 = (const int*)d_in[1];
  const int* eattr = (const int*)d_in[2];
  const float* atom_tab = (const float*)d_in[4];
  const float* bond_tab = (const float*)d_in[5];
  const float* W_m1 = (const float*)d_in[6];
  const float* b_m1 = (const float*)d_in[7];
  const float* W_m2 = (const float*)d_in[8];
  const float* b_m2 = (const float*)d_in[9];
  const float* W_me = (const float*)d_in[10];
  const float* b_me = (const float*)d_in[11];
  const float* b_mg = (const float*)d_in[13];
  const float* W_h1 = (const float*)d_in[14];
  const float* b_h1 = (const float*)d_in[15];
  const float* W_h2 = (const float*)d_in[16];
  const float* b_h2 = (const float*)d_in[17];
  const float* W_o1 = (const float*)d_in[18];
  const float* b_o1 = (const float*)d_in[19];
  const float* W_o2 = (const float*)d_in[20];
  const float* b_o2 = (const float*)d_in[21];
  const float* Wg1 = (const float*)d_in[22];
  const float* bg1 = (const float*)d_in[23];
  const float* Wg2 = (const float*)d_in[24];
  const float* bg2 = (const float*)d_in[25];
  float* out = (float*)d_out;

  char* ws = (char*)d_ws;
  float* nf = (float*)(ws);                                 // 2MB
  float* hidA = (float*)(ws + (2u << 20));                  // 2MB
  float* hidB = (float*)(ws + (4u << 20));                  // 2MB
  float* m1 = (float*)(ws + (6u << 20));                    // 2MB
  float* m2 = (float*)(ws + (8u << 20));                    // 2MB
  unsigned* aggk = (unsigned*)(ws + (10u << 20));           // 2MB
  int* win = (int*)(ws + (12u << 20));                      // 2MB (dead after k_dfill)
  ushort_t* wo = (ushort_t*)(ws + (12u << 20));             // 384KB (overlays win)
  ushort_t* wm = (ushort_t*)(ws + (12u << 20) + 393216);    // 512KB (overlays win)
  ushort_t* wt = (ushort_t*)(ws + (14u << 20));             // 256KB
  float* bf = (float*)(ws + (14u << 20) + (256u << 10));    // 256KB
  float* me = (float*)(ws + (14u << 20) + (512u << 10));    // 256KB
  unsigned* recs = (unsigned*)(ws + (14u << 20) + (768u << 10));  // 256KB
  int* dcnt = (int*)(ws + (15u << 20));                     // 16KB
  int* rowptr = (int*)(ws + (15u << 20) + (16u << 10));     // ~16KB (4097)
  int* eflag = (int*)(ws + (15u << 20) + (48u << 10));      // 4B

  hipMemsetAsync(win, 0xFF, GNN * sizeof(int), stream);
  k_detect<<<1, 128, 0, stream>>>(eidx32, eflag);
  k_node_encode<<<2048, 256, 0, stream>>>(x, atom_tab, nf, hidA);
  k_bond_fts<<<256, 256, 0, stream>>>(bond_tab, bf);
  k_scatter_win<<<256, 256, 0, stream>>>(eidx32, eflag, win);
  k_dcount<<<2048, 256, 0, stream>>>(win, dcnt);
  k_dscan<<<1, 512, 0, stream>>>(dcnt, rowptr);
  k_dfill<<<2048, 256, 0, stream>>>(win, eattr, rowptr, recs);
  k_wprep<<<256, 256, 0, stream>>>(W_h1, W_h2, wt);
  k_wprep_o<<<dim3(192, 2), 256, 0, stream>>>(W_o1, W_o2, wo);   // win dead now
  k_wprep_m<<<512, 256, 0, stream>>>(W_m1, W_m2, wm);

  int* cnt = rowptr + 4096;   // total edge count written by k_dscan

  float* hc = hidA;
  float* hn = hidB;
  for (int l = 0; l < 2; ++l) {
    const ushort_t* wt1h = wt + ((l * 2 + 0) * 2 + 0) * 16384;
    const ushort_t* wt1l = wt + ((l * 2 + 0) * 2 + 1) * 16384;
    const ushort_t* wt2h = wt + ((l * 2 + 1) * 2 + 0) * 16384;
    const ushort_t* wt2l = wt + ((l * 2 + 1) * 2 + 1) * 16384;
    const ushort_t* wo_h = wo + (l * 2 + 0) * 49152;
    const ushort_t* wo_l = wo + (l * 2 + 1) * 49152;
    k_me_init<<<256, 256, 0, stream>>>(bf, W_me + l * Hh * Hh, b_me + l * Hh,
                                       b_mg + l * Hh, me, aggk);
    k_m12<<<256, 64, 0, stream>>>(nf, hc, wm + l * 131072, b_m1 + l * Hh,
                                  b_m2 + l * Hh, m1, m2);
    k_edge<<<1024, 256, 0, stream>>>(recs, cnt, m1, m2, me, wt1h, wt1l, wt2h, wt2l,
                                     b_h1 + l * Hh, b_h2 + l * Hh, aggk);
    k_out<<<256, 64, 0, stream>>>(nf, hc, aggk, wo_h, wo_l,
                                  b_o1 + l * Hh, b_o2 + l * Hh, hn);
    float* t = hc; hc = hn; hn = t;
  }
  k_head<<<32, 128, 0, stream>>>(hc, Wg1, bg1, Wg2, bg2, out);
}

// Round 11
// 182.674 us; speedup vs baseline: 2.4393x; 1.6305x over previous
//
#include <hip/hip_runtime.h>

#define Gg   32
#define Nn   128
#define Hh   128
#define Ee   65536
#define GN   4096      // Gg*Nn
#define GNN  524288    // Gg*Nn*Nn

typedef unsigned short ushort_t;
typedef __attribute__((ext_vector_type(8))) __bf16 bf16x8;
typedef __attribute__((ext_vector_type(4))) float f32x4;
struct us4 { ushort_t a, b, c, d; };

__device__ __forceinline__ float reluf(float x) { return x > 0.f ? x : 0.f; }

// monotone float <-> u32 key (for atomicMax on floats incl. negatives)
__device__ __forceinline__ unsigned fkey(float f) {
  unsigned u = __float_as_uint(f);
  return (u & 0x80000000u) ? ~u : (u | 0x80000000u);
}
__device__ __forceinline__ float funkey(unsigned k) {
  unsigned u = (k & 0x80000000u) ? (k ^ 0x80000000u) : ~k;
  return __uint_as_float(u);
}

// round-to-nearest-even f32 -> bf16 bits
__device__ __forceinline__ ushort_t bfh(float x) {
  unsigned u = __float_as_uint(x);
  return (ushort_t)((u + 0x7FFFu + ((u >> 16) & 1u)) >> 16);
}
__device__ __forceinline__ void split2(float x, ushort_t& h, ushort_t& l) {
  h = bfh(x);
  float hf = __uint_as_float(((unsigned)h) << 16);
  l = bfh(x - hf);
}

// ---------------- edge_index layout detection ----------------
__global__ __launch_bounds__(128) void k_detect(const int* __restrict__ e32,
                                                int* __restrict__ flag) {
  __shared__ int s;
  if (threadIdx.x == 0) s = 0;
  __syncthreads();
  if (e32[2 * threadIdx.x + 1] != 0) atomicOr(&s, 1);
  __syncthreads();
  if (threadIdx.x == 0) *flag = s;  // 1 => int32 layout, 0 => int64 layout
}

// ---------------- encoders ----------------
__global__ __launch_bounds__(256) void k_node_encode(const int* __restrict__ x,
                                                     const float* __restrict__ atom_tab,
                                                     float* __restrict__ nf,
                                                     float* __restrict__ hid) {
  int t = blockIdx.x * 256 + threadIdx.x;      // over GN*Hh
  int v = t >> 7, h = t & 127;
  float s = 0.f;
#pragma unroll
  for (int f = 0; f < 9; ++f) {
    int idx = x[v * 9 + f];
    s += atom_tab[(f * 119 + idx) * Hh + h];
  }
  nf[t] = s;
  hid[t] = 0.f;
}

__global__ __launch_bounds__(256) void k_bond_fts(const float* __restrict__ bond_tab,
                                                  float* __restrict__ bf) {
  int t = blockIdx.x * 256 + threadIdx.x;      // 512*128
  int c = t >> 7, h = t & 127;
  int a0 = c & 7, a1 = (c >> 3) & 7, a2 = (c >> 6) & 7;
  bf[t] = bond_tab[(0 * 8 + a0) * Hh + h] + bond_tab[(1 * 8 + a1) * Hh + h] +
          bond_tab[(2 * 8 + a2) * Hh + h];
}

// ---------------- edge winner: win indexed by (g, d, s); last edge wins ----------
__global__ __launch_bounds__(256) void k_scatter_win(const int* __restrict__ e32,
                                                     const int* __restrict__ flag,
                                                     int* __restrict__ win) {
  int e = blockIdx.x * 256 + threadIdx.x;
  int sg, dg;
  if (*flag) { sg = e32[e]; dg = e32[Ee + e]; }
  else       { sg = e32[2 * e]; dg = e32[2 * Ee + 2 * e]; }
  int g = sg / Nn;
  int s = sg % Nn;
  int d = dg % Nn;
  atomicMax(&win[(g * Nn + d) * Nn + s], e);   // destination-major
}

// ---------------- per-destination compaction: count / scan / fill ----------------
__global__ __launch_bounds__(256) void k_dcount(const int* __restrict__ win,
                                                int* __restrict__ dcnt) {
  int tid = threadIdx.x;
  int grp = tid >> 7, t = tid & 127;
  int dest = blockIdx.x * 2 + grp;
  bool valid = win[dest * 128 + t] >= 0;
  unsigned long long mask = __ballot(valid);
  __shared__ int cw[4];
  if ((tid & 63) == 0) cw[tid >> 6] = __popcll(mask);
  __syncthreads();
  if (t == 0) dcnt[dest] = cw[grp * 2] + cw[grp * 2 + 1];
}

__global__ __launch_bounds__(512) void k_dscan(const int* __restrict__ dcnt,
                                               int* __restrict__ rowptr) {
  int tid = threadIdx.x;            // 512 threads x 8 dests = 4096
  int c0, c1, c2, c3, c4, c5, c6, c7;
  int bi = tid * 8;
  c0 = dcnt[bi + 0]; c1 = dcnt[bi + 1]; c2 = dcnt[bi + 2]; c3 = dcnt[bi + 3];
  c4 = dcnt[bi + 4]; c5 = dcnt[bi + 5]; c6 = dcnt[bi + 6]; c7 = dcnt[bi + 7];
  int s = c0 + c1 + c2 + c3 + c4 + c5 + c6 + c7;
  int x = s;
#pragma unroll
  for (int off = 1; off < 64; off <<= 1) {
    int y = __shfl_up(x, off, 64);
    if ((tid & 63) >= off) x += y;
  }
  __shared__ int wsum[8], woff[8];
  if ((tid & 63) == 63) wsum[tid >> 6] = x;
  __syncthreads();
  if (tid == 0) {
    int a = 0;
#pragma unroll
    for (int i = 0; i < 8; ++i) { woff[i] = a; a += wsum[i]; }
  }
  __syncthreads();
  int base = x - s + woff[tid >> 6];
  rowptr[bi + 0] = base; base += c0;
  rowptr[bi + 1] = base; base += c1;
  rowptr[bi + 2] = base; base += c2;
  rowptr[bi + 3] = base; base += c3;
  rowptr[bi + 4] = base; base += c4;
  rowptr[bi + 5] = base; base += c5;
  rowptr[bi + 6] = base; base += c6;
  rowptr[bi + 7] = base; base += c7;
  if (tid == 511) rowptr[4096] = base;   // total count
}

__global__ __launch_bounds__(256) void k_dfill(const int* __restrict__ win,
                                               const int* __restrict__ eattr,
                                               const int* __restrict__ rowptr,
                                               unsigned* __restrict__ recs) {
  int tid = threadIdx.x;
  int grp = tid >> 7, t = tid & 127;
  int dest = blockIdx.x * 2 + grp;
  int e = win[dest * 128 + t];
  bool valid = e >= 0;
  unsigned long long mask = __ballot(valid);
  __shared__ int cw[4];
  int lane = tid & 63;
  if (lane == 0) cw[tid >> 6] = __popcll(mask);
  __syncthreads();
  if (valid) {
    int off = __popcll(mask & ((1ull << lane) - 1));
    if ((tid >> 6) & 1) off += cw[grp * 2];
    int a0 = eattr[e * 3 + 0], a1 = eattr[e * 3 + 1], a2 = eattr[e * 3 + 2];
    unsigned code = (unsigned)(a0 + (a1 << 3) + (a2 << 6));
    unsigned idx = ((unsigned)dest << 7) | (unsigned)t;   // (g*128+d)*128+s
    recs[rowptr[dest] + off] = (idx << 9) | code;         // sorted by dest
  }
}

// ---------------- weight prep: fragment-ordered layouts ----------------
// element (n,k): nf=n>>4, lr=n&15, kf=k>>5, lg=(k>>3)&3, j=k&7
// off = ((nf*KCH + kf)*64 + lg*16 + lr)*8 + j  -> one wave-load = 1KB contiguous

// wt: [layer(2)][mat(2)][part(2)] of 16384, KCH=4
__global__ __launch_bounds__(256) void k_wprep(const float* __restrict__ W_h1,
                                               const float* __restrict__ W_h2,
                                               ushort_t* __restrict__ wt) {
  int t = blockIdx.x * 256 + threadIdx.x;      // 2*2*16384
  int l = t >> 15;
  int m = (t >> 14) & 1;
  int e = t & 16383;
  int n = e & 127, k = e >> 7;
  const float* W = (m == 0 ? W_h1 : W_h2) + l * 16384;
  float v = W[k * 128 + n];
  ushort_t h, lo;
  split2(v, h, lo);
  int nf = n >> 4, lr = n & 15, kf = k >> 5, lg = (k >> 3) & 3, j = k & 7;
  int off = ((nf * 4 + kf) * 64 + lg * 16 + lr) * 8 + j;
  int base = ((l * 2 + m) * 2) * 16384;
  wt[base + off] = h;
  wt[base + 16384 + off] = lo;
}

// wo: [layer(2)][part(2)] of 49152, KCH=12; grid (192, 2)
__global__ __launch_bounds__(256) void k_wprep_o(const float* __restrict__ W_o1,
                                                 const float* __restrict__ W_o2,
                                                 ushort_t* __restrict__ wo) {
  int e = blockIdx.x * 256 + threadIdx.x;      // 0 .. 49151  (= n*384 + k)
  int l = blockIdx.y;
  int n = e / 384, k = e - n * 384;
  float v = (k < 256) ? W_o1[(l * 256 + k) * 128 + n]
                      : W_o2[(l * 128 + (k - 256)) * 128 + n];
  ushort_t h, lo;
  split2(v, h, lo);
  int nf = n >> 4, lr = n & 15, kf = k >> 5, lg = (k >> 3) & 3, j = k & 7;
  int off = ((nf * 12 + kf) * 64 + lg * 16 + lr) * 8 + j;
  wo[(l * 2 + 0) * 49152 + off] = h;
  wo[(l * 2 + 1) * 49152 + off] = lo;
}

// wm: [layer(2)][mat(2)][part(2)] of 32768, KCH=8
__global__ __launch_bounds__(256) void k_wprep_m(const float* __restrict__ W_m1,
                                                 const float* __restrict__ W_m2,
                                                 ushort_t* __restrict__ wm) {
  int t = blockIdx.x * 256 + threadIdx.x;      // 131072 = 2l*2m*32768
  int l = t >> 16;
  int m = (t >> 15) & 1;
  int e = t & 32767;                           // n*256 + k
  int n = e >> 8, k = e & 255;
  const float* W = (m == 0 ? W_m1 : W_m2);
  float v = W[(l * 256 + k) * 128 + n];
  ushort_t h, lo;
  split2(v, h, lo);
  int nf = n >> 4, lr = n & 15, kf = k >> 5, lg = (k >> 3) & 3, j = k & 7;
  int off = ((nf * 8 + kf) * 64 + lg * 16 + lr) * 8 + j;
  int base = ((l * 2 + m) * 2) * 32768;
  wm[base + off] = h;
  wm[base + 32768 + off] = lo;
}

// ---------------- me table + agg init (fused) ----------------
__global__ __launch_bounds__(256) void k_me_init(const float* __restrict__ bf,
                                                 const float* __restrict__ W_me,
                                                 const float* __restrict__ b_me,
                                                 const float* __restrict__ b_mg,
                                                 float* __restrict__ me,
                                                 unsigned* __restrict__ aggk) {
  __shared__ float v[2][128];
  int tid = threadIdx.x;
  int half = tid >> 7, j = tid & 127;
  int c = blockIdx.x * 2 + half;
  v[half][j] = bf[c * 128 + j];
  __syncthreads();
  float acc = b_me[j] + b_mg[j];
  for (int i = 0; i < 128; ++i) acc += v[half][i] * W_me[i * 128 + j];
  me[c * 128 + j] = acc;
  unsigned key = fkey(-1.0e9f);
#pragma unroll
  for (int i = 0; i < 8; ++i) aggk[blockIdx.x * 2048 + i * 256 + tid] = key;
}

// ---------------- m1,m2 = [nf|hid] @ W_m1 / W_m2 via MFMA (4 waves/block) -------
__global__ __launch_bounds__(256) void k_m12(const float* __restrict__ nf_,
                                             const float* __restrict__ hid,
                                             const ushort_t* __restrict__ wm,
                                             const float* __restrict__ bi1,
                                             const float* __restrict__ bi2,
                                             float* __restrict__ m1,
                                             float* __restrict__ m2) {
  __shared__ ushort_t AH[16][264];
  __shared__ ushort_t AL[16][264];
  int tid = threadIdx.x;
  int v0 = blockIdx.x * 16;
#pragma unroll
  for (int i = 0; i < 4; ++i) {
    int idx = tid + i * 256;          // 1024 float4s = 16 rows x 64
    int row = idx >> 6, c4 = idx & 63;
    float4 v = (c4 < 32) ? ((const float4*)nf_)[(v0 + row) * 32 + c4]
                         : ((const float4*)hid)[(v0 + row) * 32 + (c4 - 32)];
    us4 h4, l4;
    split2(v.x, h4.a, l4.a); split2(v.y, h4.b, l4.b);
    split2(v.z, h4.c, l4.c); split2(v.w, h4.d, l4.d);
    *(us4*)&AH[row][c4 * 4] = h4;
    *(us4*)&AL[row][c4 * 4] = l4;
  }
  __syncthreads();
  int lane = tid & 63, wid = tid >> 6;
  int lr = lane & 15, lg = lane >> 4;
  f32x4 a1[2], a2[2];
#pragma unroll
  for (int i = 0; i < 2; ++i) { a1[i] = (f32x4){0.f,0.f,0.f,0.f}; a2[i] = (f32x4){0.f,0.f,0.f,0.f}; }
  const ushort_t* w1h = wm;
  const ushort_t* w1l = wm + 32768;
  const ushort_t* w2h = wm + 65536;
  const ushort_t* w2l = wm + 98304;
#pragma unroll
  for (int seg = 0; seg < 2; ++seg) {
    bf16x8 ah[4], al[4];
#pragma unroll
    for (int kf = 0; kf < 4; ++kf) {
      ah[kf] = *(const bf16x8*)&AH[lr][seg * 128 + lg * 8 + 32 * kf];
      al[kf] = *(const bf16x8*)&AL[lr][seg * 128 + lg * 8 + 32 * kf];
    }
#pragma unroll
    for (int jj = 0; jj < 2; ++jj) {
      int nfr = 2 * wid + jj;
#pragma unroll
      for (int kf = 0; kf < 4; ++kf) {
        int ch = ((nfr * 8 + seg * 4 + kf) << 9) + lane * 8;
        bf16x8 b1h = *(const bf16x8*)(w1h + ch);
        bf16x8 b1l = *(const bf16x8*)(w1l + ch);
        bf16x8 b2h = *(const bf16x8*)(w2h + ch);
        bf16x8 b2l = *(const bf16x8*)(w2l + ch);
        a1[jj] = __builtin_amdgcn_mfma_f32_16x16x32_bf16(ah[kf], b1h, a1[jj], 0, 0, 0);
        a1[jj] = __builtin_amdgcn_mfma_f32_16x16x32_bf16(ah[kf], b1l, a1[jj], 0, 0, 0);
        a1[jj] = __builtin_amdgcn_mfma_f32_16x16x32_bf16(al[kf], b1h, a1[jj], 0, 0, 0);
        a2[jj] = __builtin_amdgcn_mfma_f32_16x16x32_bf16(ah[kf], b2h, a2[jj], 0, 0, 0);
        a2[jj] = __builtin_amdgcn_mfma_f32_16x16x32_bf16(ah[kf], b2l, a2[jj], 0, 0, 0);
        a2[jj] = __builtin_amdgcn_mfma_f32_16x16x32_bf16(al[kf], b2h, a2[jj], 0, 0, 0);
      }
    }
  }
#pragma unroll
  for (int jj = 0; jj < 2; ++jj) {
    int col = 16 * (2 * wid + jj) + lr;
    float bb1 = bi1[col], bb2 = bi2[col];
#pragma unroll
    for (int reg = 0; reg < 4; ++reg) {
      int row = v0 + lg * 4 + reg;
      m1[row * Hh + col] = a1[jj][reg] + bb1;
      m2[row * Hh + col] = a2[jj][reg] + bb2;
    }
  }
}

// ---------------- MFMA A-fragment helper ----------------
__device__ __forceinline__ void load_afrag(const ushort_t (*MH)[136],
                                           const ushort_t (*ML)[136],
                                           int row, int lg,
                                           bf16x8 ah[4], bf16x8 al[4]) {
#pragma unroll
  for (int kf = 0; kf < 4; ++kf) {
    ah[kf] = *(const bf16x8*)&MH[row][lg * 8 + 32 * kf];
    al[kf] = *(const bf16x8*)&ML[row][lg * 8 + 32 * kf];
  }
}

// ---------------- edge phase: 64-edge tile, nf-split waves, coalesced B ---------
__global__ __launch_bounds__(256) void k_edge(const unsigned* __restrict__ recs,
                                              const int* __restrict__ cnt,
                                              const float* __restrict__ m1,
                                              const float* __restrict__ m2,
                                              const float* __restrict__ me,
                                              const ushort_t* __restrict__ wt1h,
                                              const ushort_t* __restrict__ wt1l,
                                              const ushort_t* __restrict__ wt2h,
                                              const ushort_t* __restrict__ wt2l,
                                              const float* __restrict__ b_h1,
                                              const float* __restrict__ b_h2,
                                              unsigned* __restrict__ aggk) {
  __shared__ ushort_t MH[64][136];
  __shared__ ushort_t ML[64][136];
  __shared__ unsigned srec[64];
  int tid = threadIdx.x;
  int n = *cnt;
  if (tid < 64) {
    int r = blockIdx.x * 64 + tid;
    srec[tid] = (r < n) ? recs[r] : 0xFFFFFFFFu;
  }
  __syncthreads();
  // build M tile (hi/lo bf16); rec idx = (g*128 + d)*128 + s
  {
    int c = tid & 127, rr = tid >> 7;
#pragma unroll
    for (int i = 0; i < 32; ++i) {
      int r = rr + i * 2;
      unsigned rec = srec[r];
      float v = 0.f;
      if (rec != 0xFFFFFFFFu) {
        int code = rec & 511;
        unsigned idx = rec >> 9;
        int s = idx & 127, d = (idx >> 7) & 127, g = idx >> 14;
        v = reluf(m1[((g << 7) + d) * Hh + c] + m2[((g << 7) + s) * Hh + c] +
                  me[code * Hh + c]);
      }
      ushort_t h, l;
      split2(v, h, l);
      MH[r][c] = h;
      ML[r][c] = l;
    }
  }
  __syncthreads();

  int lane = tid & 63, wid = tid >> 6;
  int lr = lane & 15, lg = lane >> 4;
  float b1v[2], b2v[2];
#pragma unroll
  for (int jj = 0; jj < 2; ++jj) {
    b1v[jj] = b_h1[16 * (2 * wid + jj) + lr];
    b2v[jj] = b_h2[16 * (2 * wid + jj) + lr];
  }
  f32x4 acc[4][2];
#pragma unroll
  for (int rg = 0; rg < 4; ++rg)
#pragma unroll
    for (int jj = 0; jj < 2; ++jj) acc[rg][jj] = (f32x4){0.f, 0.f, 0.f, 0.f};
  // GEMM1: wave computes all 64 rows x its 32 cols (nf = 2*wid, 2*wid+1)
#pragma unroll
  for (int rg = 0; rg < 4; ++rg) {
    bf16x8 ah[4], al[4];
    load_afrag(MH, ML, 16 * rg + lr, lg, ah, al);
#pragma unroll
    for (int jj = 0; jj < 2; ++jj) {
      int nf = 2 * wid + jj;
#pragma unroll
      for (int kf = 0; kf < 4; ++kf) {
        int ch = ((nf * 4 + kf) << 9) + lane * 8;
        bf16x8 bh = *(const bf16x8*)(wt1h + ch);
        bf16x8 bl = *(const bf16x8*)(wt1l + ch);
        acc[rg][jj] = __builtin_amdgcn_mfma_f32_16x16x32_bf16(ah[kf], bh, acc[rg][jj], 0, 0, 0);
        acc[rg][jj] = __builtin_amdgcn_mfma_f32_16x16x32_bf16(ah[kf], bl, acc[rg][jj], 0, 0, 0);
        acc[rg][jj] = __builtin_amdgcn_mfma_f32_16x16x32_bf16(al[kf], bh, acc[rg][jj], 0, 0, 0);
      }
    }
  }
  __syncthreads();   // M fully consumed by all waves
  // T = relu(acc + b1) -> MH/ML
#pragma unroll
  for (int rg = 0; rg < 4; ++rg)
#pragma unroll
    for (int jj = 0; jj < 2; ++jj)
#pragma unroll
      for (int reg = 0; reg < 4; ++reg) {
        float t = reluf(acc[rg][jj][reg] + b1v[jj]);
        int row = 16 * rg + lg * 4 + reg;
        int col = 16 * (2 * wid + jj) + lr;
        ushort_t h, l;
        split2(t, h, l);
        MH[row][col] = h;
        ML[row][col] = l;
      }
  __syncthreads();   // T complete
  // GEMM2
#pragma unroll
  for (int rg = 0; rg < 4; ++rg)
#pragma unroll
    for (int jj = 0; jj < 2; ++jj) acc[rg][jj] = (f32x4){0.f, 0.f, 0.f, 0.f};
#pragma unroll
  for (int rg = 0; rg < 4; ++rg) {
    bf16x8 ah[4], al[4];
    load_afrag(MH, ML, 16 * rg + lr, lg, ah, al);
#pragma unroll
    for (int jj = 0; jj < 2; ++jj) {
      int nf = 2 * wid + jj;
#pragma unroll
      for (int kf = 0; kf < 4; ++kf) {
        int ch = ((nf * 4 + kf) << 9) + lane * 8;
        bf16x8 bh = *(const bf16x8*)(wt2h + ch);
        bf16x8 bl = *(const bf16x8*)(wt2l + ch);
        acc[rg][jj] = __builtin_amdgcn_mfma_f32_16x16x32_bf16(ah[kf], bh, acc[rg][jj], 0, 0, 0);
        acc[rg][jj] = __builtin_amdgcn_mfma_f32_16x16x32_bf16(ah[kf], bl, acc[rg][jj], 0, 0, 0);
        acc[rg][jj] = __builtin_amdgcn_mfma_f32_16x16x32_bf16(al[kf], bh, acc[rg][jj], 0, 0, 0);
      }
    }
  }
  __syncthreads();   // T fully consumed
  // park f32 result bits in MH/ML
#pragma unroll
  for (int rg = 0; rg < 4; ++rg)
#pragma unroll
    for (int jj = 0; jj < 2; ++jj)
#pragma unroll
      for (int reg = 0; reg < 4; ++reg) {
        int row = 16 * rg + lg * 4 + reg;
        int col = 16 * (2 * wid + jj) + lr;
        unsigned b = __float_as_uint(acc[rg][jj][reg] + b2v[jj]);
        MH[row][col] = (ushort_t)(b >> 16);
        ML[row][col] = (ushort_t)(b & 0xFFFFu);
      }
  __syncthreads();
  // run-dedup scatter: rows sorted by (g,d) = rec>>16; one atomic per run per col
  {
    int c = tid & 127, half = tid >> 7;
    int rbeg = half * 32, rend = rbeg + 32;
    unsigned curkey = 0xFFFFu;
    float best = -3.0e38f;
    for (int r = rbeg; r < rend; ++r) {
      unsigned rec = srec[r];
      unsigned key = rec >> 16;   // g*128+d (<=0xFFF) or 0xFFFF if invalid
      if (key != curkey) {
        if (curkey != 0xFFFFu)
          atomicMax(aggk + (curkey << 7) + c, fkey(best));
        curkey = key;
        best = -3.0e38f;
      }
      if (key != 0xFFFFu) {
        unsigned b = ((unsigned)MH[r][c] << 16) | (unsigned)ML[r][c];
        best = fmaxf(best, __uint_as_float(b));
      }
    }
    if (curkey != 0xFFFFu)
      atomicMax(aggk + (curkey << 7) + c, fkey(best));
  }
}

// ---------------- hid update via MFMA (4 waves/block) ----------------
__global__ __launch_bounds__(256) void k_out(const float* __restrict__ nf,
                                             const float* __restrict__ hid,
                                             const unsigned* __restrict__ aggk,
                                             const ushort_t* __restrict__ wo_h,
                                             const ushort_t* __restrict__ wo_l,
                                             const float* __restrict__ bo1,
                                             const float* __restrict__ bo2,
                                             float* __restrict__ hidn) {
  __shared__ ushort_t MH[16][136];
  __shared__ ushort_t ML[16][136];
  int tid = threadIdx.x;
  int v0 = blockIdx.x * 16;
  int lane = tid & 63, wid = tid >> 6;
  int lr = lane & 15, lg = lane >> 4;
  f32x4 acc[2];
#pragma unroll
  for (int jj = 0; jj < 2; ++jj) acc[jj] = (f32x4){0.f, 0.f, 0.f, 0.f};

  for (int seg = 0; seg < 3; ++seg) {
#pragma unroll
    for (int i = 0; i < 2; ++i) {
      int idx = tid + i * 256;        // over 512 float4s
      int row = idx >> 5, c4 = idx & 31;
      float4 v;
      if (seg == 0)      v = ((const float4*)nf)[(v0 + row) * 32 + c4];
      else if (seg == 1) v = ((const float4*)hid)[(v0 + row) * 32 + c4];
      else {
        uint4 k4 = ((const uint4*)aggk)[(v0 + row) * 32 + c4];
        v.x = funkey(k4.x); v.y = funkey(k4.y); v.z = funkey(k4.z); v.w = funkey(k4.w);
      }
      us4 h4, l4;
      split2(v.x, h4.a, l4.a);
      split2(v.y, h4.b, l4.b);
      split2(v.z, h4.c, l4.c);
      split2(v.w, h4.d, l4.d);
      *(us4*)&MH[row][c4 * 4] = h4;
      *(us4*)&ML[row][c4 * 4] = l4;
    }
    __syncthreads();
    bf16x8 ah[4], al[4];
    load_afrag(MH, ML, lr, lg, ah, al);
#pragma unroll
    for (int jj = 0; jj < 2; ++jj) {
      int nfr = 2 * wid + jj;
#pragma unroll
      for (int kf = 0; kf < 4; ++kf) {
        int ch = ((nfr * 12 + seg * 4 + kf) << 9) + lane * 8;
        bf16x8 bh = *(const bf16x8*)(wo_h + ch);
        bf16x8 bl = *(const bf16x8*)(wo_l + ch);
        acc[jj] = __builtin_amdgcn_mfma_f32_16x16x32_bf16(ah[kf], bh, acc[jj], 0, 0, 0);
        acc[jj] = __builtin_amdgcn_mfma_f32_16x16x32_bf16(ah[kf], bl, acc[jj], 0, 0, 0);
        acc[jj] = __builtin_amdgcn_mfma_f32_16x16x32_bf16(al[kf], bh, acc[jj], 0, 0, 0);
      }
    }
    __syncthreads();
  }
#pragma unroll
  for (int jj = 0; jj < 2; ++jj) {
    int col = 16 * (2 * wid + jj) + lr;
    float b = bo1[col] + bo2[col];
#pragma unroll
    for (int reg = 0; reg < 4; ++reg)
      hidn[(v0 + lg * 4 + reg) * Hh + col] = reluf(acc[jj][reg] + b);
  }
}

// ---------------- readout head ----------------
__global__ __launch_bounds__(128) void k_head(const float* __restrict__ hid,
                                              const float* __restrict__ Wg1,
                                              const float* __restrict__ bg1,
                                              const float* __restrict__ Wg2,
                                              const float* __restrict__ bg2,
                                              float* __restrict__ out) {
  __shared__ float emb[Hh];
  __shared__ float tt[Hh];
  int g = blockIdx.x, j = threadIdx.x;
  float s = 0.f;
  for (int n = 0; n < Nn; ++n) s += hid[(g * Nn + n) * Hh + j];
  emb[j] = s * (1.f / Nn);
  __syncthreads();
  float a = bg1[j];
  for (int i = 0; i < Hh; ++i) a += emb[i] * Wg1[i * Hh + j];
  tt[j] = reluf(a);
  __syncthreads();
  if (j < 12) {
    float o = bg2[j];
    for (int i = 0; i < Hh; ++i) o += tt[i] * Wg2[i * 12 + j];
    out[g * 12 + j] = o;
  }
}

extern "C" void kernel_launch(void* const* d_in, const int* in_sizes, int n_in,
                              void* d_out, int out_size, void* d_ws, size_t ws_size,
                              hipStream_t stream) {
  const int* x = (const int*)d_in[0];
  const int* eidx32 = (const int*)d_in[1];
  const int* eattr = (const int*)d_in[2];
  const float* atom_tab = (const float*)d_in[4];
  const float* bond_tab = (const float*)d_in[5];
  const float* W_m1 = (const float*)d_in[6];
  const float* b_m1 = (const float*)d_in[7];
  const float* W_m2 = (const float*)d_in[8];
  const float* b_m2 = (const float*)d_in[9];
  const float* W_me = (const float*)d_in[10];
  const float* b_me = (const float*)d_in[11];
  const float* b_mg = (const float*)d_in[13];
  const float* W_h1 = (const float*)d_in[14];
  const float* b_h1 = (const float*)d_in[15];
  const float* W_h2 = (const float*)d_in[16];
  const float* b_h2 = (const float*)d_in[17];
  const float* W_o1 = (const float*)d_in[18];
  const float* b_o1 = (const float*)d_in[19];
  const float* W_o2 = (const float*)d_in[20];
  const float* b_o2 = (const float*)d_in[21];
  const float* Wg1 = (const float*)d_in[22];
  const float* bg1 = (const float*)d_in[23];
  const float* Wg2 = (const float*)d_in[24];
  const float* bg2 = (const float*)d_in[25];
  float* out = (float*)d_out;

  char* ws = (char*)d_ws;
  float* nf = (float*)(ws);                                 // 2MB
  float* hidA = (float*)(ws + (2u << 20));                  // 2MB
  float* hidB = (float*)(ws + (4u << 20));                  // 2MB
  float* m1 = (float*)(ws + (6u << 20));                    // 2MB
  float* m2 = (float*)(ws + (8u << 20));                    // 2MB
  unsigned* aggk = (unsigned*)(ws + (10u << 20));           // 2MB
  int* win = (int*)(ws + (12u << 20));                      // 2MB (dead after k_dfill)
  ushort_t* wo = (ushort_t*)(ws + (12u << 20));             // 384KB (overlays win)
  ushort_t* wm = (ushort_t*)(ws + (12u << 20) + 393216);    // 512KB (overlays win)
  ushort_t* wt = (ushort_t*)(ws + (14u << 20));             // 256KB
  float* bf = (float*)(ws + (14u << 20) + (256u << 10));    // 256KB
  float* me = (float*)(ws + (14u << 20) + (512u << 10));    // 256KB
  unsigned* recs = (unsigned*)(ws + (14u << 20) + (768u << 10));  // 256KB
  int* dcnt = (int*)(ws + (15u << 20));                     // 16KB
  int* rowptr = (int*)(ws + (15u << 20) + (16u << 10));     // ~16KB (4097)
  int* eflag = (int*)(ws + (15u << 20) + (48u << 10));      // 4B

  hipMemsetAsync(win, 0xFF, GNN * sizeof(int), stream);
  k_detect<<<1, 128, 0, stream>>>(eidx32, eflag);
  k_node_encode<<<2048, 256, 0, stream>>>(x, atom_tab, nf, hidA);
  k_bond_fts<<<256, 256, 0, stream>>>(bond_tab, bf);
  k_scatter_win<<<256, 256, 0, stream>>>(eidx32, eflag, win);
  k_dcount<<<2048, 256, 0, stream>>>(win, dcnt);
  k_dscan<<<1, 512, 0, stream>>>(dcnt, rowptr);
  k_dfill<<<2048, 256, 0, stream>>>(win, eattr, rowptr, recs);
  k_wprep<<<256, 256, 0, stream>>>(W_h1, W_h2, wt);
  k_wprep_o<<<dim3(192, 2), 256, 0, stream>>>(W_o1, W_o2, wo);   // win dead now
  k_wprep_m<<<512, 256, 0, stream>>>(W_m1, W_m2, wm);

  int* cnt = rowptr + 4096;   // total edge count written by k_dscan

  float* hc = hidA;
  float* hn = hidB;
  for (int l = 0; l < 2; ++l) {
    const ushort_t* wt1h = wt + ((l * 2 + 0) * 2 + 0) * 16384;
    const ushort_t* wt1l = wt + ((l * 2 + 0) * 2 + 1) * 16384;
    const ushort_t* wt2h = wt + ((l * 2 + 1) * 2 + 0) * 16384;
    const ushort_t* wt2l = wt + ((l * 2 + 1) * 2 + 1) * 16384;
    const ushort_t* wo_h = wo + (l * 2 + 0) * 49152;
    const ushort_t* wo_l = wo + (l * 2 + 1) * 49152;
    k_me_init<<<256, 256, 0, stream>>>(bf, W_me + l * Hh * Hh, b_me + l * Hh,
                                       b_mg + l * Hh, me, aggk);
    k_m12<<<256, 256, 0, stream>>>(nf, hc, wm + l * 131072, b_m1 + l * Hh,
                                   b_m2 + l * Hh, m1, m2);
    k_edge<<<1024, 256, 0, stream>>>(recs, cnt, m1, m2, me, wt1h, wt1l, wt2h, wt2l,
                                     b_h1 + l * Hh, b_h2 + l * Hh, aggk);
    k_out<<<256, 256, 0, stream>>>(nf, hc, aggk, wo_h, wo_l,
                                   b_o1 + l * Hh, b_o2 + l * Hh, hn);
    float* t = hc; hc = hn; hn = t;
  }
  k_head<<<32, 128, 0, stream>>>(hc, Wg1, bg1, Wg2, bg2, out);
}

// Round 12
// 134.156 us; speedup vs baseline: 3.3215x; 1.3616x over previous
//
#include <hip/hip_runtime.h>

#define Gg   32
#define Nn   128
#define Hh   128
#define Ee   65536
#define GN   4096      // Gg*Nn
#define GNN  524288    // Gg*Nn*Nn

typedef unsigned short ushort_t;
typedef __attribute__((ext_vector_type(8))) __bf16 bf16x8;
typedef __attribute__((ext_vector_type(4))) float f32x4;
struct us4 { ushort_t a, b, c, d; };

__device__ __forceinline__ float reluf(float x) { return x > 0.f ? x : 0.f; }

// monotone float <-> u32 key (for atomicMax on floats incl. negatives)
__device__ __forceinline__ unsigned fkey(float f) {
  unsigned u = __float_as_uint(f);
  return (u & 0x80000000u) ? ~u : (u | 0x80000000u);
}
__device__ __forceinline__ float funkey(unsigned k) {
  unsigned u = (k & 0x80000000u) ? (k ^ 0x80000000u) : ~k;
  return __uint_as_float(u);
}

// round-to-nearest-even f32 -> bf16 bits
__device__ __forceinline__ ushort_t bfh(float x) {
  unsigned u = __float_as_uint(x);
  return (ushort_t)((u + 0x7FFFu + ((u >> 16) & 1u)) >> 16);
}
__device__ __forceinline__ void split2(float x, ushort_t& h, ushort_t& l) {
  h = bfh(x);
  float hf = __uint_as_float(((unsigned)h) << 16);
  l = bfh(x - hf);
}

// ---------------- edge_index layout detection ----------------
__global__ __launch_bounds__(128) void k_detect(const int* __restrict__ e32,
                                                int* __restrict__ flag) {
  __shared__ int s;
  if (threadIdx.x == 0) s = 0;
  __syncthreads();
  if (e32[2 * threadIdx.x + 1] != 0) atomicOr(&s, 1);
  __syncthreads();
  if (threadIdx.x == 0) *flag = s;  // 1 => int32 layout, 0 => int64 layout
}

// ---------------- encoders ----------------
__global__ __launch_bounds__(256) void k_node_encode(const int* __restrict__ x,
                                                     const float* __restrict__ atom_tab,
                                                     float* __restrict__ nf,
                                                     float* __restrict__ hid) {
  int t = blockIdx.x * 256 + threadIdx.x;      // over GN*Hh
  int v = t >> 7, h = t & 127;
  float s = 0.f;
#pragma unroll
  for (int f = 0; f < 9; ++f) {
    int idx = x[v * 9 + f];
    s += atom_tab[(f * 119 + idx) * Hh + h];
  }
  nf[t] = s;
  hid[t] = 0.f;
}

__global__ __launch_bounds__(256) void k_bond_fts(const float* __restrict__ bond_tab,
                                                  float* __restrict__ bf) {
  int t = blockIdx.x * 256 + threadIdx.x;      // 512*128
  int c = t >> 7, h = t & 127;
  int a0 = c & 7, a1 = (c >> 3) & 7, a2 = (c >> 6) & 7;
  bf[t] = bond_tab[(0 * 8 + a0) * Hh + h] + bond_tab[(1 * 8 + a1) * Hh + h] +
          bond_tab[(2 * 8 + a2) * Hh + h];
}

// ---------------- edge winner: win indexed by (g, d, s); last edge wins ----------
__global__ __launch_bounds__(256) void k_scatter_win(const int* __restrict__ e32,
                                                     const int* __restrict__ flag,
                                                     int* __restrict__ win) {
  int e = blockIdx.x * 256 + threadIdx.x;
  int sg, dg;
  if (*flag) { sg = e32[e]; dg = e32[Ee + e]; }
  else       { sg = e32[2 * e]; dg = e32[2 * Ee + 2 * e]; }
  int g = sg / Nn;
  int s = sg % Nn;
  int d = dg % Nn;
  atomicMax(&win[(g * Nn + d) * Nn + s], e);   // destination-major
}

// ---------------- per-destination compaction: count / scan / fill ----------------
__global__ __launch_bounds__(256) void k_dcount(const int* __restrict__ win,
                                                int* __restrict__ dcnt) {
  int tid = threadIdx.x;
  int grp = tid >> 7, t = tid & 127;
  int dest = blockIdx.x * 2 + grp;
  bool valid = win[dest * 128 + t] >= 0;
  unsigned long long mask = __ballot(valid);
  __shared__ int cw[4];
  if ((tid & 63) == 0) cw[tid >> 6] = __popcll(mask);
  __syncthreads();
  if (t == 0) dcnt[dest] = cw[grp * 2] + cw[grp * 2 + 1];
}

__global__ __launch_bounds__(512) void k_dscan(const int* __restrict__ dcnt,
                                               int* __restrict__ rowptr) {
  int tid = threadIdx.x;            // 512 threads x 8 dests = 4096
  int c0, c1, c2, c3, c4, c5, c6, c7;
  int bi = tid * 8;
  c0 = dcnt[bi + 0]; c1 = dcnt[bi + 1]; c2 = dcnt[bi + 2]; c3 = dcnt[bi + 3];
  c4 = dcnt[bi + 4]; c5 = dcnt[bi + 5]; c6 = dcnt[bi + 6]; c7 = dcnt[bi + 7];
  int s = c0 + c1 + c2 + c3 + c4 + c5 + c6 + c7;
  int x = s;
#pragma unroll
  for (int off = 1; off < 64; off <<= 1) {
    int y = __shfl_up(x, off, 64);
    if ((tid & 63) >= off) x += y;
  }
  __shared__ int wsum[8], woff[8];
  if ((tid & 63) == 63) wsum[tid >> 6] = x;
  __syncthreads();
  if (tid == 0) {
    int a = 0;
#pragma unroll
    for (int i = 0; i < 8; ++i) { woff[i] = a; a += wsum[i]; }
  }
  __syncthreads();
  int base = x - s + woff[tid >> 6];
  rowptr[bi + 0] = base; base += c0;
  rowptr[bi + 1] = base; base += c1;
  rowptr[bi + 2] = base; base += c2;
  rowptr[bi + 3] = base; base += c3;
  rowptr[bi + 4] = base; base += c4;
  rowptr[bi + 5] = base; base += c5;
  rowptr[bi + 6] = base; base += c6;
  rowptr[bi + 7] = base; base += c7;
  if (tid == 511) rowptr[4096] = base;   // total count
}

__global__ __launch_bounds__(256) void k_dfill(const int* __restrict__ win,
                                               const int* __restrict__ eattr,
                                               const int* __restrict__ rowptr,
                                               unsigned* __restrict__ recs) {
  int tid = threadIdx.x;
  int grp = tid >> 7, t = tid & 127;
  int dest = blockIdx.x * 2 + grp;
  int e = win[dest * 128 + t];
  bool valid = e >= 0;
  unsigned long long mask = __ballot(valid);
  __shared__ int cw[4];
  int lane = tid & 63;
  if (lane == 0) cw[tid >> 6] = __popcll(mask);
  __syncthreads();
  if (valid) {
    int off = __popcll(mask & ((1ull << lane) - 1));
    if ((tid >> 6) & 1) off += cw[grp * 2];
    int a0 = eattr[e * 3 + 0], a1 = eattr[e * 3 + 1], a2 = eattr[e * 3 + 2];
    unsigned code = (unsigned)(a0 + (a1 << 3) + (a2 << 6));
    unsigned idx = ((unsigned)dest << 7) | (unsigned)t;   // (g*128+d)*128+s
    recs[rowptr[dest] + off] = (idx << 9) | code;         // sorted by dest
  }
}

// ---------------- weight prep: fragment-ordered layouts ----------------
// element (n,k): nf=n>>4, lr=n&15, kf=k>>5, lg=(k>>3)&3, j=k&7
// off = ((nf*KCH + kf)*64 + lg*16 + lr)*8 + j  -> one wave-load = 1KB contiguous

// wt: [layer(2)][mat(2)][part(2)] of 16384, KCH=4
__global__ __launch_bounds__(256) void k_wprep(const float* __restrict__ W_h1,
                                               const float* __restrict__ W_h2,
                                               ushort_t* __restrict__ wt) {
  int t = blockIdx.x * 256 + threadIdx.x;      // 2*2*16384
  int l = t >> 15;
  int m = (t >> 14) & 1;
  int e = t & 16383;
  int n = e & 127, k = e >> 7;
  const float* W = (m == 0 ? W_h1 : W_h2) + l * 16384;
  float v = W[k * 128 + n];
  ushort_t h, lo;
  split2(v, h, lo);
  int nf = n >> 4, lr = n & 15, kf = k >> 5, lg = (k >> 3) & 3, j = k & 7;
  int off = ((nf * 4 + kf) * 64 + lg * 16 + lr) * 8 + j;
  int base = ((l * 2 + m) * 2) * 16384;
  wt[base + off] = h;
  wt[base + 16384 + off] = lo;
}

// wo: [layer(2)][part(2)] of 49152, KCH=12; grid (192, 2)
__global__ __launch_bounds__(256) void k_wprep_o(const float* __restrict__ W_o1,
                                                 const float* __restrict__ W_o2,
                                                 ushort_t* __restrict__ wo) {
  int e = blockIdx.x * 256 + threadIdx.x;      // 0 .. 49151  (= n*384 + k)
  int l = blockIdx.y;
  int n = e / 384, k = e - n * 384;
  float v = (k < 256) ? W_o1[(l * 256 + k) * 128 + n]
                      : W_o2[(l * 128 + (k - 256)) * 128 + n];
  ushort_t h, lo;
  split2(v, h, lo);
  int nf = n >> 4, lr = n & 15, kf = k >> 5, lg = (k >> 3) & 3, j = k & 7;
  int off = ((nf * 12 + kf) * 64 + lg * 16 + lr) * 8 + j;
  wo[(l * 2 + 0) * 49152 + off] = h;
  wo[(l * 2 + 1) * 49152 + off] = lo;
}

// wm: [layer(2)][mat(2)][part(2)] of 32768, KCH=8
__global__ __launch_bounds__(256) void k_wprep_m(const float* __restrict__ W_m1,
                                                 const float* __restrict__ W_m2,
                                                 ushort_t* __restrict__ wm) {
  int t = blockIdx.x * 256 + threadIdx.x;      // 131072 = 2l*2m*32768
  int l = t >> 16;
  int m = (t >> 15) & 1;
  int e = t & 32767;                           // n*256 + k
  int n = e >> 8, k = e & 255;
  const float* W = (m == 0 ? W_m1 : W_m2);
  float v = W[(l * 256 + k) * 128 + n];
  ushort_t h, lo;
  split2(v, h, lo);
  int nf = n >> 4, lr = n & 15, kf = k >> 5, lg = (k >> 3) & 3, j = k & 7;
  int off = ((nf * 8 + kf) * 64 + lg * 16 + lr) * 8 + j;
  int base = ((l * 2 + m) * 2) * 32768;
  wm[base + off] = h;
  wm[base + 32768 + off] = lo;
}

// ---------------- me table + agg init (fused) ----------------
__global__ __launch_bounds__(256) void k_me_init(const float* __restrict__ bf,
                                                 const float* __restrict__ W_me,
                                                 const float* __restrict__ b_me,
                                                 const float* __restrict__ b_mg,
                                                 float* __restrict__ me,
                                                 unsigned* __restrict__ aggk) {
  __shared__ float v[2][128];
  int tid = threadIdx.x;
  int half = tid >> 7, j = tid & 127;
  int c = blockIdx.x * 2 + half;
  v[half][j] = bf[c * 128 + j];
  __syncthreads();
  float acc = b_me[j] + b_mg[j];
  for (int i = 0; i < 128; ++i) acc += v[half][i] * W_me[i * 128 + j];
  me[c * 128 + j] = acc;
  unsigned key = fkey(-1.0e9f);
#pragma unroll
  for (int i = 0; i < 8; ++i) aggk[blockIdx.x * 2048 + i * 256 + tid] = key;
}

// ---------------- m1,m2 = [nf|hid] @ W_m1 / W_m2 via MFMA (4 waves/block) -------
__global__ __launch_bounds__(256) void k_m12(const float* __restrict__ nf_,
                                             const float* __restrict__ hid,
                                             const ushort_t* __restrict__ wm,
                                             const float* __restrict__ bi1,
                                             const float* __restrict__ bi2,
                                             float* __restrict__ m1,
                                             float* __restrict__ m2) {
  __shared__ ushort_t AH[16][264];
  __shared__ ushort_t AL[16][264];
  int tid = threadIdx.x;
  int v0 = blockIdx.x * 16;
#pragma unroll
  for (int i = 0; i < 4; ++i) {
    int idx = tid + i * 256;          // 1024 float4s = 16 rows x 64
    int row = idx >> 6, c4 = idx & 63;
    float4 v = (c4 < 32) ? ((const float4*)nf_)[(v0 + row) * 32 + c4]
                         : ((const float4*)hid)[(v0 + row) * 32 + (c4 - 32)];
    us4 h4, l4;
    split2(v.x, h4.a, l4.a); split2(v.y, h4.b, l4.b);
    split2(v.z, h4.c, l4.c); split2(v.w, h4.d, l4.d);
    *(us4*)&AH[row][c4 * 4] = h4;
    *(us4*)&AL[row][c4 * 4] = l4;
  }
  __syncthreads();
  int lane = tid & 63, wid = tid >> 6;
  int lr = lane & 15, lg = lane >> 4;
  f32x4 a1[2], a2[2];
#pragma unroll
  for (int i = 0; i < 2; ++i) { a1[i] = (f32x4){0.f,0.f,0.f,0.f}; a2[i] = (f32x4){0.f,0.f,0.f,0.f}; }
  const ushort_t* w1h = wm;
  const ushort_t* w1l = wm + 32768;
  const ushort_t* w2h = wm + 65536;
  const ushort_t* w2l = wm + 98304;
#pragma unroll
  for (int seg = 0; seg < 2; ++seg) {
    bf16x8 ah[4], al[4];
#pragma unroll
    for (int kf = 0; kf < 4; ++kf) {
      ah[kf] = *(const bf16x8*)&AH[lr][seg * 128 + lg * 8 + 32 * kf];
      al[kf] = *(const bf16x8*)&AL[lr][seg * 128 + lg * 8 + 32 * kf];
    }
#pragma unroll
    for (int jj = 0; jj < 2; ++jj) {
      int nfr = 2 * wid + jj;
#pragma unroll
      for (int kf = 0; kf < 4; ++kf) {
        int ch = ((nfr * 8 + seg * 4 + kf) << 9) + lane * 8;
        bf16x8 b1h = *(const bf16x8*)(w1h + ch);
        bf16x8 b1l = *(const bf16x8*)(w1l + ch);
        bf16x8 b2h = *(const bf16x8*)(w2h + ch);
        bf16x8 b2l = *(const bf16x8*)(w2l + ch);
        a1[jj] = __builtin_amdgcn_mfma_f32_16x16x32_bf16(ah[kf], b1h, a1[jj], 0, 0, 0);
        a1[jj] = __builtin_amdgcn_mfma_f32_16x16x32_bf16(ah[kf], b1l, a1[jj], 0, 0, 0);
        a1[jj] = __builtin_amdgcn_mfma_f32_16x16x32_bf16(al[kf], b1h, a1[jj], 0, 0, 0);
        a2[jj] = __builtin_amdgcn_mfma_f32_16x16x32_bf16(ah[kf], b2h, a2[jj], 0, 0, 0);
        a2[jj] = __builtin_amdgcn_mfma_f32_16x16x32_bf16(ah[kf], b2l, a2[jj], 0, 0, 0);
        a2[jj] = __builtin_amdgcn_mfma_f32_16x16x32_bf16(al[kf], b2h, a2[jj], 0, 0, 0);
      }
    }
  }
#pragma unroll
  for (int jj = 0; jj < 2; ++jj) {
    int col = 16 * (2 * wid + jj) + lr;
    float bb1 = bi1[col], bb2 = bi2[col];
#pragma unroll
    for (int reg = 0; reg < 4; ++reg) {
      int row = v0 + lg * 4 + reg;
      m1[row * Hh + col] = a1[jj][reg] + bb1;
      m2[row * Hh + col] = a2[jj][reg] + bb2;
    }
  }
}

// ---------------- MFMA A-fragment helper ----------------
__device__ __forceinline__ void load_afrag(const ushort_t (*MH)[136],
                                           const ushort_t (*ML)[136],
                                           int row, int lg,
                                           bf16x8 ah[4], bf16x8 al[4]) {
#pragma unroll
  for (int kf = 0; kf < 4; ++kf) {
    ah[kf] = *(const bf16x8*)&MH[row][lg * 8 + 32 * kf];
    al[kf] = *(const bf16x8*)&ML[row][lg * 8 + 32 * kf];
  }
}

// ---------------- edge phase: 64-edge tile, 8 waves (1 col-group each) ----------
__global__ __launch_bounds__(512) void k_edge(const unsigned* __restrict__ recs,
                                              const int* __restrict__ cnt,
                                              const float* __restrict__ m1,
                                              const float* __restrict__ m2,
                                              const float* __restrict__ me,
                                              const ushort_t* __restrict__ wt1h,
                                              const ushort_t* __restrict__ wt1l,
                                              const ushort_t* __restrict__ wt2h,
                                              const ushort_t* __restrict__ wt2l,
                                              const float* __restrict__ b_h1,
                                              const float* __restrict__ b_h2,
                                              unsigned* __restrict__ aggk) {
  __shared__ ushort_t MH[64][136];
  __shared__ ushort_t ML[64][136];
  __shared__ unsigned srec[64];
  int tid = threadIdx.x;
  int n = *cnt;
  if (tid < 64) {
    int r = blockIdx.x * 64 + tid;
    srec[tid] = (r < n) ? recs[r] : 0xFFFFFFFFu;
  }
  __syncthreads();
  // build M tile (float4-vectorized; 512 threads cover 64 rows x 32 col4)
  {
    int c4 = tid & 31, rq = tid >> 5;     // rq in 0..15
#pragma unroll
    for (int i = 0; i < 4; ++i) {
      int r = 16 * i + rq;
      float4 v = make_float4(0.f, 0.f, 0.f, 0.f);
      unsigned rec = srec[r];
      if (rec != 0xFFFFFFFFu) {
        int code = rec & 511;
        unsigned idx = rec >> 9;
        int s = idx & 127, d = (idx >> 7) & 127, g = idx >> 14;
        float4 a = *(const float4*)(m1 + (((g << 7) + d) << 7) + c4 * 4);
        float4 b = *(const float4*)(m2 + (((g << 7) + s) << 7) + c4 * 4);
        float4 cme = *(const float4*)(me + (code << 7) + c4 * 4);
        v.x = reluf(a.x + b.x + cme.x);
        v.y = reluf(a.y + b.y + cme.y);
        v.z = reluf(a.z + b.z + cme.z);
        v.w = reluf(a.w + b.w + cme.w);
      }
      us4 h4, l4;
      split2(v.x, h4.a, l4.a); split2(v.y, h4.b, l4.b);
      split2(v.z, h4.c, l4.c); split2(v.w, h4.d, l4.d);
      *(us4*)&MH[r][c4 * 4] = h4;
      *(us4*)&ML[r][c4 * 4] = l4;
    }
  }
  __syncthreads();

  int lane = tid & 63, wid = tid >> 6;     // wid = nf (0..7)
  int lr = lane & 15, lg = lane >> 4;
  float b1v = b_h1[16 * wid + lr];
  float b2v = b_h2[16 * wid + lr];
  f32x4 acc[4];
#pragma unroll
  for (int rg = 0; rg < 4; ++rg) acc[rg] = (f32x4){0.f, 0.f, 0.f, 0.f};
  // GEMM1: wave computes all 64 rows x its 16 cols (nf = wid)
#pragma unroll
  for (int rg = 0; rg < 4; ++rg) {
    bf16x8 ah[4], al[4];
    load_afrag(MH, ML, 16 * rg + lr, lg, ah, al);
#pragma unroll
    for (int kf = 0; kf < 4; ++kf) {
      int ch = ((wid * 4 + kf) << 9) + lane * 8;
      bf16x8 bh = *(const bf16x8*)(wt1h + ch);
      bf16x8 bl = *(const bf16x8*)(wt1l + ch);
      acc[rg] = __builtin_amdgcn_mfma_f32_16x16x32_bf16(ah[kf], bh, acc[rg], 0, 0, 0);
      acc[rg] = __builtin_amdgcn_mfma_f32_16x16x32_bf16(ah[kf], bl, acc[rg], 0, 0, 0);
      acc[rg] = __builtin_amdgcn_mfma_f32_16x16x32_bf16(al[kf], bh, acc[rg], 0, 0, 0);
    }
  }
  __syncthreads();   // M fully consumed by all waves
  // T = relu(acc + b1) -> MH/ML
#pragma unroll
  for (int rg = 0; rg < 4; ++rg)
#pragma unroll
    for (int reg = 0; reg < 4; ++reg) {
      float t = reluf(acc[rg][reg] + b1v);
      int row = 16 * rg + lg * 4 + reg;
      int col = 16 * wid + lr;
      ushort_t h, l;
      split2(t, h, l);
      MH[row][col] = h;
      ML[row][col] = l;
    }
  __syncthreads();   // T complete
  // GEMM2
#pragma unroll
  for (int rg = 0; rg < 4; ++rg) acc[rg] = (f32x4){0.f, 0.f, 0.f, 0.f};
#pragma unroll
  for (int rg = 0; rg < 4; ++rg) {
    bf16x8 ah[4], al[4];
    load_afrag(MH, ML, 16 * rg + lr, lg, ah, al);
#pragma unroll
    for (int kf = 0; kf < 4; ++kf) {
      int ch = ((wid * 4 + kf) << 9) + lane * 8;
      bf16x8 bh = *(const bf16x8*)(wt2h + ch);
      bf16x8 bl = *(const bf16x8*)(wt2l + ch);
      acc[rg] = __builtin_amdgcn_mfma_f32_16x16x32_bf16(ah[kf], bh, acc[rg], 0, 0, 0);
      acc[rg] = __builtin_amdgcn_mfma_f32_16x16x32_bf16(ah[kf], bl, acc[rg], 0, 0, 0);
      acc[rg] = __builtin_amdgcn_mfma_f32_16x16x32_bf16(al[kf], bh, acc[rg], 0, 0, 0);
    }
  }
  __syncthreads();   // T fully consumed
  // park f32 result bits in MH/ML
#pragma unroll
  for (int rg = 0; rg < 4; ++rg)
#pragma unroll
    for (int reg = 0; reg < 4; ++reg) {
      int row = 16 * rg + lg * 4 + reg;
      int col = 16 * wid + lr;
      unsigned b = __float_as_uint(acc[rg][reg] + b2v);
      MH[row][col] = (ushort_t)(b >> 16);
      ML[row][col] = (ushort_t)(b & 0xFFFFu);
    }
  __syncthreads();
  // run-dedup scatter: rows sorted by (g,d) = rec>>16; one atomic per run per col
  {
    int c = tid & 127, quarter = tid >> 7;   // 4 x 16-row segments
    int rbeg = quarter * 16, rend = rbeg + 16;
    unsigned curkey = 0xFFFFu;
    float best = -3.0e38f;
    for (int r = rbeg; r < rend; ++r) {
      unsigned rec = srec[r];
      unsigned key = rec >> 16;   // g*128+d (<=0xFFF) or 0xFFFF if invalid
      if (key != curkey) {
        if (curkey != 0xFFFFu)
          atomicMax(aggk + (curkey << 7) + c, fkey(best));
        curkey = key;
        best = -3.0e38f;
      }
      if (key != 0xFFFFu) {
        unsigned b = ((unsigned)MH[r][c] << 16) | (unsigned)ML[r][c];
        best = fmaxf(best, __uint_as_float(b));
      }
    }
    if (curkey != 0xFFFFu)
      atomicMax(aggk + (curkey << 7) + c, fkey(best));
  }
}

// ---------------- hid update via MFMA (4 waves/block) ----------------
__global__ __launch_bounds__(256) void k_out(const float* __restrict__ nf,
                                             const float* __restrict__ hid,
                                             const unsigned* __restrict__ aggk,
                                             const ushort_t* __restrict__ wo_h,
                                             const ushort_t* __restrict__ wo_l,
                                             const float* __restrict__ bo1,
                                             const float* __restrict__ bo2,
                                             float* __restrict__ hidn) {
  __shared__ ushort_t MH[16][136];
  __shared__ ushort_t ML[16][136];
  int tid = threadIdx.x;
  int v0 = blockIdx.x * 16;
  int lane = tid & 63, wid = tid >> 6;
  int lr = lane & 15, lg = lane >> 4;
  f32x4 acc[2];
#pragma unroll
  for (int jj = 0; jj < 2; ++jj) acc[jj] = (f32x4){0.f, 0.f, 0.f, 0.f};

  for (int seg = 0; seg < 3; ++seg) {
#pragma unroll
    for (int i = 0; i < 2; ++i) {
      int idx = tid + i * 256;        // over 512 float4s
      int row = idx >> 5, c4 = idx & 31;
      float4 v;
      if (seg == 0)      v = ((const float4*)nf)[(v0 + row) * 32 + c4];
      else if (seg == 1) v = ((const float4*)hid)[(v0 + row) * 32 + c4];
      else {
        uint4 k4 = ((const uint4*)aggk)[(v0 + row) * 32 + c4];
        v.x = funkey(k4.x); v.y = funkey(k4.y); v.z = funkey(k4.z); v.w = funkey(k4.w);
      }
      us4 h4, l4;
      split2(v.x, h4.a, l4.a);
      split2(v.y, h4.b, l4.b);
      split2(v.z, h4.c, l4.c);
      split2(v.w, h4.d, l4.d);
      *(us4*)&MH[row][c4 * 4] = h4;
      *(us4*)&ML[row][c4 * 4] = l4;
    }
    __syncthreads();
    bf16x8 ah[4], al[4];
    load_afrag(MH, ML, lr, lg, ah, al);
#pragma unroll
    for (int jj = 0; jj < 2; ++jj) {
      int nfr = 2 * wid + jj;
#pragma unroll
      for (int kf = 0; kf < 4; ++kf) {
        int ch = ((nfr * 12 + seg * 4 + kf) << 9) + lane * 8;
        bf16x8 bh = *(const bf16x8*)(wo_h + ch);
        bf16x8 bl = *(const bf16x8*)(wo_l + ch);
        acc[jj] = __builtin_amdgcn_mfma_f32_16x16x32_bf16(ah[kf], bh, acc[jj], 0, 0, 0);
        acc[jj] = __builtin_amdgcn_mfma_f32_16x16x32_bf16(ah[kf], bl, acc[jj], 0, 0, 0);
        acc[jj] = __builtin_amdgcn_mfma_f32_16x16x32_bf16(al[kf], bh, acc[jj], 0, 0, 0);
      }
    }
    __syncthreads();
  }
#pragma unroll
  for (int jj = 0; jj < 2; ++jj) {
    int col = 16 * (2 * wid + jj) + lr;
    float b = bo1[col] + bo2[col];
#pragma unroll
    for (int reg = 0; reg < 4; ++reg)
      hidn[(v0 + lg * 4 + reg) * Hh + col] = reluf(acc[jj][reg] + b);
  }
}

// ---------------- readout head ----------------
__global__ __launch_bounds__(128) void k_head(const float* __restrict__ hid,
                                              const float* __restrict__ Wg1,
                                              const float* __restrict__ bg1,
                                              const float* __restrict__ Wg2,
                                              const float* __restrict__ bg2,
                                              float* __restrict__ out) {
  __shared__ float emb[Hh];
  __shared__ float tt[Hh];
  int g = blockIdx.x, j = threadIdx.x;
  float s = 0.f;
  for (int n = 0; n < Nn; ++n) s += hid[(g * Nn + n) * Hh + j];
  emb[j] = s * (1.f / Nn);
  __syncthreads();
  float a = bg1[j];
  for (int i = 0; i < Hh; ++i) a += emb[i] * Wg1[i * Hh + j];
  tt[j] = reluf(a);
  __syncthreads();
  if (j < 12) {
    float o = bg2[j];
    for (int i = 0; i < Hh; ++i) o += tt[i] * Wg2[i * 12 + j];
    out[g * 12 + j] = o;
  }
}

extern "C" void kernel_launch(void* const* d_in, const int* in_sizes, int n_in,
                              void* d_out, int out_size, void* d_ws, size_t ws_size,
                              hipStream_t stream) {
  const int* x = (const int*)d_in[0];
  const int* eidx32 = (const int*)d_in[1];
  const int* eattr = (const int*)d_in[2];
  const float* atom_tab = (const float*)d_in[4];
  const float* bond_tab = (const float*)d_in[5];
  const float* W_m1 = (const float*)d_in[6];
  const float* b_m1 = (const float*)d_in[7];
  const float* W_m2 = (const float*)d_in[8];
  const float* b_m2 = (const float*)d_in[9];
  const float* W_me = (const float*)d_in[10];
  const float* b_me = (const float*)d_in[11];
  const float* b_mg = (const float*)d_in[13];
  const float* W_h1 = (const float*)d_in[14];
  const float* b_h1 = (const float*)d_in[15];
  const float* W_h2 = (const float*)d_in[16];
  const float* b_h2 = (const float*)d_in[17];
  const float* W_o1 = (const float*)d_in[18];
  const float* b_o1 = (const float*)d_in[19];
  const float* W_o2 = (const float*)d_in[20];
  const float* b_o2 = (const float*)d_in[21];
  const float* Wg1 = (const float*)d_in[22];
  const float* bg1 = (const float*)d_in[23];
  const float* Wg2 = (const float*)d_in[24];
  const float* bg2 = (const float*)d_in[25];
  float* out = (float*)d_out;

  char* ws = (char*)d_ws;
  float* nf = (float*)(ws);                                 // 2MB
  float* hidA = (float*)(ws + (2u << 20));                  // 2MB
  float* hidB = (float*)(ws + (4u << 20));                  // 2MB
  float* m1 = (float*)(ws + (6u << 20));                    // 2MB
  float* m2 = (float*)(ws + (8u << 20));                    // 2MB
  unsigned* aggk = (unsigned*)(ws + (10u << 20));           // 2MB
  int* win = (int*)(ws + (12u << 20));                      // 2MB (dead after k_dfill)
  ushort_t* wo = (ushort_t*)(ws + (12u << 20));             // 384KB (overlays win)
  ushort_t* wm = (ushort_t*)(ws + (12u << 20) + 393216);    // 512KB (overlays win)
  ushort_t* wt = (ushort_t*)(ws + (14u << 20));             // 256KB
  float* bf = (float*)(ws + (14u << 20) + (256u << 10));    // 256KB
  float* me = (float*)(ws + (14u << 20) + (512u << 10));    // 256KB
  unsigned* recs = (unsigned*)(ws + (14u << 20) + (768u << 10));  // 256KB
  int* dcnt = (int*)(ws + (15u << 20));                     // 16KB
  int* rowptr = (int*)(ws + (15u << 20) + (16u << 10));     // ~16KB (4097)
  int* eflag = (int*)(ws + (15u << 20) + (48u << 10));      // 4B

  hipMemsetAsync(win, 0xFF, GNN * sizeof(int), stream);
  k_detect<<<1, 128, 0, stream>>>(eidx32, eflag);
  k_node_encode<<<2048, 256, 0, stream>>>(x, atom_tab, nf, hidA);
  k_bond_fts<<<256, 256, 0, stream>>>(bond_tab, bf);
  k_scatter_win<<<256, 256, 0, stream>>>(eidx32, eflag, win);
  k_dcount<<<2048, 256, 0, stream>>>(win, dcnt);
  k_dscan<<<1, 512, 0, stream>>>(dcnt, rowptr);
  k_dfill<<<2048, 256, 0, stream>>>(win, eattr, rowptr, recs);
  k_wprep<<<256, 256, 0, stream>>>(W_h1, W_h2, wt);
  k_wprep_o<<<dim3(192, 2), 256, 0, stream>>>(W_o1, W_o2, wo);   // win dead now
  k_wprep_m<<<512, 256, 0, stream>>>(W_m1, W_m2, wm);

  int* cnt = rowptr + 4096;   // total edge count written by k_dscan

  float* hc = hidA;
  float* hn = hidB;
  for (int l = 0; l < 2; ++l) {
    const ushort_t* wt1h = wt + ((l * 2 + 0) * 2 + 0) * 16384;
    const ushort_t* wt1l = wt + ((l * 2 + 0) * 2 + 1) * 16384;
    const ushort_t* wt2h = wt + ((l * 2 + 1) * 2 + 0) * 16384;
    const ushort_t* wt2l = wt + ((l * 2 + 1) * 2 + 1) * 16384;
    const ushort_t* wo_h = wo + (l * 2 + 0) * 49152;
    const ushort_t* wo_l = wo + (l * 2 + 1) * 49152;
    k_me_init<<<256, 256, 0, stream>>>(bf, W_me + l * Hh * Hh, b_me + l * Hh,
                                       b_mg + l * Hh, me, aggk);
    k_m12<<<256, 256, 0, stream>>>(nf, hc, wm + l * 131072, b_m1 + l * Hh,
                                   b_m2 + l * Hh, m1, m2);
    k_edge<<<1024, 512, 0, stream>>>(recs, cnt, m1, m2, me, wt1h, wt1l, wt2h, wt2l,
                                     b_h1 + l * Hh, b_h2 + l * Hh, aggk);
    k_out<<<256, 256, 0, stream>>>(nf, hc, aggk, wo_h, wo_l,
                                   b_o1 + l * Hh, b_o2 + l * Hh, hn);
    float* t = hc; hc = hn; hn = t;
  }
  k_head<<<32, 128, 0, stream>>>(hc, Wg1, bg1, Wg2, bg2, out);
}

// Round 13
// 127.635 us; speedup vs baseline: 3.4912x; 1.0511x over previous
//
#include <hip/hip_runtime.h>

#define Gg   32
#define Nn   128
#define Hh   128
#define Ee   65536
#define GN   4096      // Gg*Nn
#define GNN  524288    // Gg*Nn*Nn

typedef unsigned short ushort_t;
typedef __attribute__((ext_vector_type(8))) __bf16 bf16x8;
typedef __attribute__((ext_vector_type(4))) float f32x4;
struct us4 { ushort_t a, b, c, d; };

__device__ __forceinline__ float reluf(float x) { return x > 0.f ? x : 0.f; }

// monotone float <-> u32 key (for atomicMax on floats incl. negatives)
__device__ __forceinline__ unsigned fkey(float f) {
  unsigned u = __float_as_uint(f);
  return (u & 0x80000000u) ? ~u : (u | 0x80000000u);
}
__device__ __forceinline__ float funkey(unsigned k) {
  unsigned u = (k & 0x80000000u) ? (k ^ 0x80000000u) : ~k;
  return __uint_as_float(u);
}

// round-to-nearest-even f32 -> bf16 bits
__device__ __forceinline__ ushort_t bfh(float x) {
  unsigned u = __float_as_uint(x);
  return (ushort_t)((u + 0x7FFFu + ((u >> 16) & 1u)) >> 16);
}
__device__ __forceinline__ void split2(float x, ushort_t& h, ushort_t& l) {
  h = bfh(x);
  float hf = __uint_as_float(((unsigned)h) << 16);
  l = bfh(x - hf);
}

// ---------------- edge_index layout detection ----------------
__global__ __launch_bounds__(128) void k_detect(const int* __restrict__ e32,
                                                int* __restrict__ flag) {
  __shared__ int s;
  if (threadIdx.x == 0) s = 0;
  __syncthreads();
  if (e32[2 * threadIdx.x + 1] != 0) atomicOr(&s, 1);
  __syncthreads();
  if (threadIdx.x == 0) *flag = s;  // 1 => int32 layout, 0 => int64 layout
}

__global__ __launch_bounds__(256) void k_bond_fts(const float* __restrict__ bond_tab,
                                                  float* __restrict__ bf) {
  int t = blockIdx.x * 256 + threadIdx.x;      // 512*128
  int c = t >> 7, h = t & 127;
  int a0 = c & 7, a1 = (c >> 3) & 7, a2 = (c >> 6) & 7;
  bf[t] = bond_tab[(0 * 8 + a0) * Hh + h] + bond_tab[(1 * 8 + a1) * Hh + h] +
          bond_tab[(2 * 8 + a2) * Hh + h];
}

// ---------------- edge winner: win indexed by (g, d, s); last edge wins ----------
__global__ __launch_bounds__(256) void k_scatter_win(const int* __restrict__ e32,
                                                     const int* __restrict__ flag,
                                                     int* __restrict__ win) {
  int e = blockIdx.x * 256 + threadIdx.x;
  int sg, dg;
  if (*flag) { sg = e32[e]; dg = e32[Ee + e]; }
  else       { sg = e32[2 * e]; dg = e32[2 * Ee + 2 * e]; }
  int g = sg / Nn;
  int s = sg % Nn;
  int d = dg % Nn;
  atomicMax(&win[(g * Nn + d) * Nn + s], e);   // destination-major
}

// ---------------- per-destination compaction: count / scan / fill ----------------
__global__ __launch_bounds__(256) void k_dcount(const int* __restrict__ win,
                                                int* __restrict__ dcnt) {
  int tid = threadIdx.x;
  int grp = tid >> 7, t = tid & 127;
  int dest = blockIdx.x * 2 + grp;
  bool valid = win[dest * 128 + t] >= 0;
  unsigned long long mask = __ballot(valid);
  __shared__ int cw[4];
  if ((tid & 63) == 0) cw[tid >> 6] = __popcll(mask);
  __syncthreads();
  if (t == 0) dcnt[dest] = cw[grp * 2] + cw[grp * 2 + 1];
}

__global__ __launch_bounds__(512) void k_dscan(const int* __restrict__ dcnt,
                                               int* __restrict__ rowptr) {
  int tid = threadIdx.x;            // 512 threads x 8 dests = 4096
  int c0, c1, c2, c3, c4, c5, c6, c7;
  int bi = tid * 8;
  c0 = dcnt[bi + 0]; c1 = dcnt[bi + 1]; c2 = dcnt[bi + 2]; c3 = dcnt[bi + 3];
  c4 = dcnt[bi + 4]; c5 = dcnt[bi + 5]; c6 = dcnt[bi + 6]; c7 = dcnt[bi + 7];
  int s = c0 + c1 + c2 + c3 + c4 + c5 + c6 + c7;
  int x = s;
#pragma unroll
  for (int off = 1; off < 64; off <<= 1) {
    int y = __shfl_up(x, off, 64);
    if ((tid & 63) >= off) x += y;
  }
  __shared__ int wsum[8], woff[8];
  if ((tid & 63) == 63) wsum[tid >> 6] = x;
  __syncthreads();
  if (tid == 0) {
    int a = 0;
#pragma unroll
    for (int i = 0; i < 8; ++i) { woff[i] = a; a += wsum[i]; }
  }
  __syncthreads();
  int base = x - s + woff[tid >> 6];
  rowptr[bi + 0] = base; base += c0;
  rowptr[bi + 1] = base; base += c1;
  rowptr[bi + 2] = base; base += c2;
  rowptr[bi + 3] = base; base += c3;
  rowptr[bi + 4] = base; base += c4;
  rowptr[bi + 5] = base; base += c5;
  rowptr[bi + 6] = base; base += c6;
  rowptr[bi + 7] = base; base += c7;
  if (tid == 511) rowptr[4096] = base;   // total count
}

__global__ __launch_bounds__(256) void k_dfill(const int* __restrict__ win,
                                               const int* __restrict__ eattr,
                                               const int* __restrict__ rowptr,
                                               unsigned* __restrict__ recs) {
  int tid = threadIdx.x;
  int grp = tid >> 7, t = tid & 127;
  int dest = blockIdx.x * 2 + grp;
  int e = win[dest * 128 + t];
  bool valid = e >= 0;
  unsigned long long mask = __ballot(valid);
  __shared__ int cw[4];
  int lane = tid & 63;
  if (lane == 0) cw[tid >> 6] = __popcll(mask);
  __syncthreads();
  if (valid) {
    int off = __popcll(mask & ((1ull << lane) - 1));
    if ((tid >> 6) & 1) off += cw[grp * 2];
    int a0 = eattr[e * 3 + 0], a1 = eattr[e * 3 + 1], a2 = eattr[e * 3 + 2];
    unsigned code = (unsigned)(a0 + (a1 << 3) + (a2 << 6));
    unsigned idx = ((unsigned)dest << 7) | (unsigned)t;   // (g*128+d)*128+s
    recs[rowptr[dest] + off] = (idx << 9) | code;         // sorted by dest
  }
}

// ---------------- weight prep: fragment-ordered layouts ----------------
// element (n,k): nf=n>>4, lr=n&15, kf=k>>5, lg=(k>>3)&3, j=k&7
// off = ((nf*KCH + kf)*64 + lg*16 + lr)*8 + j  -> one wave-load = 1KB contiguous

// wt: [layer(2)][mat(2)][part(2)] of 16384, KCH=4
__global__ __launch_bounds__(256) void k_wprep(const float* __restrict__ W_h1,
                                               const float* __restrict__ W_h2,
                                               ushort_t* __restrict__ wt) {
  int t = blockIdx.x * 256 + threadIdx.x;      // 2*2*16384
  int l = t >> 15;
  int m = (t >> 14) & 1;
  int e = t & 16383;
  int n = e & 127, k = e >> 7;
  const float* W = (m == 0 ? W_h1 : W_h2) + l * 16384;
  float v = W[k * 128 + n];
  ushort_t h, lo;
  split2(v, h, lo);
  int nf = n >> 4, lr = n & 15, kf = k >> 5, lg = (k >> 3) & 3, j = k & 7;
  int off = ((nf * 4 + kf) * 64 + lg * 16 + lr) * 8 + j;
  int base = ((l * 2 + m) * 2) * 16384;
  wt[base + off] = h;
  wt[base + 16384 + off] = lo;
}

// wo: [layer(2)][part(2)] of 49152, KCH=12; grid (192, 2)
__global__ __launch_bounds__(256) void k_wprep_o(const float* __restrict__ W_o1,
                                                 const float* __restrict__ W_o2,
                                                 ushort_t* __restrict__ wo) {
  int e = blockIdx.x * 256 + threadIdx.x;      // 0 .. 49151  (= n*384 + k)
  int l = blockIdx.y;
  int n = e / 384, k = e - n * 384;
  float v = (k < 256) ? W_o1[(l * 256 + k) * 128 + n]
                      : W_o2[(l * 128 + (k - 256)) * 128 + n];
  ushort_t h, lo;
  split2(v, h, lo);
  int nf = n >> 4, lr = n & 15, kf = k >> 5, lg = (k >> 3) & 3, j = k & 7;
  int off = ((nf * 12 + kf) * 64 + lg * 16 + lr) * 8 + j;
  wo[(l * 2 + 0) * 49152 + off] = h;
  wo[(l * 2 + 1) * 49152 + off] = lo;
}

// wm: [layer(2)][mat(2)][part(2)] of 32768, KCH=8
__global__ __launch_bounds__(256) void k_wprep_m(const float* __restrict__ W_m1,
                                                 const float* __restrict__ W_m2,
                                                 ushort_t* __restrict__ wm) {
  int t = blockIdx.x * 256 + threadIdx.x;      // 131072 = 2l*2m*32768
  int l = t >> 16;
  int m = (t >> 15) & 1;
  int e = t & 32767;                           // n*256 + k
  int n = e >> 8, k = e & 255;
  const float* W = (m == 0 ? W_m1 : W_m2);
  float v = W[(l * 256 + k) * 128 + n];
  ushort_t h, lo;
  split2(v, h, lo);
  int nf = n >> 4, lr = n & 15, kf = k >> 5, lg = (k >> 3) & 3, j = k & 7;
  int off = ((nf * 8 + kf) * 64 + lg * 16 + lr) * 8 + j;
  int base = ((l * 2 + m) * 2) * 32768;
  wm[base + off] = h;
  wm[base + 32768 + off] = lo;
}

// ---------------- me tables (both layers) + both aggk inits, one launch --------
__global__ __launch_bounds__(256) void k_me2(const float* __restrict__ bf,
                                             const float* __restrict__ W_me,
                                             const float* __restrict__ b_me,
                                             const float* __restrict__ b_mg,
                                             float* __restrict__ me0,
                                             float* __restrict__ me1,
                                             unsigned* __restrict__ aggkA,
                                             unsigned* __restrict__ aggkB) {
  int bx = blockIdx.x;
  int l = bx >> 8, b2 = bx & 255;
  const float* W = W_me + l * 16384;
  const float* bme = b_me + l * 128;
  const float* bmg = b_mg + l * 128;
  float* me = l ? me1 : me0;
  unsigned* aggk = l ? aggkB : aggkA;
  __shared__ float v[2][128];
  int tid = threadIdx.x;
  int half = tid >> 7, j = tid & 127;
  int c = b2 * 2 + half;
  v[half][j] = bf[c * 128 + j];
  __syncthreads();
  float acc = bme[j] + bmg[j];
  for (int i = 0; i < 128; ++i) acc += v[half][i] * W[i * 128 + j];
  me[c * 128 + j] = acc;
  unsigned key = fkey(-1.0e9f);
#pragma unroll
  for (int i = 0; i < 8; ++i) aggk[b2 * 2048 + i * 256 + tid] = key;
}

// ---------------- MFMA A-fragment helpers ----------------
__device__ __forceinline__ void load_afrag(const ushort_t (*MH)[136],
                                           const ushort_t (*ML)[136],
                                           int row, int lg,
                                           bf16x8 ah[4], bf16x8 al[4]) {
#pragma unroll
  for (int kf = 0; kf < 4; ++kf) {
    ah[kf] = *(const bf16x8*)&MH[row][lg * 8 + 32 * kf];
    al[kf] = *(const bf16x8*)&ML[row][lg * 8 + 32 * kf];
  }
}

__device__ __forceinline__ void load_afrag264(const ushort_t (*MH)[264],
                                              const ushort_t (*ML)[264],
                                              int row, int base, int lg,
                                              bf16x8 ah[4], bf16x8 al[4]) {
#pragma unroll
  for (int kf = 0; kf < 4; ++kf) {
    ah[kf] = *(const bf16x8*)&MH[row][base + lg * 8 + 32 * kf];
    al[kf] = *(const bf16x8*)&ML[row][base + lg * 8 + 32 * kf];
  }
}

// ---------------- node encode + layer-0 m12 fused ----------------
// hid0 = 0 => m1 = nf @ W_m1[:128] + b1 (seg0 only)
__global__ __launch_bounds__(256) void k_encode_m12(const int* __restrict__ x,
                                                    const float* __restrict__ atom_tab,
                                                    const ushort_t* __restrict__ wm,
                                                    const float* __restrict__ bi1,
                                                    const float* __restrict__ bi2,
                                                    float* __restrict__ nf_,
                                                    float* __restrict__ hid,
                                                    float* __restrict__ m1,
                                                    float* __restrict__ m2) {
  __shared__ ushort_t AH[16][136];
  __shared__ ushort_t AL[16][136];
  __shared__ int xs[144];
  int tid = threadIdx.x;
  int v0 = blockIdx.x * 16;
  if (tid < 144) xs[tid] = x[v0 * 9 + tid];
  __syncthreads();
#pragma unroll
  for (int i = 0; i < 8; ++i) {
    int e = tid + i * 256;
    int row = e >> 7, col = e & 127;
    float s = 0.f;
#pragma unroll
    for (int f = 0; f < 9; ++f) {
      int idx = xs[row * 9 + f];
      s += atom_tab[(f * 119 + idx) * Hh + col];
    }
    nf_[(v0 + row) * Hh + col] = s;
    hid[(v0 + row) * Hh + col] = 0.f;
    ushort_t h, l;
    split2(s, h, l);
    AH[row][col] = h;
    AL[row][col] = l;
  }
  __syncthreads();
  int lane = tid & 63, wid = tid >> 6;
  int lr = lane & 15, lg = lane >> 4;
  f32x4 a1[2], a2[2];
#pragma unroll
  for (int i = 0; i < 2; ++i) { a1[i] = (f32x4){0.f,0.f,0.f,0.f}; a2[i] = (f32x4){0.f,0.f,0.f,0.f}; }
  const ushort_t* w1h = wm;
  const ushort_t* w1l = wm + 32768;
  const ushort_t* w2h = wm + 65536;
  const ushort_t* w2l = wm + 98304;
  bf16x8 ah[4], al[4];
  load_afrag(AH, AL, lr, lg, ah, al);
#pragma unroll
  for (int jj = 0; jj < 2; ++jj) {
    int nfr = 2 * wid + jj;
#pragma unroll
    for (int kf = 0; kf < 4; ++kf) {            // seg 0 only (hid = 0)
      int ch = ((nfr * 8 + kf) << 9) + lane * 8;
      bf16x8 b1h = *(const bf16x8*)(w1h + ch);
      bf16x8 b1l = *(const bf16x8*)(w1l + ch);
      bf16x8 b2h = *(const bf16x8*)(w2h + ch);
      bf16x8 b2l = *(const bf16x8*)(w2l + ch);
      a1[jj] = __builtin_amdgcn_mfma_f32_16x16x32_bf16(ah[kf], b1h, a1[jj], 0, 0, 0);
      a1[jj] = __builtin_amdgcn_mfma_f32_16x16x32_bf16(ah[kf], b1l, a1[jj], 0, 0, 0);
      a1[jj] = __builtin_amdgcn_mfma_f32_16x16x32_bf16(al[kf], b1h, a1[jj], 0, 0, 0);
      a2[jj] = __builtin_amdgcn_mfma_f32_16x16x32_bf16(ah[kf], b2h, a2[jj], 0, 0, 0);
      a2[jj] = __builtin_amdgcn_mfma_f32_16x16x32_bf16(ah[kf], b2l, a2[jj], 0, 0, 0);
      a2[jj] = __builtin_amdgcn_mfma_f32_16x16x32_bf16(al[kf], b2h, a2[jj], 0, 0, 0);
    }
  }
#pragma unroll
  for (int jj = 0; jj < 2; ++jj) {
    int col = 16 * (2 * wid + jj) + lr;
    float bb1 = bi1[col], bb2 = bi2[col];
#pragma unroll
    for (int reg = 0; reg < 4; ++reg) {
      int row = v0 + lg * 4 + reg;
      m1[row * Hh + col] = a1[jj][reg] + bb1;
      m2[row * Hh + col] = a2[jj][reg] + bb2;
    }
  }
}

// ---------------- edge phase: 64-edge tile, 8 waves (1 col-group each) ----------
__global__ __launch_bounds__(512) void k_edge(const unsigned* __restrict__ recs,
                                              const int* __restrict__ cnt,
                                              const float* __restrict__ m1,
                                              const float* __restrict__ m2,
                                              const float* __restrict__ me,
                                              const ushort_t* __restrict__ wt1h,
                                              const ushort_t* __restrict__ wt1l,
                                              const ushort_t* __restrict__ wt2h,
                                              const ushort_t* __restrict__ wt2l,
                                              const float* __restrict__ b_h1,
                                              const float* __restrict__ b_h2,
                                              unsigned* __restrict__ aggk) {
  __shared__ ushort_t MH[64][136];
  __shared__ ushort_t ML[64][136];
  __shared__ unsigned srec[64];
  int tid = threadIdx.x;
  int n = *cnt;
  if (tid < 64) {
    int r = blockIdx.x * 64 + tid;
    srec[tid] = (r < n) ? recs[r] : 0xFFFFFFFFu;
  }
  __syncthreads();
  // build M tile (float4-vectorized; 512 threads cover 64 rows x 32 col4)
  {
    int c4 = tid & 31, rq = tid >> 5;     // rq in 0..15
#pragma unroll
    for (int i = 0; i < 4; ++i) {
      int r = 16 * i + rq;
      float4 v = make_float4(0.f, 0.f, 0.f, 0.f);
      unsigned rec = srec[r];
      if (rec != 0xFFFFFFFFu) {
        int code = rec & 511;
        unsigned idx = rec >> 9;
        int s = idx & 127, d = (idx >> 7) & 127, g = idx >> 14;
        float4 a = *(const float4*)(m1 + (((g << 7) + d) << 7) + c4 * 4);
        float4 b = *(const float4*)(m2 + (((g << 7) + s) << 7) + c4 * 4);
        float4 cme = *(const float4*)(me + (code << 7) + c4 * 4);
        v.x = reluf(a.x + b.x + cme.x);
        v.y = reluf(a.y + b.y + cme.y);
        v.z = reluf(a.z + b.z + cme.z);
        v.w = reluf(a.w + b.w + cme.w);
      }
      us4 h4, l4;
      split2(v.x, h4.a, l4.a); split2(v.y, h4.b, l4.b);
      split2(v.z, h4.c, l4.c); split2(v.w, h4.d, l4.d);
      *(us4*)&MH[r][c4 * 4] = h4;
      *(us4*)&ML[r][c4 * 4] = l4;
    }
  }
  __syncthreads();

  int lane = tid & 63, wid = tid >> 6;     // wid = nf (0..7)
  int lr = lane & 15, lg = lane >> 4;
  float b1v = b_h1[16 * wid + lr];
  float b2v = b_h2[16 * wid + lr];
  f32x4 acc[4];
#pragma unroll
  for (int rg = 0; rg < 4; ++rg) acc[rg] = (f32x4){0.f, 0.f, 0.f, 0.f};
  // GEMM1: wave computes all 64 rows x its 16 cols (nf = wid)
#pragma unroll
  for (int rg = 0; rg < 4; ++rg) {
    bf16x8 ah[4], al[4];
    load_afrag(MH, ML, 16 * rg + lr, lg, ah, al);
#pragma unroll
    for (int kf = 0; kf < 4; ++kf) {
      int ch = ((wid * 4 + kf) << 9) + lane * 8;
      bf16x8 bh = *(const bf16x8*)(wt1h + ch);
      bf16x8 bl = *(const bf16x8*)(wt1l + ch);
      acc[rg] = __builtin_amdgcn_mfma_f32_16x16x32_bf16(ah[kf], bh, acc[rg], 0, 0, 0);
      acc[rg] = __builtin_amdgcn_mfma_f32_16x16x32_bf16(ah[kf], bl, acc[rg], 0, 0, 0);
      acc[rg] = __builtin_amdgcn_mfma_f32_16x16x32_bf16(al[kf], bh, acc[rg], 0, 0, 0);
    }
  }
  __syncthreads();   // M fully consumed by all waves
  // T = relu(acc + b1) -> MH/ML
#pragma unroll
  for (int rg = 0; rg < 4; ++rg)
#pragma unroll
    for (int reg = 0; reg < 4; ++reg) {
      float t = reluf(acc[rg][reg] + b1v);
      int row = 16 * rg + lg * 4 + reg;
      int col = 16 * wid + lr;
      ushort_t h, l;
      split2(t, h, l);
      MH[row][col] = h;
      ML[row][col] = l;
    }
  __syncthreads();   // T complete
  // GEMM2
#pragma unroll
  for (int rg = 0; rg < 4; ++rg) acc[rg] = (f32x4){0.f, 0.f, 0.f, 0.f};
#pragma unroll
  for (int rg = 0; rg < 4; ++rg) {
    bf16x8 ah[4], al[4];
    load_afrag(MH, ML, 16 * rg + lr, lg, ah, al);
#pragma unroll
    for (int kf = 0; kf < 4; ++kf) {
      int ch = ((wid * 4 + kf) << 9) + lane * 8;
      bf16x8 bh = *(const bf16x8*)(wt2h + ch);
      bf16x8 bl = *(const bf16x8*)(wt2l + ch);
      acc[rg] = __builtin_amdgcn_mfma_f32_16x16x32_bf16(ah[kf], bh, acc[rg], 0, 0, 0);
      acc[rg] = __builtin_amdgcn_mfma_f32_16x16x32_bf16(ah[kf], bl, acc[rg], 0, 0, 0);
      acc[rg] = __builtin_amdgcn_mfma_f32_16x16x32_bf16(al[kf], bh, acc[rg], 0, 0, 0);
    }
  }
  __syncthreads();   // T fully consumed
  // park f32 result bits in MH/ML
#pragma unroll
  for (int rg = 0; rg < 4; ++rg)
#pragma unroll
    for (int reg = 0; reg < 4; ++reg) {
      int row = 16 * rg + lg * 4 + reg;
      int col = 16 * wid + lr;
      unsigned b = __float_as_uint(acc[rg][reg] + b2v);
      MH[row][col] = (ushort_t)(b >> 16);
      ML[row][col] = (ushort_t)(b & 0xFFFFu);
    }
  __syncthreads();
  // run-dedup scatter: rows sorted by (g,d) = rec>>16; one atomic per run per col
  {
    int c = tid & 127, quarter = tid >> 7;   // 4 x 16-row segments
    int rbeg = quarter * 16, rend = rbeg + 16;
    unsigned curkey = 0xFFFFu;
    float best = -3.0e38f;
    for (int r = rbeg; r < rend; ++r) {
      unsigned rec = srec[r];
      unsigned key = rec >> 16;   // g*128+d (<=0xFFF) or 0xFFFF if invalid
      if (key != curkey) {
        if (curkey != 0xFFFFu)
          atomicMax(aggk + (curkey << 7) + c, fkey(best));
        curkey = key;
        best = -3.0e38f;
      }
      if (key != 0xFFFFu) {
        unsigned b = ((unsigned)MH[r][c] << 16) | (unsigned)ML[r][c];
        best = fmaxf(best, __uint_as_float(b));
      }
    }
    if (curkey != 0xFFFFu)
      atomicMax(aggk + (curkey << 7) + c, fkey(best));
  }
}

// ---------------- hid update via MFMA (plain, for last layer) ----------------
__global__ __launch_bounds__(256) void k_out(const float* __restrict__ nf,
                                             const float* __restrict__ hid,
                                             const unsigned* __restrict__ aggk,
                                             const ushort_t* __restrict__ wo_h,
                                             const ushort_t* __restrict__ wo_l,
                                             const float* __restrict__ bo1,
                                             const float* __restrict__ bo2,
                                             float* __restrict__ hidn) {
  __shared__ ushort_t MH[16][136];
  __shared__ ushort_t ML[16][136];
  int tid = threadIdx.x;
  int v0 = blockIdx.x * 16;
  int lane = tid & 63, wid = tid >> 6;
  int lr = lane & 15, lg = lane >> 4;
  f32x4 acc[2];
#pragma unroll
  for (int jj = 0; jj < 2; ++jj) acc[jj] = (f32x4){0.f, 0.f, 0.f, 0.f};

  for (int seg = 0; seg < 3; ++seg) {
#pragma unroll
    for (int i = 0; i < 2; ++i) {
      int idx = tid + i * 256;        // over 512 float4s
      int row = idx >> 5, c4 = idx & 31;
      float4 v;
      if (seg == 0)      v = ((const float4*)nf)[(v0 + row) * 32 + c4];
      else if (seg == 1) v = ((const float4*)hid)[(v0 + row) * 32 + c4];
      else {
        uint4 k4 = ((const uint4*)aggk)[(v0 + row) * 32 + c4];
        v.x = funkey(k4.x); v.y = funkey(k4.y); v.z = funkey(k4.z); v.w = funkey(k4.w);
      }
      us4 h4, l4;
      split2(v.x, h4.a, l4.a);
      split2(v.y, h4.b, l4.b);
      split2(v.z, h4.c, l4.c);
      split2(v.w, h4.d, l4.d);
      *(us4*)&MH[row][c4 * 4] = h4;
      *(us4*)&ML[row][c4 * 4] = l4;
    }
    __syncthreads();
    bf16x8 ah[4], al[4];
    load_afrag(MH, ML, lr, lg, ah, al);
#pragma unroll
    for (int jj = 0; jj < 2; ++jj) {
      int nfr = 2 * wid + jj;
#pragma unroll
      for (int kf = 0; kf < 4; ++kf) {
        int ch = ((nfr * 12 + seg * 4 + kf) << 9) + lane * 8;
        bf16x8 bh = *(const bf16x8*)(wo_h + ch);
        bf16x8 bl = *(const bf16x8*)(wo_l + ch);
        acc[jj] = __builtin_amdgcn_mfma_f32_16x16x32_bf16(ah[kf], bh, acc[jj], 0, 0, 0);
        acc[jj] = __builtin_amdgcn_mfma_f32_16x16x32_bf16(ah[kf], bl, acc[jj], 0, 0, 0);
        acc[jj] = __builtin_amdgcn_mfma_f32_16x16x32_bf16(al[kf], bh, acc[jj], 0, 0, 0);
      }
    }
    __syncthreads();
  }
#pragma unroll
  for (int jj = 0; jj < 2; ++jj) {
    int col = 16 * (2 * wid + jj) + lr;
    float b = bo1[col] + bo2[col];
#pragma unroll
    for (int reg = 0; reg < 4; ++reg)
      hidn[(v0 + lg * 4 + reg) * Hh + col] = reluf(acc[jj][reg] + b);
  }
}

// ---------------- hid update + next-layer m12 fused (for layer transition) -----
__global__ __launch_bounds__(256) void k_out_m12(const float* __restrict__ nf,
                                                 const float* __restrict__ hid,
                                                 const unsigned* __restrict__ aggk,
                                                 const ushort_t* __restrict__ wo_h,
                                                 const ushort_t* __restrict__ wo_l,
                                                 const float* __restrict__ bo1,
                                                 const float* __restrict__ bo2,
                                                 const ushort_t* __restrict__ wm,
                                                 const float* __restrict__ bm1,
                                                 const float* __restrict__ bm2,
                                                 float* __restrict__ hidn,
                                                 float* __restrict__ m1,
                                                 float* __restrict__ m2) {
  __shared__ ushort_t AH[16][264];
  __shared__ ushort_t AL[16][264];
  int tid = threadIdx.x;
  int v0 = blockIdx.x * 16;
  int lane = tid & 63, wid = tid >> 6;
  int lr = lane & 15, lg = lane >> 4;
  f32x4 acc[2];
#pragma unroll
  for (int jj = 0; jj < 2; ++jj) acc[jj] = (f32x4){0.f, 0.f, 0.f, 0.f};

  // phase 1: hidn = relu([nf|hid|agg] @ Wo + b)
  for (int seg = 0; seg < 3; ++seg) {
#pragma unroll
    for (int i = 0; i < 2; ++i) {
      int idx = tid + i * 256;
      int row = idx >> 5, c4 = idx & 31;
      float4 v;
      if (seg == 0)      v = ((const float4*)nf)[(v0 + row) * 32 + c4];
      else if (seg == 1) v = ((const float4*)hid)[(v0 + row) * 32 + c4];
      else {
        uint4 k4 = ((const uint4*)aggk)[(v0 + row) * 32 + c4];
        v.x = funkey(k4.x); v.y = funkey(k4.y); v.z = funkey(k4.z); v.w = funkey(k4.w);
      }
      us4 h4, l4;
      split2(v.x, h4.a, l4.a);
      split2(v.y, h4.b, l4.b);
      split2(v.z, h4.c, l4.c);
      split2(v.w, h4.d, l4.d);
      *(us4*)&AH[row][c4 * 4] = h4;
      *(us4*)&AL[row][c4 * 4] = l4;
    }
    __syncthreads();
    bf16x8 ah[4], al[4];
    load_afrag264(AH, AL, lr, 0, lg, ah, al);
#pragma unroll
    for (int jj = 0; jj < 2; ++jj) {
      int nfr = 2 * wid + jj;
#pragma unroll
      for (int kf = 0; kf < 4; ++kf) {
        int ch = ((nfr * 12 + seg * 4 + kf) << 9) + lane * 8;
        bf16x8 bh = *(const bf16x8*)(wo_h + ch);
        bf16x8 bl = *(const bf16x8*)(wo_l + ch);
        acc[jj] = __builtin_amdgcn_mfma_f32_16x16x32_bf16(ah[kf], bh, acc[jj], 0, 0, 0);
        acc[jj] = __builtin_amdgcn_mfma_f32_16x16x32_bf16(ah[kf], bl, acc[jj], 0, 0, 0);
        acc[jj] = __builtin_amdgcn_mfma_f32_16x16x32_bf16(al[kf], bh, acc[jj], 0, 0, 0);
      }
    }
    __syncthreads();
  }
  // write hidn + stage hidn into cols 128..255
#pragma unroll
  for (int jj = 0; jj < 2; ++jj) {
    int col = 16 * (2 * wid + jj) + lr;
    float b = bo1[col] + bo2[col];
#pragma unroll
    for (int reg = 0; reg < 4; ++reg) {
      float hv = reluf(acc[jj][reg] + b);
      int row = lg * 4 + reg;
      hidn[(v0 + row) * Hh + col] = hv;
      ushort_t h, l;
      split2(hv, h, l);
      AH[row][128 + col] = h;
      AL[row][128 + col] = l;
    }
  }
  // stage nf into cols 0..127
#pragma unroll
  for (int i = 0; i < 2; ++i) {
    int idx = tid + i * 256;
    int row = idx >> 5, c4 = idx & 31;
    float4 v = ((const float4*)nf)[(v0 + row) * 32 + c4];
    us4 h4, l4;
    split2(v.x, h4.a, l4.a);
    split2(v.y, h4.b, l4.b);
    split2(v.z, h4.c, l4.c);
    split2(v.w, h4.d, l4.d);
    *(us4*)&AH[row][c4 * 4] = h4;
    *(us4*)&AL[row][c4 * 4] = l4;
  }
  __syncthreads();
  // phase 2: m1/m2 = [nf|hidn] @ W_m + b (2 segs)
  f32x4 a1[2], a2[2];
#pragma unroll
  for (int i = 0; i < 2; ++i) { a1[i] = (f32x4){0.f,0.f,0.f,0.f}; a2[i] = (f32x4){0.f,0.f,0.f,0.f}; }
  const ushort_t* w1h = wm;
  const ushort_t* w1l = wm + 32768;
  const ushort_t* w2h = wm + 65536;
  const ushort_t* w2l = wm + 98304;
#pragma unroll
  for (int seg = 0; seg < 2; ++seg) {
    bf16x8 ah[4], al[4];
    load_afrag264(AH, AL, lr, seg * 128, lg, ah, al);
#pragma unroll
    for (int jj = 0; jj < 2; ++jj) {
      int nfr = 2 * wid + jj;
#pragma unroll
      for (int kf = 0; kf < 4; ++kf) {
        int ch = ((nfr * 8 + seg * 4 + kf) << 9) + lane * 8;
        bf16x8 b1h = *(const bf16x8*)(w1h + ch);
        bf16x8 b1l = *(const bf16x8*)(w1l + ch);
        bf16x8 b2h = *(const bf16x8*)(w2h + ch);
        bf16x8 b2l = *(const bf16x8*)(w2l + ch);
        a1[jj] = __builtin_amdgcn_mfma_f32_16x16x32_bf16(ah[kf], b1h, a1[jj], 0, 0, 0);
        a1[jj] = __builtin_amdgcn_mfma_f32_16x16x32_bf16(ah[kf], b1l, a1[jj], 0, 0, 0);
        a1[jj] = __builtin_amdgcn_mfma_f32_16x16x32_bf16(al[kf], b1h, a1[jj], 0, 0, 0);
        a2[jj] = __builtin_amdgcn_mfma_f32_16x16x32_bf16(ah[kf], b2h, a2[jj], 0, 0, 0);
        a2[jj] = __builtin_amdgcn_mfma_f32_16x16x32_bf16(ah[kf], b2l, a2[jj], 0, 0, 0);
        a2[jj] = __builtin_amdgcn_mfma_f32_16x16x32_bf16(al[kf], b2h, a2[jj], 0, 0, 0);
      }
    }
  }
#pragma unroll
  for (int jj = 0; jj < 2; ++jj) {
    int col = 16 * (2 * wid + jj) + lr;
    float bb1 = bm1[col], bb2 = bm2[col];
#pragma unroll
    for (int reg = 0; reg < 4; ++reg) {
      int row = v0 + lg * 4 + reg;
      m1[row * Hh + col] = a1[jj][reg] + bb1;
      m2[row * Hh + col] = a2[jj][reg] + bb2;
    }
  }
}

// ---------------- readout head ----------------
__global__ __launch_bounds__(128) void k_head(const float* __restrict__ hid,
                                              const float* __restrict__ Wg1,
                                              const float* __restrict__ bg1,
                                              const float* __restrict__ Wg2,
                                              const float* __restrict__ bg2,
                                              float* __restrict__ out) {
  __shared__ float emb[Hh];
  __shared__ float tt[Hh];
  int g = blockIdx.x, j = threadIdx.x;
  float s = 0.f;
  for (int n = 0; n < Nn; ++n) s += hid[(g * Nn + n) * Hh + j];
  emb[j] = s * (1.f / Nn);
  __syncthreads();
  float a = bg1[j];
  for (int i = 0; i < Hh; ++i) a += emb[i] * Wg1[i * Hh + j];
  tt[j] = reluf(a);
  __syncthreads();
  if (j < 12) {
    float o = bg2[j];
    for (int i = 0; i < Hh; ++i) o += tt[i] * Wg2[i * 12 + j];
    out[g * 12 + j] = o;
  }
}

extern "C" void kernel_launch(void* const* d_in, const int* in_sizes, int n_in,
                              void* d_out, int out_size, void* d_ws, size_t ws_size,
                              hipStream_t stream) {
  const int* x = (const int*)d_in[0];
  const int* eidx32 = (const int*)d_in[1];
  const int* eattr = (const int*)d_in[2];
  const float* atom_tab = (const float*)d_in[4];
  const float* bond_tab = (const float*)d_in[5];
  const float* W_m1 = (const float*)d_in[6];
  const float* b_m1 = (const float*)d_in[7];
  const float* W_m2 = (const float*)d_in[8];
  const float* b_m2 = (const float*)d_in[9];
  const float* W_me = (const float*)d_in[10];
  const float* b_me = (const float*)d_in[11];
  const float* b_mg = (const float*)d_in[13];
  const float* W_h1 = (const float*)d_in[14];
  const float* b_h1 = (const float*)d_in[15];
  const float* W_h2 = (const float*)d_in[16];
  const float* b_h2 = (const float*)d_in[17];
  const float* W_o1 = (const float*)d_in[18];
  const float* b_o1 = (const float*)d_in[19];
  const float* W_o2 = (const float*)d_in[20];
  const float* b_o2 = (const float*)d_in[21];
  const float* Wg1 = (const float*)d_in[22];
  const float* bg1 = (const float*)d_in[23];
  const float* Wg2 = (const float*)d_in[24];
  const float* bg2 = (const float*)d_in[25];
  float* out = (float*)d_out;

  char* ws = (char*)d_ws;
  float* nf = (float*)(ws);                                 // 2MB
  float* hidA = (float*)(ws + (2u << 20));                  // 2MB (hid0 zeros, hid2)
  float* hidB = (float*)(ws + (4u << 20));                  // 2MB (hid1)
  float* m1 = (float*)(ws + (6u << 20));                    // 2MB
  float* m2 = (float*)(ws + (8u << 20));                    // 2MB
  unsigned* aggkA = (unsigned*)(ws + (10u << 20));          // 2MB
  int* win = (int*)(ws + (12u << 20));                      // 2MB (dead after k_dfill)
  ushort_t* wt = (ushort_t*)(ws + (14u << 20));             // 256KB
  float* bf = (float*)(ws + (14u << 20) + (256u << 10));    // 256KB
  float* me0 = (float*)(ws + (14u << 20) + (512u << 10));   // 256KB
  float* me1 = (float*)(ws + (14u << 20) + (768u << 10));   // 256KB
  unsigned* recs = (unsigned*)(ws + (15u << 20));           // 256KB
  int* dcnt = (int*)(ws + (15u << 20) + (256u << 10));      // 16KB
  int* rowptr = (int*)(ws + (15u << 20) + (272u << 10));    // 16KB+4
  int* eflag = (int*)(ws + (15u << 20) + (304u << 10));     // 4B
  unsigned* aggkB = (unsigned*)(ws + (16u << 20));          // 2MB
  ushort_t* wo = (ushort_t*)(ws + (18u << 20));             // 384KB
  ushort_t* wm = (ushort_t*)(ws + (18u << 20) + (512u << 10));  // 512KB

  hipMemsetAsync(win, 0xFF, GNN * sizeof(int), stream);
  k_detect<<<1, 128, 0, stream>>>(eidx32, eflag);
  k_bond_fts<<<256, 256, 0, stream>>>(bond_tab, bf);
  k_wprep<<<256, 256, 0, stream>>>(W_h1, W_h2, wt);
  k_wprep_o<<<dim3(192, 2), 256, 0, stream>>>(W_o1, W_o2, wo);
  k_wprep_m<<<512, 256, 0, stream>>>(W_m1, W_m2, wm);
  k_me2<<<512, 256, 0, stream>>>(bf, W_me, b_me, b_mg, me0, me1, aggkA, aggkB);
  k_encode_m12<<<256, 256, 0, stream>>>(x, atom_tab, wm, b_m1, b_m2,
                                        nf, hidA, m1, m2);
  k_scatter_win<<<256, 256, 0, stream>>>(eidx32, eflag, win);
  k_dcount<<<2048, 256, 0, stream>>>(win, dcnt);
  k_dscan<<<1, 512, 0, stream>>>(dcnt, rowptr);
  k_dfill<<<2048, 256, 0, stream>>>(win, eattr, rowptr, recs);

  int* cnt = rowptr + 4096;   // total edge count written by k_dscan

  // layer 0
  k_edge<<<1024, 512, 0, stream>>>(recs, cnt, m1, m2, me0,
                                   wt + 0 * 16384, wt + 1 * 16384,
                                   wt + 2 * 16384, wt + 3 * 16384,
                                   b_h1, b_h2, aggkA);
  k_out_m12<<<256, 256, 0, stream>>>(nf, hidA, aggkA,
                                     wo + 0 * 49152, wo + 1 * 49152,
                                     b_o1, b_o2,
                                     wm + 131072, b_m1 + Hh, b_m2 + Hh,
                                     hidB, m1, m2);
  // layer 1
  k_edge<<<1024, 512, 0, stream>>>(recs, cnt, m1, m2, me1,
                                   wt + 4 * 16384, wt + 5 * 16384,
                                   wt + 6 * 16384, wt + 7 * 16384,
                                   b_h1 + Hh, b_h2 + Hh, aggkB);
  k_out<<<256, 256, 0, stream>>>(nf, hidB, aggkB,
                                 wo + 2 * 49152, wo + 3 * 49152,
                                 b_o1 + Hh, b_o2 + Hh, hidA);
  k_head<<<32, 128, 0, stream>>>(hidA, Wg1, bg1, Wg2, bg2, out);
}